// Round 4
// baseline (632.292 us; speedup 1.0000x reference)
//
#include <hip/hip_runtime.h>
#include <hip/hip_bf16.h>

#define N_TOK 2048
#define DMODEL 2048
#define NH 16
#define DK 128
#define DFF 8192

typedef __attribute__((ext_vector_type(8))) short short8;
typedef __attribute__((ext_vector_type(4))) short s16x4;
typedef __attribute__((ext_vector_type(4))) float f32x4;

__device__ __forceinline__ short f2bf(float f) {
    unsigned int x = __builtin_bit_cast(unsigned int, f);
    unsigned int r = (x + 0x7fffu + ((x >> 16) & 1u)) >> 16;
    return (short)r;
}

// ---------------- cast X (f32 -> bf16), 8 elems/thread ----------------
__global__ __launch_bounds__(256) void cast_f32_bf16(const float* __restrict__ in,
                                                     short* __restrict__ out, int n8) {
    int i = blockIdx.x * 256 + threadIdx.x;
    if (i >= n8) return;
    const float4* p = (const float4*)in + (size_t)i * 2;
    float4 a = p[0], b = p[1];
    short8 o;
    o[0] = f2bf(a.x); o[1] = f2bf(a.y); o[2] = f2bf(a.z); o[3] = f2bf(a.w);
    o[4] = f2bf(b.x); o[5] = f2bf(b.y); o[6] = f2bf(b.z); o[7] = f2bf(b.w);
    *(short8*)(out + (size_t)i * 8) = o;
}

// ---------------- transpose + cast to bf16 (64x64 LDS tiles) ----------------
template <typename TIN>
__global__ __launch_bounds__(256) void transpose_cast(const TIN* __restrict__ in,
                                                      short* __restrict__ out,
                                                      int R, int C, long sIn, long sOut) {
    __shared__ float t[64][65];
    in  += (long)blockIdx.z * sIn;
    out += (long)blockIdx.z * sOut;
    int tx = threadIdx.x & 63, ty = threadIdx.x >> 6;
    long r0 = (long)blockIdx.y * 64, c0 = (long)blockIdx.x * 64;
    for (int i = 0; i < 16; i++) {
        int r = ty + i * 4;
        t[r][tx] = (float)in[(r0 + r) * (long)C + c0 + tx];
    }
    __syncthreads();
    for (int i = 0; i < 16; i++) {
        int r = ty + i * 4;
        out[(c0 + r) * (long)R + r0 + tx] = f2bf(t[tx][r]);
    }
}

// ---------------- async global->LDS helper ----------------
__device__ __forceinline__ void gld_lds16(const short* g, short* l) {
    __builtin_amdgcn_global_load_lds(
        (const __attribute__((address_space(1))) void*)g,
        (__attribute__((address_space(3))) void*)l, 16, 0, 0);
}

// ---------------- bf16 GEMM, B pre-transposed ([n][k]) -------------------
// 128x128 tile, 4 waves (2x2 of 64x64), BK=32, m97 structure.
// MODE 0: out bf16, +bias (QKV batched z=48, bias selected by z>>4)
// MODE 1: out bf16, +bias, ReLU      (FFN1)
// MODE 3: out f32, no bias, split-K slab z  (FFN2)
template <int MODE>
__global__ __launch_bounds__(256) void gemm_bt(const short* __restrict__ A,
                                               const short* __restrict__ Bt,
                                               void* __restrict__ Cv,
                                               const float* __restrict__ bias,
                                               const float* __restrict__ bias2,
                                               const float* __restrict__ bias3,
                                               int M, int N, int K, int Kloop,
                                               long sA, long sB, long sC) {
    __shared__ short As[128 * 32];
    __shared__ short Bs[128 * 32];
    const int tid = threadIdx.x;
    const int lane = tid & 63, w = tid >> 6;
    const long z = blockIdx.z;
    const float* bp = bias;
    if (MODE == 0) {
        int sel = (int)(z >> 4);
        bp = (sel == 0 ? bias : sel == 1 ? bias2 : bias3) + (z & 15) * 128;
        Bt += z * sB;
    } else if (MODE == 3) {
        A += z * (long)Kloop;
        Bt += z * (long)Kloop;
    } else {
        A += z * sA; Bt += z * sB;
    }
    const long brow = (long)blockIdx.y * 128, bcol = (long)blockIdx.x * 128;

    const int srow = w * 32 + (lane >> 2);
    const int koff = (lane & 3) * 8;
    const short* ga0 = A  + (brow + srow) * (long)K + koff;
    const short* ga1 = ga0 + 16L * K;
    const short* gb0 = Bt + (bcol + srow) * (long)K + koff;
    const short* gb1 = gb0 + 16L * K;
    short* lA0 = As + (w * 2 + 0) * 512;
    short* lA1 = As + (w * 2 + 1) * 512;
    short* lB0 = Bs + (w * 2 + 0) * 512;
    short* lB1 = Bs + (w * 2 + 1) * 512;

    const int wr = w >> 1, wc = w & 1;
    const int fr = lane & 15, fq = lane >> 4;
    f32x4 acc[4][4] = {};

    for (int k0 = 0; k0 < Kloop; k0 += 32) {
        gld_lds16(ga0, lA0); gld_lds16(ga1, lA1);
        gld_lds16(gb0, lB0); gld_lds16(gb1, lB1);
        ga0 += 32; ga1 += 32; gb0 += 32; gb1 += 32;
        __syncthreads();
        short8 af[4], bf[4];
#pragma unroll
        for (int m = 0; m < 4; m++)
            af[m] = *(const short8*)(As + (wr * 64 + m * 16 + fr) * 32 + fq * 8);
#pragma unroll
        for (int n = 0; n < 4; n++)
            bf[n] = *(const short8*)(Bs + (wc * 64 + n * 16 + fr) * 32 + fq * 8);
#pragma unroll
        for (int m = 0; m < 4; m++)
#pragma unroll
            for (int n = 0; n < 4; n++)
                acc[m][n] = __builtin_amdgcn_mfma_f32_16x16x32_bf16(af[m], bf[n], acc[m][n], 0, 0, 0);
        __syncthreads();
    }

    const long crow0 = brow + wr * 64, ccol0 = bcol + wc * 64;
#pragma unroll
    for (int n = 0; n < 4; n++) {
        long col = ccol0 + n * 16 + fr;
        float bv = (MODE == 3) ? 0.f : bp[col];
#pragma unroll
        for (int m = 0; m < 4; m++) {
#pragma unroll
            for (int r = 0; r < 4; r++) {
                long row = crow0 + m * 16 + fq * 4 + r;
                float v = acc[m][n][r] + bv;
                if (MODE == 1) v = fmaxf(v, 0.f);
                if (MODE == 3)
                    ((float*)Cv)[z * sC + row * (long)N + col] = v;
                else
                    ((short*)Cv)[z * sC + row * (long)N + col] = f2bf(v);
            }
        }
    }
}

// ---------------- flash attention v4: 8 waves x 16 q-rows, K+V preloaded ----
// Q,K: [H][N][DK] bf16.  VT: [H][DK][N] bf16.  O: [N][DMODEL] f32.
// Grid 256 blocks x 512 threads; block = (h, qt of 128 rows); barrier-free.
__global__ __launch_bounds__(512, 2) void attn_flash(const short* __restrict__ Q,
                                                     const short* __restrict__ Kc,
                                                     const short* __restrict__ VT,
                                                     float* __restrict__ O) {
    __shared__ short P[8][16 * 64];  // per-wave XOR-swizzled P tile
    const int tid = threadIdx.x, lane = tid & 63, w = tid >> 6;
    const int h = blockIdx.x >> 4, qt = blockIdx.x & 15;
    const int fr = lane & 15, fq = lane >> 4;
    const long qbase = (long)qt * 128 + w * 16;
    const short* Qh = Q  + (long)h * N_TOK * DK;
    const short* Kh = Kc + (long)h * N_TOK * DK;
    const short* Vh = VT + (long)h * DK * N_TOK;

    // Q fragments (B-operand of swapped QK): lane holds Q[qbase+fr][k-chunk]
    short8 qf[4];
#pragma unroll
    for (int c = 0; c < 4; c++)
        qf[c] = *(const short8*)(Qh + (qbase + fr) * DK + c * 32 + fq * 8);

    float mrow = -1e30f, lrow = 0.f;
    f32x4 oacc[8] = {};
    const float C1 = 0.08838834764831845f * 1.4426950408889634f; // 1/sqrt(128)*log2e

    int wr_off[4], rd_off[2];
#pragma unroll
    for (int jc = 0; jc < 4; jc++)
        wr_off[jc] = (fr * 64 + jc * 16 + fq * 4) ^ ((fr & 7) << 3);
#pragma unroll
    for (int kc = 0; kc < 2; kc++)
        rd_off[kc] = (fr * 64 + kc * 32 + fq * 8) ^ ((fr & 7) << 3);
    short* Pw = P[w];

    for (int kv = 0; kv < N_TOK; kv += 64) {
        // K fragments (A-operand) + V fragments (A-operand of PV), all issued up-front
        short8 kf[16], vf[16];
#pragma unroll
        for (int jc = 0; jc < 4; jc++)
#pragma unroll
            for (int c = 0; c < 4; c++)
                kf[jc * 4 + c] = *(const short8*)(Kh + (long)(kv + jc * 16 + fr) * DK + c * 32 + fq * 8);
#pragma unroll
        for (int f = 0; f < 8; f++)
#pragma unroll
            for (int kc = 0; kc < 2; kc++)
                vf[f * 2 + kc] = *(const short8*)(Vh + (f * 16 + fr) * (long)N_TOK + kv + kc * 32 + fq * 8);

        // S^T = K . Q^T : lane holds S[key=jc*16+fq*4+r][q=fr]
        f32x4 s[4] = {};
#pragma unroll
        for (int jc = 0; jc < 4; jc++)
#pragma unroll
            for (int c = 0; c < 4; c++)
                s[jc] = __builtin_amdgcn_mfma_f32_16x16x32_bf16(kf[jc * 4 + c], qf[c], s[jc], 0, 0, 0);

        // online softmax: per-lane q-row (q=fr), 16 keys in-register; reduce over fq
        float tm = -1e30f;
#pragma unroll
        for (int jc = 0; jc < 4; jc++)
#pragma unroll
            for (int r = 0; r < 4; r++) tm = fmaxf(tm, s[jc][r]);
        tm = fmaxf(tm, __shfl_xor(tm, 16));
        tm = fmaxf(tm, __shfl_xor(tm, 32));
        float nm = fmaxf(mrow, tm);
        float resc = exp2f(C1 * (mrow - nm));
        mrow = nm;
        float sum = 0.f;
#pragma unroll
        for (int jc = 0; jc < 4; jc++)
#pragma unroll
            for (int r = 0; r < 4; r++) {
                float p = exp2f(C1 * (s[jc][r] - nm));
                s[jc][r] = p;
                sum += p;
            }
        sum += __shfl_xor(sum, 16);
        sum += __shfl_xor(sum, 32);
        lrow = lrow * resc + sum;
#pragma unroll
        for (int f = 0; f < 8; f++)
#pragma unroll
            for (int r = 0; r < 4; r++) oacc[f][r] *= resc;

        // P bounce through per-wave LDS (layout fix for PV B-operand)
#pragma unroll
        for (int jc = 0; jc < 4; jc++) {
            s16x4 pk;
            pk[0] = f2bf(s[jc][0]); pk[1] = f2bf(s[jc][1]);
            pk[2] = f2bf(s[jc][2]); pk[3] = f2bf(s[jc][3]);
            *(s16x4*)(Pw + wr_off[jc]) = pk;
        }
        short8 pa[2];
#pragma unroll
        for (int kc = 0; kc < 2; kc++)
            pa[kc] = *(const short8*)(Pw + rd_off[kc]);

        // O^T += V^T . P^T (V already in registers)
#pragma unroll
        for (int f = 0; f < 8; f++)
#pragma unroll
            for (int kc = 0; kc < 2; kc++)
                oacc[f] = __builtin_amdgcn_mfma_f32_16x16x32_bf16(vf[f * 2 + kc], pa[kc], oacc[f], 0, 0, 0);
    }
    const float inv = 1.f / lrow;
    const long row = qbase + fr;
#pragma unroll
    for (int f = 0; f < 8; f++) {
        float4 o;
        o.x = oacc[f][0] * inv; o.y = oacc[f][1] * inv;
        o.z = oacc[f][2] * inv; o.w = oacc[f][3] * inv;
        *(float4*)(O + row * (long)DMODEL + h * DK + f * 16 + fq * 4) = o;
    }
}

// ---------------- fused Add + LayerNorm (1 block = 1 row of 2048) -----------
template <bool WBF>
__global__ __launch_bounds__(256) void add_ln(const float* __restrict__ A,
                                              const float* __restrict__ B,
                                              const float* __restrict__ alpha,
                                              const float* __restrict__ beta,
                                              float* __restrict__ out,
                                              short* __restrict__ outbf) {
    const int row = blockIdx.x, t = threadIdx.x;
    const long base = (long)row * DMODEL;
    float4 va[2], vb[2];
    float s = 0.f, q = 0.f;
#pragma unroll
    for (int i = 0; i < 2; i++) {
        long off = base + (long)(t + i * 256) * 4;
        va[i] = *(const float4*)(A + off);
        vb[i] = *(const float4*)(B + off);
        float x0 = va[i].x + vb[i].x, x1 = va[i].y + vb[i].y;
        float x2 = va[i].z + vb[i].z, x3 = va[i].w + vb[i].w;
        s += x0 + x1 + x2 + x3;
        q += x0 * x0 + x1 * x1 + x2 * x2 + x3 * x3;
    }
#pragma unroll
    for (int o = 1; o < 64; o <<= 1) { s += __shfl_xor(s, o); q += __shfl_xor(q, o); }
    __shared__ float red[8];
    if ((t & 63) == 0) { red[t >> 6] = s; red[4 + (t >> 6)] = q; }
    __syncthreads();
    s = red[0] + red[1] + red[2] + red[3];
    q = red[4] + red[5] + red[6] + red[7];
    const float mean = s * (1.f / DMODEL);
    const float var = q * (1.f / DMODEL) - mean * mean;
    const float rstd = rsqrtf(var + 1e-5f);
#pragma unroll
    for (int i = 0; i < 2; i++) {
        long off = base + (long)(t + i * 256) * 4;
        float4 al = *(const float4*)(alpha + off);
        float4 be = *(const float4*)(beta + off);
        float x[4] = { va[i].x + vb[i].x, va[i].y + vb[i].y, va[i].z + vb[i].z, va[i].w + vb[i].w };
        float a[4] = { al.x, al.y, al.z, al.w };
        float b[4] = { be.x, be.y, be.z, be.w };
#pragma unroll
        for (int j = 0; j < 4; j++) {
            float o2 = (x[j] - mean) * rstd * a[j] + b[j];
            out[off + j] = o2;
            if (WBF) outbf[off + j] = f2bf(o2);
        }
    }
}

// ---------------- Add + LN2 with 4-slab split-K reduction + bias ------------
__global__ __launch_bounds__(256) void add_ln2_red(const float* __restrict__ H1,
                                                   const float* __restrict__ F4,
                                                   const float* __restrict__ b2,
                                                   const float* __restrict__ alpha,
                                                   const float* __restrict__ beta,
                                                   float* __restrict__ out) {
    const int row = blockIdx.x, t = threadIdx.x;
    const long base = (long)row * DMODEL;
    const long SL = (long)N_TOK * DMODEL;
    float x[8];
    float s = 0.f, q = 0.f;
#pragma unroll
    for (int i = 0; i < 2; i++) {
        long off = base + (long)(t + i * 256) * 4;
        int col = (t + i * 256) * 4;
        float4 a  = *(const float4*)(H1 + off);
        float4 f0 = *(const float4*)(F4 + off);
        float4 f1 = *(const float4*)(F4 + off + SL);
        float4 f2 = *(const float4*)(F4 + off + 2 * SL);
        float4 f3 = *(const float4*)(F4 + off + 3 * SL);
        float4 bb = *(const float4*)(b2 + col);
        x[i * 4 + 0] = a.x + f0.x + f1.x + f2.x + f3.x + bb.x;
        x[i * 4 + 1] = a.y + f0.y + f1.y + f2.y + f3.y + bb.y;
        x[i * 4 + 2] = a.z + f0.z + f1.z + f2.z + f3.z + bb.z;
        x[i * 4 + 3] = a.w + f0.w + f1.w + f2.w + f3.w + bb.w;
#pragma unroll
        for (int j = 0; j < 4; j++) { s += x[i * 4 + j]; q += x[i * 4 + j] * x[i * 4 + j]; }
    }
#pragma unroll
    for (int o = 1; o < 64; o <<= 1) { s += __shfl_xor(s, o); q += __shfl_xor(q, o); }
    __shared__ float red[8];
    if ((t & 63) == 0) { red[t >> 6] = s; red[4 + (t >> 6)] = q; }
    __syncthreads();
    s = red[0] + red[1] + red[2] + red[3];
    q = red[4] + red[5] + red[6] + red[7];
    const float mean = s * (1.f / DMODEL);
    const float var = q * (1.f / DMODEL) - mean * mean;
    const float rstd = rsqrtf(var + 1e-5f);
#pragma unroll
    for (int i = 0; i < 2; i++) {
        long off = base + (long)(t + i * 256) * 4;
        float4 al = *(const float4*)(alpha + off);
        float4 be = *(const float4*)(beta + off);
        float a[4] = { al.x, al.y, al.z, al.w };
        float b[4] = { be.x, be.y, be.z, be.w };
#pragma unroll
        for (int j = 0; j < 4; j++)
            out[off + j] = (x[i * 4 + j] - mean) * rstd * a[j] + b[j];
    }
}

extern "C" void kernel_launch(void* const* d_in, const int* in_sizes, int n_in,
                              void* d_out, int out_size, void* d_ws, size_t ws_size,
                              hipStream_t stream) {
    const float* X      = (const float*)d_in[0];
    const float* Wq     = (const float*)d_in[1];
    const float* bq     = (const float*)d_in[2];
    const float* Wk     = (const float*)d_in[3];
    const float* bk     = (const float*)d_in[4];
    const float* Wv     = (const float*)d_in[5];
    const float* bv     = (const float*)d_in[6];
    const float* alpha1 = (const float*)d_in[7];
    const float* beta1  = (const float*)d_in[8];
    const float* W1     = (const float*)d_in[9];
    const float* b1     = (const float*)d_in[10];
    const float* W2     = (const float*)d_in[11];
    const float* b2     = (const float*)d_in[12];
    const float* alpha2 = (const float*)d_in[13];
    const float* beta2  = (const float*)d_in[14];
    float* out = (float*)d_out;

    char* ws = (char*)d_ws;
    size_t off = 0;
    auto alloc = [&](size_t bytes) -> void* {
        void* p = ws + off;
        off += (bytes + 255) & ~(size_t)255;
        return p;
    };
    short* XBF   = (short*)alloc(2048UL * 2048 * 2);       // dead after QKV gemm
    short* WQKVT = (short*)alloc(48UL * 128 * 2048 * 2);   // dead after QKV gemm
    short* W1T   = (short*)alloc(8192UL * 2048 * 2);       // dead after FFN1
    short* W2T   = (short*)alloc(2048UL * 8192 * 2);
    short* QKV   = (short*)alloc(48UL * 2048 * 128 * 2);   // Q(0-15),K(16-31),V(32-47)
    short* VT    = (short*)alloc(16UL * 128 * 2048 * 2);
    float* ATTN  = (float*)alloc(2048UL * 2048 * 4);
    float* H1    = (float*)alloc(2048UL * 2048 * 4);
    short* H1BF  = (short*)alloc(2048UL * 2048 * 2);
    short* G     = (short*)alloc(2048UL * 8192 * 2);
    // F4 (64 MB, 4 split-K f32 slabs) aliases XBF+WQKVT+W1T (all dead by FFN2)
    float* F4 = (float*)XBF;

    // 1. casts / transposes
    cast_f32_bf16<<<2048, 256, 0, stream>>>(X, XBF, 2048 * 2048 / 8);
    transpose_cast<float><<<dim3(2, 32, 16), 256, 0, stream>>>(Wq, WQKVT,                    2048, 128, 2048L * 128, 128L * 2048);
    transpose_cast<float><<<dim3(2, 32, 16), 256, 0, stream>>>(Wk, WQKVT + 16L * 128 * 2048, 2048, 128, 2048L * 128, 128L * 2048);
    transpose_cast<float><<<dim3(2, 32, 16), 256, 0, stream>>>(Wv, WQKVT + 32L * 128 * 2048, 2048, 128, 2048L * 128, 128L * 2048);
    transpose_cast<float><<<dim3(128, 32, 1), 256, 0, stream>>>(W1, W1T, 2048, 8192, 0, 0);
    transpose_cast<float><<<dim3(32, 128, 1), 256, 0, stream>>>(W2, W2T, 8192, 2048, 0, 0);

    // 2. QKV projections: single batched launch, z=48
    gemm_bt<0><<<dim3(1, 16, 48), 256, 0, stream>>>(XBF, WQKVT, QKV, bq, bk, bv,
                                                    2048, 128, 2048, 2048, 0, 128L * 2048, 2048L * 128);

    // 3. V -> V^T per head
    transpose_cast<__hip_bfloat16><<<dim3(2, 32, 16), 256, 0, stream>>>(
        (const __hip_bfloat16*)(QKV + 32L * 2048 * 128), VT, 2048, 128, 2048L * 128, 128L * 2048);

    // 4. attention (256 blocks x 8 waves, 16 q-rows/wave, 2 waves/SIMD)
    attn_flash<<<256, 512, 0, stream>>>(QKV, QKV + 16L * 2048 * 128, VT, ATTN);

    // 5. Add & LN 1
    add_ln<true><<<2048, 256, 0, stream>>>(X, ATTN, alpha1, beta1, H1, H1BF);

    // 6. FFN (FFN2 split-K=4)
    gemm_bt<1><<<dim3(64, 16, 1), 256, 0, stream>>>(H1BF, W1T, G, b1, nullptr, nullptr,
                                                    2048, 8192, 2048, 2048, 0, 0, 0);
    gemm_bt<3><<<dim3(16, 16, 4), 256, 0, stream>>>(G, W2T, F4, nullptr, nullptr, nullptr,
                                                    2048, 2048, 8192, 2048, 0, 0, 2048L * 2048);

    // 7. Add + reduce + LN 2 -> output
    add_ln2_red<<<2048, 256, 0, stream>>>(H1, F4, b2, alpha2, beta2, out);
}

// Round 6
// 481.968 us; speedup vs baseline: 1.3119x; 1.3119x over previous
//
#include <hip/hip_runtime.h>
#include <hip/hip_bf16.h>

#define N_TOK 2048
#define DMODEL 2048
#define NH 16
#define DK 128
#define DFF 8192

typedef __attribute__((ext_vector_type(8))) short short8;
typedef __attribute__((ext_vector_type(4))) short s16x4;
typedef __attribute__((ext_vector_type(4))) float f32x4;

__device__ __forceinline__ short f2bf(float f) {
    unsigned int x = __builtin_bit_cast(unsigned int, f);
    unsigned int r = (x + 0x7fffu + ((x >> 16) & 1u)) >> 16;
    return (short)r;
}

// ---------------- cast X (f32 -> bf16), 8 elems/thread ----------------
__global__ __launch_bounds__(256) void cast_f32_bf16(const float* __restrict__ in,
                                                     short* __restrict__ out, int n8) {
    int i = blockIdx.x * 256 + threadIdx.x;
    if (i >= n8) return;
    const float4* p = (const float4*)in + (size_t)i * 2;
    float4 a = p[0], b = p[1];
    short8 o;
    o[0] = f2bf(a.x); o[1] = f2bf(a.y); o[2] = f2bf(a.z); o[3] = f2bf(a.w);
    o[4] = f2bf(b.x); o[5] = f2bf(b.y); o[6] = f2bf(b.z); o[7] = f2bf(b.w);
    *(short8*)(out + (size_t)i * 8) = o;
}

// ---------------- transpose + cast to bf16 (64x64 LDS tiles) ----------------
template <typename TIN>
__global__ __launch_bounds__(256) void transpose_cast(const TIN* __restrict__ in,
                                                      short* __restrict__ out,
                                                      int R, int C, long sIn, long sOut) {
    __shared__ float t[64][65];
    in  += (long)blockIdx.z * sIn;
    out += (long)blockIdx.z * sOut;
    int tx = threadIdx.x & 63, ty = threadIdx.x >> 6;
    long r0 = (long)blockIdx.y * 64, c0 = (long)blockIdx.x * 64;
    for (int i = 0; i < 16; i++) {
        int r = ty + i * 4;
        t[r][tx] = (float)in[(r0 + r) * (long)C + c0 + tx];
    }
    __syncthreads();
    for (int i = 0; i < 16; i++) {
        int r = ty + i * 4;
        out[(c0 + r) * (long)R + r0 + tx] = f2bf(t[tx][r]);
    }
}

// ---------------- async global->LDS helper ----------------
__device__ __forceinline__ void gld_lds16(const void* g, void* l) {
    __builtin_amdgcn_global_load_lds(
        (const __attribute__((address_space(1))) void*)g,
        (__attribute__((address_space(3))) void*)l, 16, 0, 0);
}

// ---------------- bf16 GEMM, B pre-transposed ([n][k]) -------------------
// 128x128 tile, 4 waves (2x2 of 64x64), BK=32, m97 structure.
template <int MODE>
__global__ __launch_bounds__(256) void gemm_bt(const short* __restrict__ A,
                                               const short* __restrict__ Bt,
                                               void* __restrict__ Cv,
                                               const float* __restrict__ bias,
                                               const float* __restrict__ bias2,
                                               const float* __restrict__ bias3,
                                               int M, int N, int K, int Kloop,
                                               long sA, long sB, long sC) {
    __shared__ short As[128 * 32];
    __shared__ short Bs[128 * 32];
    const int tid = threadIdx.x;
    const int lane = tid & 63, w = tid >> 6;
    const long z = blockIdx.z;
    const float* bp = bias;
    if (MODE == 0) {
        int sel = (int)(z >> 4);
        bp = (sel == 0 ? bias : sel == 1 ? bias2 : bias3) + (z & 15) * 128;
        Bt += z * sB;
    } else if (MODE == 3) {
        A += z * (long)Kloop;
        Bt += z * (long)Kloop;
    } else {
        A += z * sA; Bt += z * sB;
    }
    const long brow = (long)blockIdx.y * 128, bcol = (long)blockIdx.x * 128;

    const int srow = w * 32 + (lane >> 2);
    const int koff = (lane & 3) * 8;
    const short* ga0 = A  + (brow + srow) * (long)K + koff;
    const short* ga1 = ga0 + 16L * K;
    const short* gb0 = Bt + (bcol + srow) * (long)K + koff;
    const short* gb1 = gb0 + 16L * K;
    short* lA0 = As + (w * 2 + 0) * 512;
    short* lA1 = As + (w * 2 + 1) * 512;
    short* lB0 = Bs + (w * 2 + 0) * 512;
    short* lB1 = Bs + (w * 2 + 1) * 512;

    const int wr = w >> 1, wc = w & 1;
    const int fr = lane & 15, fq = lane >> 4;
    f32x4 acc[4][4] = {};

    for (int k0 = 0; k0 < Kloop; k0 += 32) {
        gld_lds16(ga0, lA0); gld_lds16(ga1, lA1);
        gld_lds16(gb0, lB0); gld_lds16(gb1, lB1);
        ga0 += 32; ga1 += 32; gb0 += 32; gb1 += 32;
        __syncthreads();
        short8 af[4], bf[4];
#pragma unroll
        for (int m = 0; m < 4; m++)
            af[m] = *(const short8*)(As + (wr * 64 + m * 16 + fr) * 32 + fq * 8);
#pragma unroll
        for (int n = 0; n < 4; n++)
            bf[n] = *(const short8*)(Bs + (wc * 64 + n * 16 + fr) * 32 + fq * 8);
#pragma unroll
        for (int m = 0; m < 4; m++)
#pragma unroll
            for (int n = 0; n < 4; n++)
                acc[m][n] = __builtin_amdgcn_mfma_f32_16x16x32_bf16(af[m], bf[n], acc[m][n], 0, 0, 0);
        __syncthreads();
    }

    const long crow0 = brow + wr * 64, ccol0 = bcol + wc * 64;
#pragma unroll
    for (int n = 0; n < 4; n++) {
        long col = ccol0 + n * 16 + fr;
        float bv = (MODE == 3) ? 0.f : bp[col];
#pragma unroll
        for (int m = 0; m < 4; m++) {
#pragma unroll
            for (int r = 0; r < 4; r++) {
                long row = crow0 + m * 16 + fq * 4 + r;
                float v = acc[m][n][r] + bv;
                if (MODE == 1) v = fmaxf(v, 0.f);
                if (MODE == 3)
                    ((float*)Cv)[z * sC + row * (long)N + col] = v;
                else
                    ((short*)Cv)[z * sC + row * (long)N + col] = f2bf(v);
            }
        }
    }
}

// ---------------- flash attention v5: LDS-staged K/V shared by 8 waves ------
// Q,K: [H][N][DK] bf16.  VT: [H][DK][N] bf16.  O: [N][DMODEL] f32.
// 256 blocks x 512 thr. Block = (h, 128 q-rows). K dbuf(32K)+V(16K)+P(16K)=64KB.
// K/V staged via global_load_lds with inverse-swizzled GLOBAL source (linear
// LDS dest, rule #21); frag reads XOR ((row&7)<<4) -> conflict-free b128.
__global__ __launch_bounds__(512, 2) void attn_flash(const short* __restrict__ Q,
                                                     const short* __restrict__ Kc,
                                                     const short* __restrict__ VT,
                                                     float* __restrict__ O) {
    __shared__ short lds[32768];           // 64 KB: K0[8192] K1[8192] V[8192] P[8][1024]
    const int tid = threadIdx.x, lane = tid & 63, w = tid >> 6;
    const int bid = blockIdx.x;
    const int vid = (bid & 7) * 32 + (bid >> 3);   // XCD-chunked swizzle (256%8==0)
    const int h = vid >> 4, qt = vid & 15;
    const int fr = lane & 15, fq = lane >> 4;
    const long qbase = (long)qt * 128 + w * 16;
    const short* Qh = Q  + (long)h * N_TOK * DK;
    const short* Kh = Kc + (long)h * N_TOK * DK;
    const short* Vh = VT + (long)h * DK * N_TOK;
    short* Pw = lds + 24576 + w * 1024;

    // Q fragments (B-operand of swapped QK)
    short8 qf[4];
#pragma unroll
    for (int c = 0; c < 4; c++)
        qf[c] = *(const short8*)(Qh + (qbase + fr) * DK + c * 32 + fq * 8);

    float mrow = -1e30f, lrow = 0.f;
    f32x4 oacc[8] = {};
    const float C1 = 0.08838834764831845f * 1.4426950408889634f; // 1/sqrt(128)*log2e

    // P-bounce offsets (shorts, involution swizzle)
    int wr_off[4], rd_off[2];
#pragma unroll
    for (int jc = 0; jc < 4; jc++)
        wr_off[jc] = (fr * 64 + jc * 16 + fq * 4) ^ ((fr & 7) << 3);
#pragma unroll
    for (int kc = 0; kc < 2; kc++)
        rd_off[kc] = (fr * 64 + kc * 32 + fq * 8) ^ ((fr & 7) << 3);
    // K/V fragment column-byte offsets (loop-invariant, swizzled)
    int colKb[4], colVb[2];
#pragma unroll
    for (int c = 0; c < 4; c++) colKb[c] = (c * 64 + fq * 16) ^ ((fr & 7) << 4);
#pragma unroll
    for (int kc = 0; kc < 2; kc++) colVb[kc] = (kc * 64 + fq * 16) ^ ((fr & 7) << 4);

    // staging helpers: LDS dest linear (wave-uniform base, HW adds lane*16);
    // global src carries the inverse swizzle. No pointer arrays (addrspace!).
    auto stageK = [&](int kvt, int buf) {
        const char* Kg = (const char*)(Kh + (long)kvt * 64 * DK);  // 16KB contiguous
        char* Kd = (char*)(lds + buf * 8192);
#pragma unroll
        for (int i = 0; i < 2; i++) {
            int a = (w * 2 + i) * 1024 + (lane << 4);
            int src = a ^ (((a >> 8) & 7) << 4);
            gld_lds16(Kg + src, Kd + (w * 2 + i) * 1024);
        }
    };
    auto stageV = [&](int kvt) {
        char* Vd = (char*)(lds + 16384);
#pragma unroll
        for (int i = 0; i < 2; i++) {
            int a = (w * 2 + i) * 1024 + (lane << 4);
            int row = a >> 7;                              // 0..127
            int inner = (a & 127) ^ ((row & 7) << 4);
            const char* src = (const char*)Vh + ((long)row * N_TOK + (long)kvt * 64) * 2 + inner;
            gld_lds16(src, Vd + (w * 2 + i) * 1024);
        }
    };

    const int NT = N_TOK / 64;   // 32
    stageK(0, 0);
    __syncthreads();             // K(0) ready

    for (int t = 0; t < NT; t++) {
        const int cur = t & 1;
        // issue this tile's V + next tile's K (overlap with QK+softmax)
        stageV(t);
        if (t + 1 < NT) stageK(t + 1, cur ^ 1);

        // S^T = K . Q^T from LDS K[cur]
        const char* Kcb = (const char*)(lds + cur * 8192);
        f32x4 s[4] = {};
#pragma unroll
        for (int jc = 0; jc < 4; jc++) {
            const char* rb = Kcb + (jc * 16 + fr) * 256;
#pragma unroll
            for (int c = 0; c < 4; c++) {
                short8 kf = *(const short8*)(rb + colKb[c]);
                s[jc] = __builtin_amdgcn_mfma_f32_16x16x32_bf16(kf, qf[c], s[jc], 0, 0, 0);
            }
        }

        // online softmax: lane owns q-row fr, 16 key-scores in-register
        float tm = -1e30f;
#pragma unroll
        for (int jc = 0; jc < 4; jc++)
#pragma unroll
            for (int r = 0; r < 4; r++) tm = fmaxf(tm, s[jc][r]);
        tm = fmaxf(tm, __shfl_xor(tm, 16));
        tm = fmaxf(tm, __shfl_xor(tm, 32));
        float nm = fmaxf(mrow, tm);
        float resc = exp2f(C1 * (mrow - nm));
        mrow = nm;
        float sum = 0.f;
#pragma unroll
        for (int jc = 0; jc < 4; jc++)
#pragma unroll
            for (int r = 0; r < 4; r++) {
                float p = exp2f(C1 * (s[jc][r] - nm));
                s[jc][r] = p;
                sum += p;
            }
        sum += __shfl_xor(sum, 16);
        sum += __shfl_xor(sum, 32);
        lrow = lrow * resc + sum;
#pragma unroll
        for (int f = 0; f < 8; f++)
#pragma unroll
            for (int r = 0; r < 4; r++) oacc[f][r] *= resc;

        // P bounce through per-wave LDS region
#pragma unroll
        for (int jc = 0; jc < 4; jc++) {
            s16x4 pk;
            pk[0] = f2bf(s[jc][0]); pk[1] = f2bf(s[jc][1]);
            pk[2] = f2bf(s[jc][2]); pk[3] = f2bf(s[jc][3]);
            *(s16x4*)(Pw + wr_off[jc]) = pk;
        }
        short8 pa[2];
#pragma unroll
        for (int kc = 0; kc < 2; kc++)
            pa[kc] = *(const short8*)(Pw + rd_off[kc]);

        __syncthreads();   // V(t) staged by all waves -> ready

        // O^T += V^T . P^T from LDS V
        const char* Vcb = (const char*)(lds + 16384);
#pragma unroll
        for (int f = 0; f < 8; f++) {
            const char* rb = Vcb + (f * 16 + fr) * 128;
#pragma unroll
            for (int kc = 0; kc < 2; kc++) {
                short8 vf = *(const short8*)(rb + colVb[kc]);
                oacc[f] = __builtin_amdgcn_mfma_f32_16x16x32_bf16(vf, pa[kc], oacc[f], 0, 0, 0);
            }
        }
        __syncthreads();   // all PV reads done -> V/K[cur] reusable
    }

    const float inv = 1.f / lrow;
    const long row = qbase + fr;
#pragma unroll
    for (int f = 0; f < 8; f++) {
        float4 o;
        o.x = oacc[f][0] * inv; o.y = oacc[f][1] * inv;
        o.z = oacc[f][2] * inv; o.w = oacc[f][3] * inv;
        *(float4*)(O + row * (long)DMODEL + h * DK + f * 16 + fq * 4) = o;
    }
}

// ---------------- fused Add + LayerNorm (1 block = 1 row of 2048) -----------
template <bool WBF>
__global__ __launch_bounds__(256) void add_ln(const float* __restrict__ A,
                                              const float* __restrict__ B,
                                              const float* __restrict__ alpha,
                                              const float* __restrict__ beta,
                                              float* __restrict__ out,
                                              short* __restrict__ outbf) {
    const int row = blockIdx.x, t = threadIdx.x;
    const long base = (long)row * DMODEL;
    float4 va[2], vb[2];
    float s = 0.f, q = 0.f;
#pragma unroll
    for (int i = 0; i < 2; i++) {
        long off = base + (long)(t + i * 256) * 4;
        va[i] = *(const float4*)(A + off);
        vb[i] = *(const float4*)(B + off);
        float x0 = va[i].x + vb[i].x, x1 = va[i].y + vb[i].y;
        float x2 = va[i].z + vb[i].z, x3 = va[i].w + vb[i].w;
        s += x0 + x1 + x2 + x3;
        q += x0 * x0 + x1 * x1 + x2 * x2 + x3 * x3;
    }
#pragma unroll
    for (int o = 1; o < 64; o <<= 1) { s += __shfl_xor(s, o); q += __shfl_xor(q, o); }
    __shared__ float red[8];
    if ((t & 63) == 0) { red[t >> 6] = s; red[4 + (t >> 6)] = q; }
    __syncthreads();
    s = red[0] + red[1] + red[2] + red[3];
    q = red[4] + red[5] + red[6] + red[7];
    const float mean = s * (1.f / DMODEL);
    const float var = q * (1.f / DMODEL) - mean * mean;
    const float rstd = rsqrtf(var + 1e-5f);
#pragma unroll
    for (int i = 0; i < 2; i++) {
        long off = base + (long)(t + i * 256) * 4;
        float4 al = *(const float4*)(alpha + off);
        float4 be = *(const float4*)(beta + off);
        float x[4] = { va[i].x + vb[i].x, va[i].y + vb[i].y, va[i].z + vb[i].z, va[i].w + vb[i].w };
        float a[4] = { al.x, al.y, al.z, al.w };
        float b[4] = { be.x, be.y, be.z, be.w };
#pragma unroll
        for (int j = 0; j < 4; j++) {
            float o2 = (x[j] - mean) * rstd * a[j] + b[j];
            out[off + j] = o2;
            if (WBF) outbf[off + j] = f2bf(o2);
        }
    }
}

// ---------------- Add + LN2 with 4-slab split-K reduction + bias ------------
__global__ __launch_bounds__(256) void add_ln2_red(const float* __restrict__ H1,
                                                   const float* __restrict__ F4,
                                                   const float* __restrict__ b2,
                                                   const float* __restrict__ alpha,
                                                   const float* __restrict__ beta,
                                                   float* __restrict__ out) {
    const int row = blockIdx.x, t = threadIdx.x;
    const long base = (long)row * DMODEL;
    const long SL = (long)N_TOK * DMODEL;
    float x[8];
    float s = 0.f, q = 0.f;
#pragma unroll
    for (int i = 0; i < 2; i++) {
        long off = base + (long)(t + i * 256) * 4;
        int col = (t + i * 256) * 4;
        float4 a  = *(const float4*)(H1 + off);
        float4 f0 = *(const float4*)(F4 + off);
        float4 f1 = *(const float4*)(F4 + off + SL);
        float4 f2 = *(const float4*)(F4 + off + 2 * SL);
        float4 f3 = *(const float4*)(F4 + off + 3 * SL);
        float4 bb = *(const float4*)(b2 + col);
        x[i * 4 + 0] = a.x + f0.x + f1.x + f2.x + f3.x + bb.x;
        x[i * 4 + 1] = a.y + f0.y + f1.y + f2.y + f3.y + bb.y;
        x[i * 4 + 2] = a.z + f0.z + f1.z + f2.z + f3.z + bb.z;
        x[i * 4 + 3] = a.w + f0.w + f1.w + f2.w + f3.w + bb.w;
#pragma unroll
        for (int j = 0; j < 4; j++) { s += x[i * 4 + j]; q += x[i * 4 + j] * x[i * 4 + j]; }
    }
#pragma unroll
    for (int o = 1; o < 64; o <<= 1) { s += __shfl_xor(s, o); q += __shfl_xor(q, o); }
    __shared__ float red[8];
    if ((t & 63) == 0) { red[t >> 6] = s; red[4 + (t >> 6)] = q; }
    __syncthreads();
    s = red[0] + red[1] + red[2] + red[3];
    q = red[4] + red[5] + red[6] + red[7];
    const float mean = s * (1.f / DMODEL);
    const float var = q * (1.f / DMODEL) - mean * mean;
    const float rstd = rsqrtf(var + 1e-5f);
#pragma unroll
    for (int i = 0; i < 2; i++) {
        long off = base + (long)(t + i * 256) * 4;
        float4 al = *(const float4*)(alpha + off);
        float4 be = *(const float4*)(beta + off);
        float a[4] = { al.x, al.y, al.z, al.w };
        float b[4] = { be.x, be.y, be.z, be.w };
#pragma unroll
        for (int j = 0; j < 4; j++)
            out[off + j] = (x[i * 4 + j] - mean) * rstd * a[j] + b[j];
    }
}

extern "C" void kernel_launch(void* const* d_in, const int* in_sizes, int n_in,
                              void* d_out, int out_size, void* d_ws, size_t ws_size,
                              hipStream_t stream) {
    const float* X      = (const float*)d_in[0];
    const float* Wq     = (const float*)d_in[1];
    const float* bq     = (const float*)d_in[2];
    const float* Wk     = (const float*)d_in[3];
    const float* bk     = (const float*)d_in[4];
    const float* Wv     = (const float*)d_in[5];
    const float* bv     = (const float*)d_in[6];
    const float* alpha1 = (const float*)d_in[7];
    const float* beta1  = (const float*)d_in[8];
    const float* W1     = (const float*)d_in[9];
    const float* b1     = (const float*)d_in[10];
    const float* W2     = (const float*)d_in[11];
    const float* b2     = (const float*)d_in[12];
    const float* alpha2 = (const float*)d_in[13];
    const float* beta2  = (const float*)d_in[14];
    float* out = (float*)d_out;

    char* ws = (char*)d_ws;
    size_t off = 0;
    auto alloc = [&](size_t bytes) -> void* {
        void* p = ws + off;
        off += (bytes + 255) & ~(size_t)255;
        return p;
    };
    short* XBF   = (short*)alloc(2048UL * 2048 * 2);       // dead after QKV gemm
    short* WQKVT = (short*)alloc(48UL * 128 * 2048 * 2);   // dead after QKV gemm
    short* W1T   = (short*)alloc(8192UL * 2048 * 2);       // dead after FFN1
    short* W2T   = (short*)alloc(2048UL * 8192 * 2);
    short* QKV   = (short*)alloc(48UL * 2048 * 128 * 2);   // Q(0-15),K(16-31),V(32-47)
    short* VT    = (short*)alloc(16UL * 128 * 2048 * 2);
    float* ATTN  = (float*)alloc(2048UL * 2048 * 4);
    float* H1    = (float*)alloc(2048UL * 2048 * 4);
    short* H1BF  = (short*)alloc(2048UL * 2048 * 2);
    short* G     = (short*)alloc(2048UL * 8192 * 2);
    // F4 (64 MB, 4 split-K f32 slabs) aliases XBF+WQKVT+W1T (all dead by FFN2)
    float* F4 = (float*)XBF;

    // 1. casts / transposes
    cast_f32_bf16<<<2048, 256, 0, stream>>>(X, XBF, 2048 * 2048 / 8);
    transpose_cast<float><<<dim3(2, 32, 16), 256, 0, stream>>>(Wq, WQKVT,                    2048, 128, 2048L * 128, 128L * 2048);
    transpose_cast<float><<<dim3(2, 32, 16), 256, 0, stream>>>(Wk, WQKVT + 16L * 128 * 2048, 2048, 128, 2048L * 128, 128L * 2048);
    transpose_cast<float><<<dim3(2, 32, 16), 256, 0, stream>>>(Wv, WQKVT + 32L * 128 * 2048, 2048, 128, 2048L * 128, 128L * 2048);
    transpose_cast<float><<<dim3(128, 32, 1), 256, 0, stream>>>(W1, W1T, 2048, 8192, 0, 0);
    transpose_cast<float><<<dim3(32, 128, 1), 256, 0, stream>>>(W2, W2T, 8192, 2048, 0, 0);

    // 2. QKV projections: single batched launch, z=48
    gemm_bt<0><<<dim3(1, 16, 48), 256, 0, stream>>>(XBF, WQKVT, QKV, bq, bk, bv,
                                                    2048, 128, 2048, 2048, 0, 128L * 2048, 2048L * 128);

    // 3. V -> V^T per head
    transpose_cast<__hip_bfloat16><<<dim3(2, 32, 16), 256, 0, stream>>>(
        (const __hip_bfloat16*)(QKV + 32L * 2048 * 128), VT, 2048, 128, 2048L * 128, 128L * 2048);

    // 4. attention (256 blocks x 8 waves; LDS-staged K/V)
    attn_flash<<<256, 512, 0, stream>>>(QKV, QKV + 16L * 2048 * 128, VT, ATTN);

    // 5. Add & LN 1
    add_ln<true><<<2048, 256, 0, stream>>>(X, ATTN, alpha1, beta1, H1, H1BF);

    // 6. FFN (FFN2 split-K=4)
    gemm_bt<1><<<dim3(64, 16, 1), 256, 0, stream>>>(H1BF, W1T, G, b1, nullptr, nullptr,
                                                    2048, 8192, 2048, 2048, 0, 0, 0);
    gemm_bt<3><<<dim3(16, 16, 4), 256, 0, stream>>>(G, W2T, F4, nullptr, nullptr, nullptr,
                                                    2048, 2048, 8192, 2048, 0, 0, 2048L * 2048);

    // 7. Add + reduce + LN 2 -> output
    add_ln2_red<<<2048, 256, 0, stream>>>(H1, F4, b2, alpha2, beta2, out);
}

// Round 7
// 401.816 us; speedup vs baseline: 1.5736x; 1.1995x over previous
//
#include <hip/hip_runtime.h>
#include <hip/hip_bf16.h>

#define N_TOK 2048
#define DMODEL 2048
#define NH 16
#define DK 128
#define DFF 8192

typedef __attribute__((ext_vector_type(8))) short short8;
typedef __attribute__((ext_vector_type(4))) short s16x4;
typedef __attribute__((ext_vector_type(4))) float f32x4;

__device__ __forceinline__ short f2bf(float f) {
    unsigned int x = __builtin_bit_cast(unsigned int, f);
    unsigned int r = (x + 0x7fffu + ((x >> 16) & 1u)) >> 16;
    return (short)r;
}

// ---------------- cast X (f32 -> bf16), 8 elems/thread ----------------
__global__ __launch_bounds__(256) void cast_f32_bf16(const float* __restrict__ in,
                                                     short* __restrict__ out, int n8) {
    int i = blockIdx.x * 256 + threadIdx.x;
    if (i >= n8) return;
    const float4* p = (const float4*)in + (size_t)i * 2;
    float4 a = p[0], b = p[1];
    short8 o;
    o[0] = f2bf(a.x); o[1] = f2bf(a.y); o[2] = f2bf(a.z); o[3] = f2bf(a.w);
    o[4] = f2bf(b.x); o[5] = f2bf(b.y); o[6] = f2bf(b.z); o[7] = f2bf(b.w);
    *(short8*)(out + (size_t)i * 8) = o;
}

// ---------------- transpose + cast to bf16 (64x64 LDS tiles) ----------------
template <typename TIN>
__global__ __launch_bounds__(256) void transpose_cast(const TIN* __restrict__ in,
                                                      short* __restrict__ out,
                                                      int R, int C, long sIn, long sOut) {
    __shared__ float t[64][65];
    in  += (long)blockIdx.z * sIn;
    out += (long)blockIdx.z * sOut;
    int tx = threadIdx.x & 63, ty = threadIdx.x >> 6;
    long r0 = (long)blockIdx.y * 64, c0 = (long)blockIdx.x * 64;
    for (int i = 0; i < 16; i++) {
        int r = ty + i * 4;
        t[r][tx] = (float)in[(r0 + r) * (long)C + c0 + tx];
    }
    __syncthreads();
    for (int i = 0; i < 16; i++) {
        int r = ty + i * 4;
        out[(c0 + r) * (long)R + r0 + tx] = f2bf(t[tx][r]);
    }
}

// ---------------- async global->LDS helper ----------------
__device__ __forceinline__ void gld_lds16(const void* g, void* l) {
    __builtin_amdgcn_global_load_lds(
        (const __attribute__((address_space(1))) void*)g,
        (__attribute__((address_space(3))) void*)l, 16, 0, 0);
}

// ======== 256x256 bf16 GEMM, BK=32, 8 waves, 4-deep counted-vmcnt ring ======
// B pre-transposed [n][k]. LDS 128 KB: 4 bufs x (A[256][32] + B[256][32]).
// Frag reads swizzled (col ^ ((fr&3)<<4)) -> conflict-free b128; staging
// carries inverse swizzle on the GLOBAL source (linear LDS dest).
// MODE 0: QKV fused N=6144, bias per 2048-col group, bf16 slab output
// MODE 1: FFN1 N=8192, +bias, ReLU, bf16
// MODE 2: FFN2 split-K slab z (Kloop=2048 of Ktot), f32 slab output
template <int MODE>
__global__ __launch_bounds__(512, 2) void gemm256(const short* __restrict__ A,
                                                  const short* __restrict__ Bt,
                                                  void* __restrict__ Cv,
                                                  const float* __restrict__ b0,
                                                  const float* __restrict__ b1,
                                                  const float* __restrict__ b2,
                                                  int Ktot, int TM) {
    __shared__ short lds[65536];   // 128 KB
    const int tid = threadIdx.x, lane = tid & 63, w = tid >> 6;
    const int T = gridDim.x;
    const int bid = blockIdx.x;
    const int vbid = (bid & 7) * (T >> 3) + (bid >> 3);   // XCD chunking
    const int mt = vbid % TM;
    const int rest = vbid / TM;
    int nt = rest, z = 0;
    if (MODE == 2) { nt = rest & 7; z = rest >> 3; }
    const long brow = (long)mt * 256, bcol = (long)nt * 256;
    const short* Ab = A + (MODE == 2 ? (long)z * 2048 : 0);
    const short* Bb = Bt + (MODE == 2 ? (long)z * 2048 : 0);

    const int NT = 2048 / 32;   // 64 K-tiles (Kloop = 2048 in all modes)

    auto stage = [&](int t) {
        const int buf = t & 3;
        char* db = (char*)lds + buf * 32768;
        const long k0 = (long)t * 32;
#pragma unroll
        for (int i = 0; i < 2; i++) {
            int a = i * 8192 + w * 1024 + (lane << 4);
            int row = a >> 6;
            int colb = (a & 63) ^ ((row & 3) << 4);
            gld_lds16((const char*)(Ab + (brow + row) * (long)Ktot + k0) + colb,
                      db + i * 8192 + w * 1024);
            gld_lds16((const char*)(Bb + (bcol + row) * (long)Ktot + k0) + colb,
                      db + 16384 + i * 8192 + w * 1024);
        }
    };

    const int wr = w >> 2, wc = w & 3;          // 2 x 4 wave grid (128 x 64 out)
    const int fr = lane & 15, fq = lane >> 4;
    const int fcol = (fq * 16) ^ ((fr & 3) << 4);
    f32x4 acc[8][4] = {};

    stage(0); stage(1); stage(2);
    asm volatile("s_waitcnt vmcnt(8)" ::: "memory");
    __builtin_amdgcn_s_barrier();

    for (int t = 0; t < NT; t++) {
        if (t + 3 < NT) stage(t + 3);
        const char* Abuf = (const char*)lds + (t & 3) * 32768;
        const char* Bbuf = Abuf + 16384;
        short8 af[8], bf[4];
#pragma unroll
        for (int m = 0; m < 8; m++)
            af[m] = *(const short8*)(Abuf + (wr * 128 + m * 16 + fr) * 64 + fcol);
#pragma unroll
        for (int n = 0; n < 4; n++)
            bf[n] = *(const short8*)(Bbuf + (wc * 64 + n * 16 + fr) * 64 + fcol);
#pragma unroll
        for (int m = 0; m < 8; m++)
#pragma unroll
            for (int n = 0; n < 4; n++)
                acc[m][n] = __builtin_amdgcn_mfma_f32_16x16x32_bf16(af[m], bf[n], acc[m][n], 0, 0, 0);
        // counted waits: ensure tile t+1 staged before crossing the barrier
        if (t + 3 < NT)      asm volatile("s_waitcnt vmcnt(8)" ::: "memory");
        else if (t + 2 < NT) asm volatile("s_waitcnt vmcnt(4)" ::: "memory");
        else if (t + 1 < NT) asm volatile("s_waitcnt vmcnt(0)" ::: "memory");
        __builtin_amdgcn_sched_barrier(0);
        __builtin_amdgcn_s_barrier();
        __builtin_amdgcn_sched_barrier(0);
    }

    const long crow0 = brow + wr * 128, ccol0 = bcol + wc * 64;
#pragma unroll
    for (int n = 0; n < 4; n++) {
        const long col = ccol0 + n * 16 + fr;
        float bval = 0.f;
        if (MODE == 0) {
            const float* bp = (col >> 11) == 0 ? b0 : (col >> 11) == 1 ? b1 : b2;
            bval = bp[col & 2047];
        } else if (MODE == 1) bval = b0[col];
#pragma unroll
        for (int m = 0; m < 8; m++) {
#pragma unroll
            for (int r = 0; r < 4; r++) {
                const long row = crow0 + m * 16 + fq * 4 + r;
                float v = acc[m][n][r] + bval;
                if (MODE == 0) {
                    const long slab = col >> 7;
                    ((short*)Cv)[slab * (2048L * 128) + row * 128 + (col & 127)] = f2bf(v);
                } else if (MODE == 1) {
                    ((short*)Cv)[row * 8192 + col] = f2bf(fmaxf(v, 0.f));
                } else {
                    ((float*)Cv)[(long)z * (2048L * 2048) + row * 2048 + col] = v;
                }
            }
        }
    }
}

// ---------------- flash attention v5: LDS-staged K/V shared by 8 waves ------
__global__ __launch_bounds__(512, 2) void attn_flash(const short* __restrict__ Q,
                                                     const short* __restrict__ Kc,
                                                     const short* __restrict__ VT,
                                                     float* __restrict__ O) {
    __shared__ short lds[32768];           // 64 KB: K0[8192] K1[8192] V[8192] P[8][1024]
    const int tid = threadIdx.x, lane = tid & 63, w = tid >> 6;
    const int bid = blockIdx.x;
    const int vid = (bid & 7) * 32 + (bid >> 3);   // XCD-chunked swizzle (256%8==0)
    const int h = vid >> 4, qt = vid & 15;
    const int fr = lane & 15, fq = lane >> 4;
    const long qbase = (long)qt * 128 + w * 16;
    const short* Qh = Q  + (long)h * N_TOK * DK;
    const short* Kh = Kc + (long)h * N_TOK * DK;
    const short* Vh = VT + (long)h * DK * N_TOK;
    short* Pw = lds + 24576 + w * 1024;

    short8 qf[4];
#pragma unroll
    for (int c = 0; c < 4; c++)
        qf[c] = *(const short8*)(Qh + (qbase + fr) * DK + c * 32 + fq * 8);

    float mrow = -1e30f, lrow = 0.f;
    f32x4 oacc[8] = {};
    const float C1 = 0.08838834764831845f * 1.4426950408889634f; // 1/sqrt(128)*log2e

    int wr_off[4], rd_off[2];
#pragma unroll
    for (int jc = 0; jc < 4; jc++)
        wr_off[jc] = (fr * 64 + jc * 16 + fq * 4) ^ ((fr & 7) << 3);
#pragma unroll
    for (int kc = 0; kc < 2; kc++)
        rd_off[kc] = (fr * 64 + kc * 32 + fq * 8) ^ ((fr & 7) << 3);
    int colKb[4], colVb[2];
#pragma unroll
    for (int c = 0; c < 4; c++) colKb[c] = (c * 64 + fq * 16) ^ ((fr & 7) << 4);
#pragma unroll
    for (int kc = 0; kc < 2; kc++) colVb[kc] = (kc * 64 + fq * 16) ^ ((fr & 7) << 4);

    auto stageK = [&](int kvt, int buf) {
        const char* Kg = (const char*)(Kh + (long)kvt * 64 * DK);
        char* Kd = (char*)(lds + buf * 8192);
#pragma unroll
        for (int i = 0; i < 2; i++) {
            int a = (w * 2 + i) * 1024 + (lane << 4);
            int src = a ^ (((a >> 8) & 7) << 4);
            gld_lds16(Kg + src, Kd + (w * 2 + i) * 1024);
        }
    };
    auto stageV = [&](int kvt) {
        char* Vd = (char*)(lds + 16384);
#pragma unroll
        for (int i = 0; i < 2; i++) {
            int a = (w * 2 + i) * 1024 + (lane << 4);
            int row = a >> 7;
            int inner = (a & 127) ^ ((row & 7) << 4);
            const char* src = (const char*)Vh + ((long)row * N_TOK + (long)kvt * 64) * 2 + inner;
            gld_lds16(src, Vd + (w * 2 + i) * 1024);
        }
    };

    const int NT = N_TOK / 64;
    stageK(0, 0);
    __syncthreads();

    for (int t = 0; t < NT; t++) {
        const int cur = t & 1;
        stageV(t);
        if (t + 1 < NT) stageK(t + 1, cur ^ 1);

        const char* Kcb = (const char*)(lds + cur * 8192);
        f32x4 s[4] = {};
#pragma unroll
        for (int jc = 0; jc < 4; jc++) {
            const char* rb = Kcb + (jc * 16 + fr) * 256;
#pragma unroll
            for (int c = 0; c < 4; c++) {
                short8 kf = *(const short8*)(rb + colKb[c]);
                s[jc] = __builtin_amdgcn_mfma_f32_16x16x32_bf16(kf, qf[c], s[jc], 0, 0, 0);
            }
        }

        float tm = -1e30f;
#pragma unroll
        for (int jc = 0; jc < 4; jc++)
#pragma unroll
            for (int r = 0; r < 4; r++) tm = fmaxf(tm, s[jc][r]);
        tm = fmaxf(tm, __shfl_xor(tm, 16));
        tm = fmaxf(tm, __shfl_xor(tm, 32));
        float nm = fmaxf(mrow, tm);
        float resc = exp2f(C1 * (mrow - nm));
        mrow = nm;
        float sum = 0.f;
#pragma unroll
        for (int jc = 0; jc < 4; jc++)
#pragma unroll
            for (int r = 0; r < 4; r++) {
                float p = exp2f(C1 * (s[jc][r] - nm));
                s[jc][r] = p;
                sum += p;
            }
        sum += __shfl_xor(sum, 16);
        sum += __shfl_xor(sum, 32);
        lrow = lrow * resc + sum;
#pragma unroll
        for (int f = 0; f < 8; f++)
#pragma unroll
            for (int r = 0; r < 4; r++) oacc[f][r] *= resc;

#pragma unroll
        for (int jc = 0; jc < 4; jc++) {
            s16x4 pk;
            pk[0] = f2bf(s[jc][0]); pk[1] = f2bf(s[jc][1]);
            pk[2] = f2bf(s[jc][2]); pk[3] = f2bf(s[jc][3]);
            *(s16x4*)(Pw + wr_off[jc]) = pk;
        }
        short8 pa[2];
#pragma unroll
        for (int kc = 0; kc < 2; kc++)
            pa[kc] = *(const short8*)(Pw + rd_off[kc]);

        __syncthreads();

        const char* Vcb = (const char*)(lds + 16384);
#pragma unroll
        for (int f = 0; f < 8; f++) {
            const char* rb = Vcb + (f * 16 + fr) * 128;
#pragma unroll
            for (int kc = 0; kc < 2; kc++) {
                short8 vf = *(const short8*)(rb + colVb[kc]);
                oacc[f] = __builtin_amdgcn_mfma_f32_16x16x32_bf16(vf, pa[kc], oacc[f], 0, 0, 0);
            }
        }
        __syncthreads();
    }

    const float inv = 1.f / lrow;
    const long row = qbase + fr;
#pragma unroll
    for (int f = 0; f < 8; f++) {
        float4 o;
        o.x = oacc[f][0] * inv; o.y = oacc[f][1] * inv;
        o.z = oacc[f][2] * inv; o.w = oacc[f][3] * inv;
        *(float4*)(O + row * (long)DMODEL + h * DK + f * 16 + fq * 4) = o;
    }
}

// ---------------- fused Add + LayerNorm (1 block = 1 row of 2048) -----------
template <bool WBF>
__global__ __launch_bounds__(256) void add_ln(const float* __restrict__ A,
                                              const float* __restrict__ B,
                                              const float* __restrict__ alpha,
                                              const float* __restrict__ beta,
                                              float* __restrict__ out,
                                              short* __restrict__ outbf) {
    const int row = blockIdx.x, t = threadIdx.x;
    const long base = (long)row * DMODEL;
    float4 va[2], vb[2];
    float s = 0.f, q = 0.f;
#pragma unroll
    for (int i = 0; i < 2; i++) {
        long off = base + (long)(t + i * 256) * 4;
        va[i] = *(const float4*)(A + off);
        vb[i] = *(const float4*)(B + off);
        float x0 = va[i].x + vb[i].x, x1 = va[i].y + vb[i].y;
        float x2 = va[i].z + vb[i].z, x3 = va[i].w + vb[i].w;
        s += x0 + x1 + x2 + x3;
        q += x0 * x0 + x1 * x1 + x2 * x2 + x3 * x3;
    }
#pragma unroll
    for (int o = 1; o < 64; o <<= 1) { s += __shfl_xor(s, o); q += __shfl_xor(q, o); }
    __shared__ float red[8];
    if ((t & 63) == 0) { red[t >> 6] = s; red[4 + (t >> 6)] = q; }
    __syncthreads();
    s = red[0] + red[1] + red[2] + red[3];
    q = red[4] + red[5] + red[6] + red[7];
    const float mean = s * (1.f / DMODEL);
    const float var = q * (1.f / DMODEL) - mean * mean;
    const float rstd = rsqrtf(var + 1e-5f);
#pragma unroll
    for (int i = 0; i < 2; i++) {
        long off = base + (long)(t + i * 256) * 4;
        float4 al = *(const float4*)(alpha + off);
        float4 be = *(const float4*)(beta + off);
        float x[4] = { va[i].x + vb[i].x, va[i].y + vb[i].y, va[i].z + vb[i].z, va[i].w + vb[i].w };
        float a[4] = { al.x, al.y, al.z, al.w };
        float b[4] = { be.x, be.y, be.z, be.w };
#pragma unroll
        for (int j = 0; j < 4; j++) {
            float o2 = (x[j] - mean) * rstd * a[j] + b[j];
            out[off + j] = o2;
            if (WBF) outbf[off + j] = f2bf(o2);
        }
    }
}

// ---------------- Add + LN2 with 4-slab split-K reduction + bias ------------
__global__ __launch_bounds__(256) void add_ln2_red(const float* __restrict__ H1,
                                                   const float* __restrict__ F4,
                                                   const float* __restrict__ b2,
                                                   const float* __restrict__ alpha,
                                                   const float* __restrict__ beta,
                                                   float* __restrict__ out) {
    const int row = blockIdx.x, t = threadIdx.x;
    const long base = (long)row * DMODEL;
    const long SL = (long)N_TOK * DMODEL;
    float x[8];
    float s = 0.f, q = 0.f;
#pragma unroll
    for (int i = 0; i < 2; i++) {
        long off = base + (long)(t + i * 256) * 4;
        int col = (t + i * 256) * 4;
        float4 a  = *(const float4*)(H1 + off);
        float4 f0 = *(const float4*)(F4 + off);
        float4 f1 = *(const float4*)(F4 + off + SL);
        float4 f2 = *(const float4*)(F4 + off + 2 * SL);
        float4 f3 = *(const float4*)(F4 + off + 3 * SL);
        float4 bb = *(const float4*)(b2 + col);
        x[i * 4 + 0] = a.x + f0.x + f1.x + f2.x + f3.x + bb.x;
        x[i * 4 + 1] = a.y + f0.y + f1.y + f2.y + f3.y + bb.y;
        x[i * 4 + 2] = a.z + f0.z + f1.z + f2.z + f3.z + bb.z;
        x[i * 4 + 3] = a.w + f0.w + f1.w + f2.w + f3.w + bb.w;
#pragma unroll
        for (int j = 0; j < 4; j++) { s += x[i * 4 + j]; q += x[i * 4 + j] * x[i * 4 + j]; }
    }
#pragma unroll
    for (int o = 1; o < 64; o <<= 1) { s += __shfl_xor(s, o); q += __shfl_xor(q, o); }
    __shared__ float red[8];
    if ((t & 63) == 0) { red[t >> 6] = s; red[4 + (t >> 6)] = q; }
    __syncthreads();
    s = red[0] + red[1] + red[2] + red[3];
    q = red[4] + red[5] + red[6] + red[7];
    const float mean = s * (1.f / DMODEL);
    const float var = q * (1.f / DMODEL) - mean * mean;
    const float rstd = rsqrtf(var + 1e-5f);
#pragma unroll
    for (int i = 0; i < 2; i++) {
        long off = base + (long)(t + i * 256) * 4;
        float4 al = *(const float4*)(alpha + off);
        float4 be = *(const float4*)(beta + off);
        float a[4] = { al.x, al.y, al.z, al.w };
        float b[4] = { be.x, be.y, be.z, be.w };
#pragma unroll
        for (int j = 0; j < 4; j++)
            out[off + j] = (x[i * 4 + j] - mean) * rstd * a[j] + b[j];
    }
}

extern "C" void kernel_launch(void* const* d_in, const int* in_sizes, int n_in,
                              void* d_out, int out_size, void* d_ws, size_t ws_size,
                              hipStream_t stream) {
    const float* X      = (const float*)d_in[0];
    const float* Wq     = (const float*)d_in[1];
    const float* bq     = (const float*)d_in[2];
    const float* Wk     = (const float*)d_in[3];
    const float* bk     = (const float*)d_in[4];
    const float* Wv     = (const float*)d_in[5];
    const float* bv     = (const float*)d_in[6];
    const float* alpha1 = (const float*)d_in[7];
    const float* beta1  = (const float*)d_in[8];
    const float* W1     = (const float*)d_in[9];
    const float* b1     = (const float*)d_in[10];
    const float* W2     = (const float*)d_in[11];
    const float* b2     = (const float*)d_in[12];
    const float* alpha2 = (const float*)d_in[13];
    const float* beta2  = (const float*)d_in[14];
    float* out = (float*)d_out;

    char* ws = (char*)d_ws;
    size_t off = 0;
    auto alloc = [&](size_t bytes) -> void* {
        void* p = ws + off;
        off += (bytes + 255) & ~(size_t)255;
        return p;
    };
    short* XBF   = (short*)alloc(2048UL * 2048 * 2);       // dead after QKV gemm
    short* WQKVT = (short*)alloc(48UL * 128 * 2048 * 2);   // = [6144][2048]; dead after QKV
    short* W1T   = (short*)alloc(8192UL * 2048 * 2);       // dead after FFN1
    short* W2T   = (short*)alloc(2048UL * 8192 * 2);
    short* QKV   = (short*)alloc(48UL * 2048 * 128 * 2);   // Q(0-15),K(16-31),V(32-47)
    short* VT    = (short*)alloc(16UL * 128 * 2048 * 2);
    float* ATTN  = (float*)alloc(2048UL * 2048 * 4);
    float* H1    = (float*)alloc(2048UL * 2048 * 4);
    short* H1BF  = (short*)alloc(2048UL * 2048 * 2);
    short* G     = (short*)alloc(2048UL * 8192 * 2);
    // F4 (64 MB, 4 split-K f32 slabs) aliases XBF+WQKVT+W1T (all dead by FFN2)
    float* F4 = (float*)XBF;

    // 1. casts / transposes
    cast_f32_bf16<<<2048, 256, 0, stream>>>(X, XBF, 2048 * 2048 / 8);
    transpose_cast<float><<<dim3(2, 32, 16), 256, 0, stream>>>(Wq, WQKVT,                    2048, 128, 2048L * 128, 128L * 2048);
    transpose_cast<float><<<dim3(2, 32, 16), 256, 0, stream>>>(Wk, WQKVT + 16L * 128 * 2048, 2048, 128, 2048L * 128, 128L * 2048);
    transpose_cast<float><<<dim3(2, 32, 16), 256, 0, stream>>>(Wv, WQKVT + 32L * 128 * 2048, 2048, 128, 2048L * 128, 128L * 2048);
    transpose_cast<float><<<dim3(128, 32, 1), 256, 0, stream>>>(W1, W1T, 2048, 8192, 0, 0);
    transpose_cast<float><<<dim3(32, 128, 1), 256, 0, stream>>>(W2, W2T, 8192, 2048, 0, 0);

    // 2. QKV fused GEMM: M=2048, N=6144 (TM=8, TN=24 -> 192 blocks)
    gemm256<0><<<192, 512, 0, stream>>>(XBF, WQKVT, QKV, bq, bk, bv, 2048, 8);

    // 3. V -> V^T per head
    transpose_cast<__hip_bfloat16><<<dim3(2, 32, 16), 256, 0, stream>>>(
        (const __hip_bfloat16*)(QKV + 32L * 2048 * 128), VT, 2048, 128, 2048L * 128, 128L * 2048);

    // 4. attention (256 blocks x 8 waves; LDS-staged K/V)
    attn_flash<<<256, 512, 0, stream>>>(QKV, QKV + 16L * 2048 * 128, VT, ATTN);

    // 5. Add & LN 1
    add_ln<true><<<2048, 256, 0, stream>>>(X, ATTN, alpha1, beta1, H1, H1BF);

    // 6. FFN: FFN1 M=2048 N=8192 (256 blocks); FFN2 split-K=4 (256 blocks)
    gemm256<1><<<256, 512, 0, stream>>>(H1BF, W1T, G, b1, nullptr, nullptr, 2048, 8);
    gemm256<2><<<256, 512, 0, stream>>>(G, W2T, F4, nullptr, nullptr, nullptr, 8192, 8);

    // 7. Add + reduce + LN 2 -> output
    add_ln2_red<<<2048, 256, 0, stream>>>(H1, F4, b2, alpha2, beta2, out);
}

// Round 8
// 394.712 us; speedup vs baseline: 1.6019x; 1.0180x over previous
//
#include <hip/hip_runtime.h>
#include <hip/hip_bf16.h>

#define N_TOK 2048
#define DMODEL 2048
#define NH 16
#define DK 128
#define DFF 8192

typedef __attribute__((ext_vector_type(8))) short short8;
typedef __attribute__((ext_vector_type(4))) short s16x4;
typedef __attribute__((ext_vector_type(4))) float f32x4;

__device__ __forceinline__ short f2bf(float f) {
    unsigned int x = __builtin_bit_cast(unsigned int, f);
    unsigned int r = (x + 0x7fffu + ((x >> 16) & 1u)) >> 16;
    return (short)r;
}

// ---------------- cast X (f32 -> bf16), 8 elems/thread ----------------
__global__ __launch_bounds__(256) void cast_f32_bf16(const float* __restrict__ in,
                                                     short* __restrict__ out, int n8) {
    int i = blockIdx.x * 256 + threadIdx.x;
    if (i >= n8) return;
    const float4* p = (const float4*)in + (size_t)i * 2;
    float4 a = p[0], b = p[1];
    short8 o;
    o[0] = f2bf(a.x); o[1] = f2bf(a.y); o[2] = f2bf(a.z); o[3] = f2bf(a.w);
    o[4] = f2bf(b.x); o[5] = f2bf(b.y); o[6] = f2bf(b.z); o[7] = f2bf(b.w);
    *(short8*)(out + (size_t)i * 8) = o;
}

// ---------------- transpose + cast to bf16 (64x64 LDS tiles) ----------------
template <typename TIN>
__global__ __launch_bounds__(256) void transpose_cast(const TIN* __restrict__ in,
                                                      short* __restrict__ out,
                                                      int R, int C, long sIn, long sOut) {
    __shared__ float t[64][65];
    in  += (long)blockIdx.z * sIn;
    out += (long)blockIdx.z * sOut;
    int tx = threadIdx.x & 63, ty = threadIdx.x >> 6;
    long r0 = (long)blockIdx.y * 64, c0 = (long)blockIdx.x * 64;
    for (int i = 0; i < 16; i++) {
        int r = ty + i * 4;
        t[r][tx] = (float)in[(r0 + r) * (long)C + c0 + tx];
    }
    __syncthreads();
    for (int i = 0; i < 16; i++) {
        int r = ty + i * 4;
        out[(c0 + r) * (long)R + r0 + tx] = f2bf(t[tx][r]);
    }
}

// ---------------- async global->LDS helper ----------------
__device__ __forceinline__ void gld_lds16(const void* g, void* l) {
    __builtin_amdgcn_global_load_lds(
        (const __attribute__((address_space(1))) void*)g,
        (__attribute__((address_space(3))) void*)l, 16, 0, 0);
}

// ======== 256x256 bf16 GEMM, BK=32, 8 waves, 4-deep counted-vmcnt ring ======
// B pre-transposed [n][k]. LDS 128 KB: 4 bufs x (A[256][32] + B[256][32]).
// Swizzle: col granule XOR ((row>>1)&3) -> 2 lanes/16B-slot (conflict-free);
// staging carries inverse on the GLOBAL source (linear LDS dest).
template <int MODE>
__global__ __launch_bounds__(512, 2) void gemm256(const short* __restrict__ A,
                                                  const short* __restrict__ Bt,
                                                  void* __restrict__ Cv,
                                                  const float* __restrict__ b0,
                                                  const float* __restrict__ b1,
                                                  const float* __restrict__ b2,
                                                  int Ktot, int TM) {
    __shared__ short lds[65536];   // 128 KB
    const int tid = threadIdx.x, lane = tid & 63, w = tid >> 6;
    const int T = gridDim.x;
    const int bid = blockIdx.x;
    const int vbid = (bid & 7) * (T >> 3) + (bid >> 3);   // XCD chunking
    const int mt = vbid % TM;
    const int rest = vbid / TM;
    int nt = rest, z = 0;
    if (MODE == 2) { nt = rest & 7; z = rest >> 3; }
    const long brow = (long)mt * 256, bcol = (long)nt * 256;
    const short* Ab = A + (MODE == 2 ? (long)z * 2048 : 0);
    const short* Bb = Bt + (MODE == 2 ? (long)z * 2048 : 0);

    const int NT = 2048 / 32;   // 64 K-tiles (Kloop = 2048 in all modes)

    auto stage = [&](int t) {
        const int buf = t & 3;
        char* db = (char*)lds + buf * 32768;
        const long k0 = (long)t * 32;
#pragma unroll
        for (int i = 0; i < 2; i++) {
            int a = i * 8192 + w * 1024 + (lane << 4);
            int row = a >> 6;
            int colb = (a & 63) ^ (((row >> 1) & 3) << 4);
            gld_lds16((const char*)(Ab + (brow + row) * (long)Ktot + k0) + colb,
                      db + i * 8192 + w * 1024);
            gld_lds16((const char*)(Bb + (bcol + row) * (long)Ktot + k0) + colb,
                      db + 16384 + i * 8192 + w * 1024);
        }
    };

    const int wr = w >> 2, wc = w & 3;          // 2 x 4 wave grid (128 x 64 out)
    const int fr = lane & 15, fq = lane >> 4;
    const int fcol = (fq * 16) ^ (((fr >> 1) & 3) << 4);
    f32x4 acc[8][4] = {};

    stage(0); stage(1); stage(2);
    asm volatile("s_waitcnt vmcnt(8)" ::: "memory");
    __builtin_amdgcn_s_barrier();

    for (int t = 0; t < NT; t++) {
        if (t + 3 < NT) stage(t + 3);
        const char* Abuf = (const char*)lds + (t & 3) * 32768;
        const char* Bbuf = Abuf + 16384;
        short8 af[8], bf[4];
#pragma unroll
        for (int m = 0; m < 8; m++)
            af[m] = *(const short8*)(Abuf + (wr * 128 + m * 16 + fr) * 64 + fcol);
#pragma unroll
        for (int n = 0; n < 4; n++)
            bf[n] = *(const short8*)(Bbuf + (wc * 64 + n * 16 + fr) * 64 + fcol);
        __builtin_amdgcn_s_setprio(1);
#pragma unroll
        for (int m = 0; m < 8; m++)
#pragma unroll
            for (int n = 0; n < 4; n++)
                acc[m][n] = __builtin_amdgcn_mfma_f32_16x16x32_bf16(af[m], bf[n], acc[m][n], 0, 0, 0);
        __builtin_amdgcn_s_setprio(0);
        // counted waits: ensure tile t+1 staged before crossing the barrier
        if (t + 3 < NT)      asm volatile("s_waitcnt vmcnt(8)" ::: "memory");
        else if (t + 2 < NT) asm volatile("s_waitcnt vmcnt(4)" ::: "memory");
        else if (t + 1 < NT) asm volatile("s_waitcnt vmcnt(0)" ::: "memory");
        __builtin_amdgcn_sched_barrier(0);
        __builtin_amdgcn_s_barrier();
        __builtin_amdgcn_sched_barrier(0);
    }

    const long crow0 = brow + wr * 128, ccol0 = bcol + wc * 64;
#pragma unroll
    for (int n = 0; n < 4; n++) {
        const long col = ccol0 + n * 16 + fr;
        float bval = 0.f;
        if (MODE == 0) {
            const float* bp = (col >> 11) == 0 ? b0 : (col >> 11) == 1 ? b1 : b2;
            bval = bp[col & 2047];
        } else if (MODE == 1) bval = b0[col];
#pragma unroll
        for (int m = 0; m < 8; m++) {
#pragma unroll
            for (int r = 0; r < 4; r++) {
                const long row = crow0 + m * 16 + fq * 4 + r;
                float v = acc[m][n][r] + bval;
                if (MODE == 0) {
                    const long slab = col >> 7;
                    ((short*)Cv)[slab * (2048L * 128) + row * 128 + (col & 127)] = f2bf(v);
                } else if (MODE == 1) {
                    ((short*)Cv)[row * 8192 + col] = f2bf(fmaxf(v, 0.f));
                } else {
                    ((float*)Cv)[(long)z * (2048L * 2048) + row * 2048 + col] = v;
                }
            }
        }
    }
}

// ---------------- flash attention v5: LDS-staged K/V shared by 8 waves ------
__global__ __launch_bounds__(512, 2) void attn_flash(const short* __restrict__ Q,
                                                     const short* __restrict__ Kc,
                                                     const short* __restrict__ VT,
                                                     float* __restrict__ O) {
    __shared__ short lds[32768];           // 64 KB: K0[8192] K1[8192] V[8192] P[8][1024]
    const int tid = threadIdx.x, lane = tid & 63, w = tid >> 6;
    const int bid = blockIdx.x;
    const int vid = (bid & 7) * 32 + (bid >> 3);   // XCD-chunked swizzle (256%8==0)
    const int h = vid >> 4, qt = vid & 15;
    const int fr = lane & 15, fq = lane >> 4;
    const long qbase = (long)qt * 128 + w * 16;
    const short* Qh = Q  + (long)h * N_TOK * DK;
    const short* Kh = Kc + (long)h * N_TOK * DK;
    const short* Vh = VT + (long)h * DK * N_TOK;
    short* Pw = lds + 24576 + w * 1024;

    short8 qf[4];
#pragma unroll
    for (int c = 0; c < 4; c++)
        qf[c] = *(const short8*)(Qh + (qbase + fr) * DK + c * 32 + fq * 8);

    float mrow = -1e30f, lrow = 0.f;
    f32x4 oacc[8] = {};
    const float C1 = 0.08838834764831845f * 1.4426950408889634f; // 1/sqrt(128)*log2e

    int wr_off[4], rd_off[2];
#pragma unroll
    for (int jc = 0; jc < 4; jc++)
        wr_off[jc] = (fr * 64 + jc * 16 + fq * 4) ^ ((fr & 7) << 3);
#pragma unroll
    for (int kc = 0; kc < 2; kc++)
        rd_off[kc] = (fr * 64 + kc * 32 + fq * 8) ^ ((fr & 7) << 3);
    int colKb[4], colVb[2];
#pragma unroll
    for (int c = 0; c < 4; c++) colKb[c] = (c * 64 + fq * 16) ^ ((fr & 7) << 4);
#pragma unroll
    for (int kc = 0; kc < 2; kc++) colVb[kc] = (kc * 64 + fq * 16) ^ ((fr & 7) << 4);

    auto stageK = [&](int kvt, int buf) {
        const char* Kg = (const char*)(Kh + (long)kvt * 64 * DK);
        char* Kd = (char*)(lds + buf * 8192);
#pragma unroll
        for (int i = 0; i < 2; i++) {
            int a = (w * 2 + i) * 1024 + (lane << 4);
            int src = a ^ (((a >> 8) & 7) << 4);
            gld_lds16(Kg + src, Kd + (w * 2 + i) * 1024);
        }
    };
    auto stageV = [&](int kvt) {
        char* Vd = (char*)(lds + 16384);
#pragma unroll
        for (int i = 0; i < 2; i++) {
            int a = (w * 2 + i) * 1024 + (lane << 4);
            int row = a >> 7;
            int inner = (a & 127) ^ ((row & 7) << 4);
            const char* src = (const char*)Vh + ((long)row * N_TOK + (long)kvt * 64) * 2 + inner;
            gld_lds16(src, Vd + (w * 2 + i) * 1024);
        }
    };

    const int NT = N_TOK / 64;
    stageK(0, 0);
    __syncthreads();

    for (int t = 0; t < NT; t++) {
        const int cur = t & 1;
        stageV(t);
        if (t + 1 < NT) stageK(t + 1, cur ^ 1);

        const char* Kcb = (const char*)(lds + cur * 8192);
        f32x4 s[4] = {};
#pragma unroll
        for (int jc = 0; jc < 4; jc++) {
            const char* rb = Kcb + (jc * 16 + fr) * 256;
#pragma unroll
            for (int c = 0; c < 4; c++) {
                short8 kf = *(const short8*)(rb + colKb[c]);
                s[jc] = __builtin_amdgcn_mfma_f32_16x16x32_bf16(kf, qf[c], s[jc], 0, 0, 0);
            }
        }

        float tm = -1e30f;
#pragma unroll
        for (int jc = 0; jc < 4; jc++)
#pragma unroll
            for (int r = 0; r < 4; r++) tm = fmaxf(tm, s[jc][r]);
        tm = fmaxf(tm, __shfl_xor(tm, 16));
        tm = fmaxf(tm, __shfl_xor(tm, 32));
        float nm = fmaxf(mrow, tm);
        float resc = exp2f(C1 * (mrow - nm));
        mrow = nm;
        float sum = 0.f;
#pragma unroll
        for (int jc = 0; jc < 4; jc++)
#pragma unroll
            for (int r = 0; r < 4; r++) {
                float p = exp2f(C1 * (s[jc][r] - nm));
                s[jc][r] = p;
                sum += p;
            }
        sum += __shfl_xor(sum, 16);
        sum += __shfl_xor(sum, 32);
        lrow = lrow * resc + sum;
#pragma unroll
        for (int f = 0; f < 8; f++)
#pragma unroll
            for (int r = 0; r < 4; r++) oacc[f][r] *= resc;

#pragma unroll
        for (int jc = 0; jc < 4; jc++) {
            s16x4 pk;
            pk[0] = f2bf(s[jc][0]); pk[1] = f2bf(s[jc][1]);
            pk[2] = f2bf(s[jc][2]); pk[3] = f2bf(s[jc][3]);
            *(s16x4*)(Pw + wr_off[jc]) = pk;
        }
        short8 pa[2];
#pragma unroll
        for (int kc = 0; kc < 2; kc++)
            pa[kc] = *(const short8*)(Pw + rd_off[kc]);

        __syncthreads();

        const char* Vcb = (const char*)(lds + 16384);
#pragma unroll
        for (int f = 0; f < 8; f++) {
            const char* rb = Vcb + (f * 16 + fr) * 128;
#pragma unroll
            for (int kc = 0; kc < 2; kc++) {
                short8 vf = *(const short8*)(rb + colVb[kc]);
                oacc[f] = __builtin_amdgcn_mfma_f32_16x16x32_bf16(vf, pa[kc], oacc[f], 0, 0, 0);
            }
        }
        __syncthreads();
    }

    const float inv = 1.f / lrow;
    const long row = qbase + fr;
#pragma unroll
    for (int f = 0; f < 8; f++) {
        float4 o;
        o.x = oacc[f][0] * inv; o.y = oacc[f][1] * inv;
        o.z = oacc[f][2] * inv; o.w = oacc[f][3] * inv;
        *(float4*)(O + row * (long)DMODEL + h * DK + f * 16 + fq * 4) = o;
    }
}

// ---------------- fused Add + LayerNorm (1 block = 1 row of 2048) -----------
template <bool WBF>
__global__ __launch_bounds__(256) void add_ln(const float* __restrict__ A,
                                              const float* __restrict__ B,
                                              const float* __restrict__ alpha,
                                              const float* __restrict__ beta,
                                              float* __restrict__ out,
                                              short* __restrict__ outbf) {
    const int row = blockIdx.x, t = threadIdx.x;
    const long base = (long)row * DMODEL;
    float4 va[2], vb[2];
    float s = 0.f, q = 0.f;
#pragma unroll
    for (int i = 0; i < 2; i++) {
        long off = base + (long)(t + i * 256) * 4;
        va[i] = *(const float4*)(A + off);
        vb[i] = *(const float4*)(B + off);
        float x0 = va[i].x + vb[i].x, x1 = va[i].y + vb[i].y;
        float x2 = va[i].z + vb[i].z, x3 = va[i].w + vb[i].w;
        s += x0 + x1 + x2 + x3;
        q += x0 * x0 + x1 * x1 + x2 * x2 + x3 * x3;
    }
#pragma unroll
    for (int o = 1; o < 64; o <<= 1) { s += __shfl_xor(s, o); q += __shfl_xor(q, o); }
    __shared__ float red[8];
    if ((t & 63) == 0) { red[t >> 6] = s; red[4 + (t >> 6)] = q; }
    __syncthreads();
    s = red[0] + red[1] + red[2] + red[3];
    q = red[4] + red[5] + red[6] + red[7];
    const float mean = s * (1.f / DMODEL);
    const float var = q * (1.f / DMODEL) - mean * mean;
    const float rstd = rsqrtf(var + 1e-5f);
#pragma unroll
    for (int i = 0; i < 2; i++) {
        long off = base + (long)(t + i * 256) * 4;
        float4 al = *(const float4*)(alpha + off);
        float4 be = *(const float4*)(beta + off);
        float x[4] = { va[i].x + vb[i].x, va[i].y + vb[i].y, va[i].z + vb[i].z, va[i].w + vb[i].w };
        float a[4] = { al.x, al.y, al.z, al.w };
        float b[4] = { be.x, be.y, be.z, be.w };
#pragma unroll
        for (int j = 0; j < 4; j++) {
            float o2 = (x[j] - mean) * rstd * a[j] + b[j];
            out[off + j] = o2;
            if (WBF) outbf[off + j] = f2bf(o2);
        }
    }
}

// ---------------- Add + LN2 with 4-slab split-K reduction + bias ------------
__global__ __launch_bounds__(256) void add_ln2_red(const float* __restrict__ H1,
                                                   const float* __restrict__ F4,
                                                   const float* __restrict__ b2,
                                                   const float* __restrict__ alpha,
                                                   const float* __restrict__ beta,
                                                   float* __restrict__ out) {
    const int row = blockIdx.x, t = threadIdx.x;
    const long base = (long)row * DMODEL;
    const long SL = (long)N_TOK * DMODEL;
    float x[8];
    float s = 0.f, q = 0.f;
#pragma unroll
    for (int i = 0; i < 2; i++) {
        long off = base + (long)(t + i * 256) * 4;
        int col = (t + i * 256) * 4;
        float4 a  = *(const float4*)(H1 + off);
        float4 f0 = *(const float4*)(F4 + off);
        float4 f1 = *(const float4*)(F4 + off + SL);
        float4 f2 = *(const float4*)(F4 + off + 2 * SL);
        float4 f3 = *(const float4*)(F4 + off + 3 * SL);
        float4 bb = *(const float4*)(b2 + col);
        x[i * 4 + 0] = a.x + f0.x + f1.x + f2.x + f3.x + bb.x;
        x[i * 4 + 1] = a.y + f0.y + f1.y + f2.y + f3.y + bb.y;
        x[i * 4 + 2] = a.z + f0.z + f1.z + f2.z + f3.z + bb.z;
        x[i * 4 + 3] = a.w + f0.w + f1.w + f2.w + f3.w + bb.w;
#pragma unroll
        for (int j = 0; j < 4; j++) { s += x[i * 4 + j]; q += x[i * 4 + j] * x[i * 4 + j]; }
    }
#pragma unroll
    for (int o = 1; o < 64; o <<= 1) { s += __shfl_xor(s, o); q += __shfl_xor(q, o); }
    __shared__ float red[8];
    if ((t & 63) == 0) { red[t >> 6] = s; red[4 + (t >> 6)] = q; }
    __syncthreads();
    s = red[0] + red[1] + red[2] + red[3];
    q = red[4] + red[5] + red[6] + red[7];
    const float mean = s * (1.f / DMODEL);
    const float var = q * (1.f / DMODEL) - mean * mean;
    const float rstd = rsqrtf(var + 1e-5f);
#pragma unroll
    for (int i = 0; i < 2; i++) {
        long off = base + (long)(t + i * 256) * 4;
        float4 al = *(const float4*)(alpha + off);
        float4 be = *(const float4*)(beta + off);
        float a[4] = { al.x, al.y, al.z, al.w };
        float b[4] = { be.x, be.y, be.z, be.w };
#pragma unroll
        for (int j = 0; j < 4; j++)
            out[off + j] = (x[i * 4 + j] - mean) * rstd * a[j] + b[j];
    }
}

extern "C" void kernel_launch(void* const* d_in, const int* in_sizes, int n_in,
                              void* d_out, int out_size, void* d_ws, size_t ws_size,
                              hipStream_t stream) {
    const float* X      = (const float*)d_in[0];
    const float* Wq     = (const float*)d_in[1];
    const float* bq     = (const float*)d_in[2];
    const float* Wk     = (const float*)d_in[3];
    const float* bk     = (const float*)d_in[4];
    const float* Wv     = (const float*)d_in[5];
    const float* bv     = (const float*)d_in[6];
    const float* alpha1 = (const float*)d_in[7];
    const float* beta1  = (const float*)d_in[8];
    const float* W1     = (const float*)d_in[9];
    const float* b1     = (const float*)d_in[10];
    const float* W2     = (const float*)d_in[11];
    const float* b2     = (const float*)d_in[12];
    const float* alpha2 = (const float*)d_in[13];
    const float* beta2  = (const float*)d_in[14];
    float* out = (float*)d_out;

    char* ws = (char*)d_ws;
    size_t off = 0;
    auto alloc = [&](size_t bytes) -> void* {
        void* p = ws + off;
        off += (bytes + 255) & ~(size_t)255;
        return p;
    };
    short* XBF   = (short*)alloc(2048UL * 2048 * 2);       // dead after QKV gemm
    short* WQKVT = (short*)alloc(48UL * 128 * 2048 * 2);   // = [6144][2048]; dead after QKV
    short* W1T   = (short*)alloc(8192UL * 2048 * 2);       // dead after FFN1
    short* W2T   = (short*)alloc(2048UL * 8192 * 2);
    short* QKV   = (short*)alloc(48UL * 2048 * 128 * 2);   // Q(0-15),K(16-31),V(32-47)
    short* VT    = (short*)alloc(16UL * 128 * 2048 * 2);
    float* ATTN  = (float*)alloc(2048UL * 2048 * 4);
    float* H1    = (float*)alloc(2048UL * 2048 * 4);
    short* H1BF  = (short*)alloc(2048UL * 2048 * 2);
    short* G     = (short*)alloc(2048UL * 8192 * 2);
    // F4 (64 MB, 4 split-K f32 slabs) aliases XBF+WQKVT+W1T (all dead by FFN2)
    float* F4 = (float*)XBF;

    // 1. casts / transposes
    cast_f32_bf16<<<2048, 256, 0, stream>>>(X, XBF, 2048 * 2048 / 8);
    transpose_cast<float><<<dim3(2, 32, 16), 256, 0, stream>>>(Wq, WQKVT,                    2048, 128, 2048L * 128, 128L * 2048);
    transpose_cast<float><<<dim3(2, 32, 16), 256, 0, stream>>>(Wk, WQKVT + 16L * 128 * 2048, 2048, 128, 2048L * 128, 128L * 2048);
    transpose_cast<float><<<dim3(2, 32, 16), 256, 0, stream>>>(Wv, WQKVT + 32L * 128 * 2048, 2048, 128, 2048L * 128, 128L * 2048);
    transpose_cast<float><<<dim3(128, 32, 1), 256, 0, stream>>>(W1, W1T, 2048, 8192, 0, 0);
    transpose_cast<float><<<dim3(32, 128, 1), 256, 0, stream>>>(W2, W2T, 8192, 2048, 0, 0);

    // 2. QKV fused GEMM: M=2048, N=6144 (TM=8, TN=24 -> 192 blocks)
    gemm256<0><<<192, 512, 0, stream>>>(XBF, WQKVT, QKV, bq, bk, bv, 2048, 8);

    // 3. V -> V^T per head
    transpose_cast<__hip_bfloat16><<<dim3(2, 32, 16), 256, 0, stream>>>(
        (const __hip_bfloat16*)(QKV + 32L * 2048 * 128), VT, 2048, 128, 2048L * 128, 128L * 2048);

    // 4. attention (256 blocks x 8 waves; LDS-staged K/V)
    attn_flash<<<256, 512, 0, stream>>>(QKV, QKV + 16L * 2048 * 128, VT, ATTN);

    // 5. Add & LN 1
    add_ln<true><<<2048, 256, 0, stream>>>(X, ATTN, alpha1, beta1, H1, H1BF);

    // 6. FFN: FFN1 M=2048 N=8192 (256 blocks); FFN2 split-K=4 (256 blocks)
    gemm256<1><<<256, 512, 0, stream>>>(H1BF, W1T, G, b1, nullptr, nullptr, 2048, 8);
    gemm256<2><<<256, 512, 0, stream>>>(G, W2T, F4, nullptr, nullptr, nullptr, 8192, 8);

    // 7. Add + reduce + LN 2 -> output
    add_ln2_red<<<2048, 256, 0, stream>>>(H1, F4, b2, alpha2, beta2, out);
}

// Round 9
// 393.458 us; speedup vs baseline: 1.6070x; 1.0032x over previous
//
#include <hip/hip_runtime.h>
#include <hip/hip_bf16.h>

#define N_TOK 2048
#define DMODEL 2048
#define NH 16
#define DK 128
#define DFF 8192

typedef __attribute__((ext_vector_type(8))) short short8;
typedef __attribute__((ext_vector_type(4))) short s16x4;
typedef __attribute__((ext_vector_type(4))) float f32x4;

__device__ __forceinline__ short f2bf(float f) {
    unsigned int x = __builtin_bit_cast(unsigned int, f);
    unsigned int r = (x + 0x7fffu + ((x >> 16) & 1u)) >> 16;
    return (short)r;
}

// ---------------- cast X (f32 -> bf16), 8 elems/thread ----------------
__global__ __launch_bounds__(256) void cast_f32_bf16(const float* __restrict__ in,
                                                     short* __restrict__ out, int n8) {
    int i = blockIdx.x * 256 + threadIdx.x;
    if (i >= n8) return;
    const float4* p = (const float4*)in + (size_t)i * 2;
    float4 a = p[0], b = p[1];
    short8 o;
    o[0] = f2bf(a.x); o[1] = f2bf(a.y); o[2] = f2bf(a.z); o[3] = f2bf(a.w);
    o[4] = f2bf(b.x); o[5] = f2bf(b.y); o[6] = f2bf(b.z); o[7] = f2bf(b.w);
    *(short8*)(out + (size_t)i * 8) = o;
}

// ---------------- transpose + cast to bf16 (64x64 LDS tiles) ----------------
template <typename TIN>
__global__ __launch_bounds__(256) void transpose_cast(const TIN* __restrict__ in,
                                                      short* __restrict__ out,
                                                      int R, int C, long sIn, long sOut) {
    __shared__ float t[64][65];
    in  += (long)blockIdx.z * sIn;
    out += (long)blockIdx.z * sOut;
    int tx = threadIdx.x & 63, ty = threadIdx.x >> 6;
    long r0 = (long)blockIdx.y * 64, c0 = (long)blockIdx.x * 64;
    for (int i = 0; i < 16; i++) {
        int r = ty + i * 4;
        t[r][tx] = (float)in[(r0 + r) * (long)C + c0 + tx];
    }
    __syncthreads();
    for (int i = 0; i < 16; i++) {
        int r = ty + i * 4;
        out[(c0 + r) * (long)R + r0 + tx] = f2bf(t[tx][r]);
    }
}

// ---------------- async global->LDS helper ----------------
__device__ __forceinline__ void gld_lds16(const void* g, void* l) {
    __builtin_amdgcn_global_load_lds(
        (const __attribute__((address_space(1))) void*)g,
        (__attribute__((address_space(3))) void*)l, 16, 0, 0);
}

// ======== 256x256 bf16 GEMM, BK=32, 8 waves, 4-deep ring + reg dbuf =========
// B pre-transposed [n][k]. LDS 128 KB: 4 bufs x (A[256][32] + B[256][32]).
// Swizzle: col granule XOR ((row>>1)&3); staging carries inverse on the
// GLOBAL source (linear LDS dest). Fragments register-double-buffered:
// iter t MFMAs set(t) while ds_reading set(t+1) -> LDS hides under MFMA.
template <int MODE>
__global__ __launch_bounds__(512, 2) void gemm256(const short* __restrict__ A,
                                                  const short* __restrict__ Bt,
                                                  void* __restrict__ Cv,
                                                  const float* __restrict__ b0,
                                                  const float* __restrict__ b1,
                                                  const float* __restrict__ b2,
                                                  int Ktot, int TM) {
    __shared__ short lds[65536];   // 128 KB
    const int tid = threadIdx.x, lane = tid & 63, w = tid >> 6;
    const int T = gridDim.x;
    const int bid = blockIdx.x;
    const int vbid = (bid & 7) * (T >> 3) + (bid >> 3);   // XCD chunking
    const int mt = vbid % TM;
    const int rest = vbid / TM;
    int nt = rest, z = 0;
    if (MODE == 2) { nt = rest & 7; z = rest >> 3; }
    const long brow = (long)mt * 256, bcol = (long)nt * 256;
    const short* Ab = A + (MODE == 2 ? (long)z * 2048 : 0);
    const short* Bb = Bt + (MODE == 2 ? (long)z * 2048 : 0);

    const int NT = 2048 / 32;   // 64 K-tiles (Kloop = 2048 in all modes)

    auto stage = [&](int t) {
        const int buf = t & 3;
        char* db = (char*)lds + buf * 32768;
        const long k0 = (long)t * 32;
#pragma unroll
        for (int i = 0; i < 2; i++) {
            int a = i * 8192 + w * 1024 + (lane << 4);
            int row = a >> 6;
            int colb = (a & 63) ^ (((row >> 1) & 3) << 4);
            gld_lds16((const char*)(Ab + (brow + row) * (long)Ktot + k0) + colb,
                      db + i * 8192 + w * 1024);
            gld_lds16((const char*)(Bb + (bcol + row) * (long)Ktot + k0) + colb,
                      db + 16384 + i * 8192 + w * 1024);
        }
    };

    const int wr = w >> 2, wc = w & 3;          // 2 x 4 wave grid (128 x 64 out)
    const int fr = lane & 15, fq = lane >> 4;
    const int fcol = (fq * 16) ^ (((fr >> 1) & 3) << 4);
    f32x4 acc[8][4] = {};

    auto readFrags = [&](int t, short8* af, short8* bf) {
        const char* Abuf = (const char*)lds + (t & 3) * 32768;
        const char* Bbuf = Abuf + 16384;
#pragma unroll
        for (int m = 0; m < 8; m++)
            af[m] = *(const short8*)(Abuf + (wr * 128 + m * 16 + fr) * 64 + fcol);
#pragma unroll
        for (int n = 0; n < 4; n++)
            bf[n] = *(const short8*)(Bbuf + (wc * 64 + n * 16 + fr) * 64 + fcol);
    };

    stage(0); stage(1); stage(2);
    asm volatile("s_waitcnt vmcnt(4)" ::: "memory");   // drains stage(0),(1)
    __builtin_amdgcn_s_barrier();

    short8 afA[8], bfA[4], afB[8], bfB[4];
    readFrags(0, afA, bfA);

    for (int t = 0; t < NT; t += 2) {
        // ---- even iter: compute set A (tile t), prefetch set B (tile t+1) --
        if (t + 3 < NT) stage(t + 3);
        readFrags(t + 1, afB, bfB);            // buf(t+1) staged & barrier-synced
        __builtin_amdgcn_s_setprio(1);
#pragma unroll
        for (int m = 0; m < 8; m++)
#pragma unroll
            for (int n = 0; n < 4; n++)
                acc[m][n] = __builtin_amdgcn_mfma_f32_16x16x32_bf16(afA[m], bfA[n], acc[m][n], 0, 0, 0);
        __builtin_amdgcn_s_setprio(0);
        if (t + 3 < NT) asm volatile("s_waitcnt vmcnt(4)" ::: "memory");
        else            asm volatile("s_waitcnt vmcnt(0)" ::: "memory");
        __builtin_amdgcn_sched_barrier(0);
        __builtin_amdgcn_s_barrier();
        __builtin_amdgcn_sched_barrier(0);

        // ---- odd iter: compute set B (tile t+1), prefetch set A (tile t+2) -
        if (t + 4 < NT) stage(t + 4);
        if (t + 2 < NT) readFrags(t + 2, afA, bfA);
        __builtin_amdgcn_s_setprio(1);
#pragma unroll
        for (int m = 0; m < 8; m++)
#pragma unroll
            for (int n = 0; n < 4; n++)
                acc[m][n] = __builtin_amdgcn_mfma_f32_16x16x32_bf16(afB[m], bfB[n], acc[m][n], 0, 0, 0);
        __builtin_amdgcn_s_setprio(0);
        if (t + 4 < NT) asm volatile("s_waitcnt vmcnt(4)" ::: "memory");
        else            asm volatile("s_waitcnt vmcnt(0)" ::: "memory");
        __builtin_amdgcn_sched_barrier(0);
        __builtin_amdgcn_s_barrier();
        __builtin_amdgcn_sched_barrier(0);
    }

    const long crow0 = brow + wr * 128, ccol0 = bcol + wc * 64;
#pragma unroll
    for (int n = 0; n < 4; n++) {
        const long col = ccol0 + n * 16 + fr;
        float bval = 0.f;
        if (MODE == 0) {
            const float* bp = (col >> 11) == 0 ? b0 : (col >> 11) == 1 ? b1 : b2;
            bval = bp[col & 2047];
        } else if (MODE == 1) bval = b0[col];
#pragma unroll
        for (int m = 0; m < 8; m++) {
#pragma unroll
            for (int r = 0; r < 4; r++) {
                const long row = crow0 + m * 16 + fq * 4 + r;
                float v = acc[m][n][r] + bval;
                if (MODE == 0) {
                    const long slab = col >> 7;
                    ((short*)Cv)[slab * (2048L * 128) + row * 128 + (col & 127)] = f2bf(v);
                } else if (MODE == 1) {
                    ((short*)Cv)[row * 8192 + col] = f2bf(fmaxf(v, 0.f));
                } else {
                    ((float*)Cv)[(long)z * (2048L * 2048) + row * 2048 + col] = v;
                }
            }
        }
    }
}

// ---------------- flash attention v5: LDS-staged K/V shared by 8 waves ------
__global__ __launch_bounds__(512, 2) void attn_flash(const short* __restrict__ Q,
                                                     const short* __restrict__ Kc,
                                                     const short* __restrict__ VT,
                                                     float* __restrict__ O) {
    __shared__ short lds[32768];           // 64 KB: K0[8192] K1[8192] V[8192] P[8][1024]
    const int tid = threadIdx.x, lane = tid & 63, w = tid >> 6;
    const int bid = blockIdx.x;
    const int vid = (bid & 7) * 32 + (bid >> 3);   // XCD-chunked swizzle (256%8==0)
    const int h = vid >> 4, qt = vid & 15;
    const int fr = lane & 15, fq = lane >> 4;
    const long qbase = (long)qt * 128 + w * 16;
    const short* Qh = Q  + (long)h * N_TOK * DK;
    const short* Kh = Kc + (long)h * N_TOK * DK;
    const short* Vh = VT + (long)h * DK * N_TOK;
    short* Pw = lds + 24576 + w * 1024;

    short8 qf[4];
#pragma unroll
    for (int c = 0; c < 4; c++)
        qf[c] = *(const short8*)(Qh + (qbase + fr) * DK + c * 32 + fq * 8);

    float mrow = -1e30f, lrow = 0.f;
    f32x4 oacc[8] = {};
    const float C1 = 0.08838834764831845f * 1.4426950408889634f; // 1/sqrt(128)*log2e

    int wr_off[4], rd_off[2];
#pragma unroll
    for (int jc = 0; jc < 4; jc++)
        wr_off[jc] = (fr * 64 + jc * 16 + fq * 4) ^ ((fr & 7) << 3);
#pragma unroll
    for (int kc = 0; kc < 2; kc++)
        rd_off[kc] = (fr * 64 + kc * 32 + fq * 8) ^ ((fr & 7) << 3);
    int colKb[4], colVb[2];
#pragma unroll
    for (int c = 0; c < 4; c++) colKb[c] = (c * 64 + fq * 16) ^ ((fr & 7) << 4);
#pragma unroll
    for (int kc = 0; kc < 2; kc++) colVb[kc] = (kc * 64 + fq * 16) ^ ((fr & 7) << 4);

    auto stageK = [&](int kvt, int buf) {
        const char* Kg = (const char*)(Kh + (long)kvt * 64 * DK);
        char* Kd = (char*)(lds + buf * 8192);
#pragma unroll
        for (int i = 0; i < 2; i++) {
            int a = (w * 2 + i) * 1024 + (lane << 4);
            int src = a ^ (((a >> 8) & 7) << 4);
            gld_lds16(Kg + src, Kd + (w * 2 + i) * 1024);
        }
    };
    auto stageV = [&](int kvt) {
        char* Vd = (char*)(lds + 16384);
#pragma unroll
        for (int i = 0; i < 2; i++) {
            int a = (w * 2 + i) * 1024 + (lane << 4);
            int row = a >> 7;
            int inner = (a & 127) ^ ((row & 7) << 4);
            const char* src = (const char*)Vh + ((long)row * N_TOK + (long)kvt * 64) * 2 + inner;
            gld_lds16(src, Vd + (w * 2 + i) * 1024);
        }
    };

    const int NT = N_TOK / 64;
    stageK(0, 0);
    __syncthreads();

    for (int t = 0; t < NT; t++) {
        const int cur = t & 1;
        stageV(t);
        if (t + 1 < NT) stageK(t + 1, cur ^ 1);

        const char* Kcb = (const char*)(lds + cur * 8192);
        f32x4 s[4] = {};
#pragma unroll
        for (int jc = 0; jc < 4; jc++) {
            const char* rb = Kcb + (jc * 16 + fr) * 256;
#pragma unroll
            for (int c = 0; c < 4; c++) {
                short8 kf = *(const short8*)(rb + colKb[c]);
                s[jc] = __builtin_amdgcn_mfma_f32_16x16x32_bf16(kf, qf[c], s[jc], 0, 0, 0);
            }
        }

        float tm = -1e30f;
#pragma unroll
        for (int jc = 0; jc < 4; jc++)
#pragma unroll
            for (int r = 0; r < 4; r++) tm = fmaxf(tm, s[jc][r]);
        tm = fmaxf(tm, __shfl_xor(tm, 16));
        tm = fmaxf(tm, __shfl_xor(tm, 32));
        float nm = fmaxf(mrow, tm);
        float resc = exp2f(C1 * (mrow - nm));
        mrow = nm;
        float sum = 0.f;
#pragma unroll
        for (int jc = 0; jc < 4; jc++)
#pragma unroll
            for (int r = 0; r < 4; r++) {
                float p = exp2f(C1 * (s[jc][r] - nm));
                s[jc][r] = p;
                sum += p;
            }
        sum += __shfl_xor(sum, 16);
        sum += __shfl_xor(sum, 32);
        lrow = lrow * resc + sum;
#pragma unroll
        for (int f = 0; f < 8; f++)
#pragma unroll
            for (int r = 0; r < 4; r++) oacc[f][r] *= resc;

#pragma unroll
        for (int jc = 0; jc < 4; jc++) {
            s16x4 pk;
            pk[0] = f2bf(s[jc][0]); pk[1] = f2bf(s[jc][1]);
            pk[2] = f2bf(s[jc][2]); pk[3] = f2bf(s[jc][3]);
            *(s16x4*)(Pw + wr_off[jc]) = pk;
        }
        short8 pa[2];
#pragma unroll
        for (int kc = 0; kc < 2; kc++)
            pa[kc] = *(const short8*)(Pw + rd_off[kc]);

        __syncthreads();

        const char* Vcb = (const char*)(lds + 16384);
#pragma unroll
        for (int f = 0; f < 8; f++) {
            const char* rb = Vcb + (f * 16 + fr) * 128;
#pragma unroll
            for (int kc = 0; kc < 2; kc++) {
                short8 vf = *(const short8*)(rb + colVb[kc]);
                oacc[f] = __builtin_amdgcn_mfma_f32_16x16x32_bf16(vf, pa[kc], oacc[f], 0, 0, 0);
            }
        }
        __syncthreads();
    }

    const float inv = 1.f / lrow;
    const long row = qbase + fr;
#pragma unroll
    for (int f = 0; f < 8; f++) {
        float4 o;
        o.x = oacc[f][0] * inv; o.y = oacc[f][1] * inv;
        o.z = oacc[f][2] * inv; o.w = oacc[f][3] * inv;
        *(float4*)(O + row * (long)DMODEL + h * DK + f * 16 + fq * 4) = o;
    }
}

// ---------------- fused Add + LayerNorm (1 block = 1 row of 2048) -----------
template <bool WBF>
__global__ __launch_bounds__(256) void add_ln(const float* __restrict__ A,
                                              const float* __restrict__ B,
                                              const float* __restrict__ alpha,
                                              const float* __restrict__ beta,
                                              float* __restrict__ out,
                                              short* __restrict__ outbf) {
    const int row = blockIdx.x, t = threadIdx.x;
    const long base = (long)row * DMODEL;
    float4 va[2], vb[2];
    float s = 0.f, q = 0.f;
#pragma unroll
    for (int i = 0; i < 2; i++) {
        long off = base + (long)(t + i * 256) * 4;
        va[i] = *(const float4*)(A + off);
        vb[i] = *(const float4*)(B + off);
        float x0 = va[i].x + vb[i].x, x1 = va[i].y + vb[i].y;
        float x2 = va[i].z + vb[i].z, x3 = va[i].w + vb[i].w;
        s += x0 + x1 + x2 + x3;
        q += x0 * x0 + x1 * x1 + x2 * x2 + x3 * x3;
    }
#pragma unroll
    for (int o = 1; o < 64; o <<= 1) { s += __shfl_xor(s, o); q += __shfl_xor(q, o); }
    __shared__ float red[8];
    if ((t & 63) == 0) { red[t >> 6] = s; red[4 + (t >> 6)] = q; }
    __syncthreads();
    s = red[0] + red[1] + red[2] + red[3];
    q = red[4] + red[5] + red[6] + red[7];
    const float mean = s * (1.f / DMODEL);
    const float var = q * (1.f / DMODEL) - mean * mean;
    const float rstd = rsqrtf(var + 1e-5f);
#pragma unroll
    for (int i = 0; i < 2; i++) {
        long off = base + (long)(t + i * 256) * 4;
        float4 al = *(const float4*)(alpha + off);
        float4 be = *(const float4*)(beta + off);
        float x[4] = { va[i].x + vb[i].x, va[i].y + vb[i].y, va[i].z + vb[i].z, va[i].w + vb[i].w };
        float a[4] = { al.x, al.y, al.z, al.w };
        float b[4] = { be.x, be.y, be.z, be.w };
#pragma unroll
        for (int j = 0; j < 4; j++) {
            float o2 = (x[j] - mean) * rstd * a[j] + b[j];
            out[off + j] = o2;
            if (WBF) outbf[off + j] = f2bf(o2);
        }
    }
}

// ---------------- Add + LN2 with 4-slab split-K reduction + bias ------------
__global__ __launch_bounds__(256) void add_ln2_red(const float* __restrict__ H1,
                                                   const float* __restrict__ F4,
                                                   const float* __restrict__ b2,
                                                   const float* __restrict__ alpha,
                                                   const float* __restrict__ beta,
                                                   float* __restrict__ out) {
    const int row = blockIdx.x, t = threadIdx.x;
    const long base = (long)row * DMODEL;
    const long SL = (long)N_TOK * DMODEL;
    float x[8];
    float s = 0.f, q = 0.f;
#pragma unroll
    for (int i = 0; i < 2; i++) {
        long off = base + (long)(t + i * 256) * 4;
        int col = (t + i * 256) * 4;
        float4 a  = *(const float4*)(H1 + off);
        float4 f0 = *(const float4*)(F4 + off);
        float4 f1 = *(const float4*)(F4 + off + SL);
        float4 f2 = *(const float4*)(F4 + off + 2 * SL);
        float4 f3 = *(const float4*)(F4 + off + 3 * SL);
        float4 bb = *(const float4*)(b2 + col);
        x[i * 4 + 0] = a.x + f0.x + f1.x + f2.x + f3.x + bb.x;
        x[i * 4 + 1] = a.y + f0.y + f1.y + f2.y + f3.y + bb.y;
        x[i * 4 + 2] = a.z + f0.z + f1.z + f2.z + f3.z + bb.z;
        x[i * 4 + 3] = a.w + f0.w + f1.w + f2.w + f3.w + bb.w;
#pragma unroll
        for (int j = 0; j < 4; j++) { s += x[i * 4 + j]; q += x[i * 4 + j] * x[i * 4 + j]; }
    }
#pragma unroll
    for (int o = 1; o < 64; o <<= 1) { s += __shfl_xor(s, o); q += __shfl_xor(q, o); }
    __shared__ float red[8];
    if ((t & 63) == 0) { red[t >> 6] = s; red[4 + (t >> 6)] = q; }
    __syncthreads();
    s = red[0] + red[1] + red[2] + red[3];
    q = red[4] + red[5] + red[6] + red[7];
    const float mean = s * (1.f / DMODEL);
    const float var = q * (1.f / DMODEL) - mean * mean;
    const float rstd = rsqrtf(var + 1e-5f);
#pragma unroll
    for (int i = 0; i < 2; i++) {
        long off = base + (long)(t + i * 256) * 4;
        float4 al = *(const float4*)(alpha + off);
        float4 be = *(const float4*)(beta + off);
        float a[4] = { al.x, al.y, al.z, al.w };
        float b[4] = { be.x, be.y, be.z, be.w };
#pragma unroll
        for (int j = 0; j < 4; j++)
            out[off + j] = (x[i * 4 + j] - mean) * rstd * a[j] + b[j];
    }
}

extern "C" void kernel_launch(void* const* d_in, const int* in_sizes, int n_in,
                              void* d_out, int out_size, void* d_ws, size_t ws_size,
                              hipStream_t stream) {
    const float* X      = (const float*)d_in[0];
    const float* Wq     = (const float*)d_in[1];
    const float* bq     = (const float*)d_in[2];
    const float* Wk     = (const float*)d_in[3];
    const float* bk     = (const float*)d_in[4];
    const float* Wv     = (const float*)d_in[5];
    const float* bv     = (const float*)d_in[6];
    const float* alpha1 = (const float*)d_in[7];
    const float* beta1  = (const float*)d_in[8];
    const float* W1     = (const float*)d_in[9];
    const float* b1     = (const float*)d_in[10];
    const float* W2     = (const float*)d_in[11];
    const float* b2     = (const float*)d_in[12];
    const float* alpha2 = (const float*)d_in[13];
    const float* beta2  = (const float*)d_in[14];
    float* out = (float*)d_out;

    char* ws = (char*)d_ws;
    size_t off = 0;
    auto alloc = [&](size_t bytes) -> void* {
        void* p = ws + off;
        off += (bytes + 255) & ~(size_t)255;
        return p;
    };
    short* XBF   = (short*)alloc(2048UL * 2048 * 2);       // dead after QKV gemm
    short* WQKVT = (short*)alloc(48UL * 128 * 2048 * 2);   // = [6144][2048]; dead after QKV
    short* W1T   = (short*)alloc(8192UL * 2048 * 2);       // dead after FFN1
    short* W2T   = (short*)alloc(2048UL * 8192 * 2);
    short* QKV   = (short*)alloc(48UL * 2048 * 128 * 2);   // Q(0-15),K(16-31),V(32-47)
    short* VT    = (short*)alloc(16UL * 128 * 2048 * 2);
    float* ATTN  = (float*)alloc(2048UL * 2048 * 4);
    float* H1    = (float*)alloc(2048UL * 2048 * 4);
    short* H1BF  = (short*)alloc(2048UL * 2048 * 2);
    short* G     = (short*)alloc(2048UL * 8192 * 2);
    // F4 (64 MB, 4 split-K f32 slabs) aliases XBF+WQKVT+W1T (all dead by FFN2)
    float* F4 = (float*)XBF;

    // 1. casts / transposes
    cast_f32_bf16<<<2048, 256, 0, stream>>>(X, XBF, 2048 * 2048 / 8);
    transpose_cast<float><<<dim3(2, 32, 16), 256, 0, stream>>>(Wq, WQKVT,                    2048, 128, 2048L * 128, 128L * 2048);
    transpose_cast<float><<<dim3(2, 32, 16), 256, 0, stream>>>(Wk, WQKVT + 16L * 128 * 2048, 2048, 128, 2048L * 128, 128L * 2048);
    transpose_cast<float><<<dim3(2, 32, 16), 256, 0, stream>>>(Wv, WQKVT + 32L * 128 * 2048, 2048, 128, 2048L * 128, 128L * 2048);
    transpose_cast<float><<<dim3(128, 32, 1), 256, 0, stream>>>(W1, W1T, 2048, 8192, 0, 0);
    transpose_cast<float><<<dim3(32, 128, 1), 256, 0, stream>>>(W2, W2T, 8192, 2048, 0, 0);

    // 2. QKV fused GEMM: M=2048, N=6144 (TM=8, TN=24 -> 192 blocks)
    gemm256<0><<<192, 512, 0, stream>>>(XBF, WQKVT, QKV, bq, bk, bv, 2048, 8);

    // 3. V -> V^T per head
    transpose_cast<__hip_bfloat16><<<dim3(2, 32, 16), 256, 0, stream>>>(
        (const __hip_bfloat16*)(QKV + 32L * 2048 * 128), VT, 2048, 128, 2048L * 128, 128L * 2048);

    // 4. attention (256 blocks x 8 waves; LDS-staged K/V)
    attn_flash<<<256, 512, 0, stream>>>(QKV, QKV + 16L * 2048 * 128, VT, ATTN);

    // 5. Add & LN 1
    add_ln<true><<<2048, 256, 0, stream>>>(X, ATTN, alpha1, beta1, H1, H1BF);

    // 6. FFN: FFN1 M=2048 N=8192 (256 blocks); FFN2 split-K=4 (256 blocks)
    gemm256<1><<<256, 512, 0, stream>>>(H1BF, W1T, G, b1, nullptr, nullptr, 2048, 8);
    gemm256<2><<<256, 512, 0, stream>>>(G, W2T, F4, nullptr, nullptr, nullptr, 8192, 8);

    // 7. Add + reduce + LN 2 -> output
    add_ln2_red<<<2048, 256, 0, stream>>>(H1, F4, b2, alpha2, beta2, out);
}

// Round 10
// 383.612 us; speedup vs baseline: 1.6483x; 1.0257x over previous
//
#include <hip/hip_runtime.h>
#include <hip/hip_bf16.h>

#define N_TOK 2048
#define DMODEL 2048
#define NH 16
#define DK 128
#define DFF 8192

typedef __attribute__((ext_vector_type(8))) short short8;
typedef __attribute__((ext_vector_type(4))) short s16x4;
typedef __attribute__((ext_vector_type(4))) float f32x4;

__device__ __forceinline__ short f2bf(float f) {
    unsigned int x = __builtin_bit_cast(unsigned int, f);
    unsigned int r = (x + 0x7fffu + ((x >> 16) & 1u)) >> 16;
    return (short)r;
}

// ---------------- cast X (f32 -> bf16), 8 elems/thread ----------------
__global__ __launch_bounds__(256) void cast_f32_bf16(const float* __restrict__ in,
                                                     short* __restrict__ out, int n8) {
    int i = blockIdx.x * 256 + threadIdx.x;
    if (i >= n8) return;
    const float4* p = (const float4*)in + (size_t)i * 2;
    float4 a = p[0], b = p[1];
    short8 o;
    o[0] = f2bf(a.x); o[1] = f2bf(a.y); o[2] = f2bf(a.z); o[3] = f2bf(a.w);
    o[4] = f2bf(b.x); o[5] = f2bf(b.y); o[6] = f2bf(b.z); o[7] = f2bf(b.w);
    *(short8*)(out + (size_t)i * 8) = o;
}

// ---------------- transpose + cast to bf16 (64x64 LDS tiles) ----------------
template <typename TIN>
__global__ __launch_bounds__(256) void transpose_cast(const TIN* __restrict__ in,
                                                      short* __restrict__ out,
                                                      int R, int C, long sIn, long sOut) {
    __shared__ float t[64][65];
    in  += (long)blockIdx.z * sIn;
    out += (long)blockIdx.z * sOut;
    int tx = threadIdx.x & 63, ty = threadIdx.x >> 6;
    long r0 = (long)blockIdx.y * 64, c0 = (long)blockIdx.x * 64;
    for (int i = 0; i < 16; i++) {
        int r = ty + i * 4;
        t[r][tx] = (float)in[(r0 + r) * (long)C + c0 + tx];
    }
    __syncthreads();
    for (int i = 0; i < 16; i++) {
        int r = ty + i * 4;
        out[(c0 + r) * (long)R + r0 + tx] = f2bf(t[tx][r]);
    }
}

// ---------------- async global->LDS helper ----------------
__device__ __forceinline__ void gld_lds16(const void* g, void* l) {
    __builtin_amdgcn_global_load_lds(
        (const __attribute__((address_space(1))) void*)g,
        (__attribute__((address_space(3))) void*)l, 16, 0, 0);
}

// ======== 256x256 bf16 GEMM, BK=64, 8 waves, 8-phase counted-vmcnt ==========
// B pre-transposed [n][k]. LDS 128 KB = 2 bufs x (A[256][64] + B[256][64]).
// Per iter: 2 K-tiles (buf0 even, buf1 odd), 8 phases; phase = one C-quadrant
// (mh,nh): {ds_read frags; stage 1 region; BAR; lgkm0; 16 MFMA; [vmcnt(8)];
// BAR}. Regions staged only after their last reader's closing barrier
// (A-mh freed after its nh0 phase via reg caching; B-nh after 2nd read).
// vmcnt(8) at P0/P3/P4/P7 retires exactly the loads needed 1-2 phases later.
#define VM8 asm volatile("s_waitcnt vmcnt(8)" ::: "memory")
#define VM4 asm volatile("s_waitcnt vmcnt(4)" ::: "memory")
#define VM0 asm volatile("s_waitcnt vmcnt(0)" ::: "memory")
#define VMNONE ((void)0)

#define PHASE(BUF, MH, NH, STAGE_STMT, VMSTMT)                                  \
  {                                                                             \
    if (NH == 0) {                                                              \
      _Pragma("unroll") for (int mp = 0; mp < 4; mp++)                          \
        _Pragma("unroll") for (int kk = 0; kk < 2; kk++) {                      \
          int rowA = wr * 128 + (MH) * 64 + mp * 16 + fr;                       \
          af[mp][kk] = *(const short8*)((const char*)lds + (BUF) * 65536 +      \
                         rowA * 128 + (((kk * 4 + fq) ^ (rowA & 7)) << 4));     \
        }                                                                       \
    }                                                                           \
    _Pragma("unroll") for (int np = 0; np < 2; np++)                            \
      _Pragma("unroll") for (int kk = 0; kk < 2; kk++) {                        \
        int rowB = wc * 64 + (NH) * 32 + np * 16 + fr;                          \
        bf[np][kk] = *(const short8*)((const char*)lds + (BUF) * 65536 + 32768 +\
                       rowB * 128 + (((kk * 4 + fq) ^ (rowB & 7)) << 4));       \
      }                                                                         \
    STAGE_STMT;                                                                 \
    __builtin_amdgcn_s_barrier();                                               \
    asm volatile("s_waitcnt lgkmcnt(0)" ::: "memory");                          \
    __builtin_amdgcn_sched_barrier(0);                                          \
    __builtin_amdgcn_s_setprio(1);                                              \
    _Pragma("unroll") for (int mp = 0; mp < 4; mp++)                            \
      _Pragma("unroll") for (int np = 0; np < 2; np++)                          \
        _Pragma("unroll") for (int kk = 0; kk < 2; kk++)                        \
          acc[(MH) * 4 + mp][(NH) * 2 + np] =                                   \
              __builtin_amdgcn_mfma_f32_16x16x32_bf16(                          \
                  af[mp][kk], bf[np][kk], acc[(MH) * 4 + mp][(NH) * 2 + np],    \
                  0, 0, 0);                                                     \
    __builtin_amdgcn_s_setprio(0);                                              \
    VMSTMT;                                                                     \
    __builtin_amdgcn_sched_barrier(0);                                          \
    __builtin_amdgcn_s_barrier();                                               \
    __builtin_amdgcn_sched_barrier(0);                                          \
  }

template <int MODE>
__global__ __launch_bounds__(512, 2) void gemm256(const short* __restrict__ A,
                                                  const short* __restrict__ Bt,
                                                  void* __restrict__ Cv,
                                                  const float* __restrict__ b0,
                                                  const float* __restrict__ b1,
                                                  const float* __restrict__ b2,
                                                  int Ktot, int TM) {
    __shared__ short lds[65536];   // 128 KB
    const int tid = threadIdx.x, lane = tid & 63, w = tid >> 6;
    const int T = gridDim.x, bid = blockIdx.x;
    const int vbid = (bid & 7) * (T >> 3) + (bid >> 3);   // XCD chunking
    const int mt = vbid % TM;
    const int rest = vbid / TM;
    int nt = rest, z = 0;
    if (MODE == 2) { nt = rest & 7; z = rest >> 3; }
    const long brow = (long)mt * 256, bcol = (long)nt * 256;
    const short* Ab = A + (MODE == 2 ? (long)z * 2048 : 0);
    const short* Bb = Bt + (MODE == 2 ? (long)z * 2048 : 0);

    // region staging: 16KB units, 2 gld_lds/thread, linear LDS dest,
    // inverse swizzle on the GLOBAL source (granule ^ (row&7)).
    auto stageA = [&](int kt, int buf, int mh) {
#pragma unroll
        for (int j = 0; j < 2; j++) {
            int row = mh * 64 + j * 128 + (tid >> 3);
            int g = (lane & 7) ^ (row & 7);
            gld_lds16((const char*)(Ab + (brow + row) * (long)Ktot + (long)kt * 64) + g * 16,
                      (char*)lds + buf * 65536 + mh * 8192 + j * 16384 + w * 1024 + lane * 16);
        }
    };
    auto stageB = [&](int kt, int buf, int nh) {
#pragma unroll
        for (int j = 0; j < 2; j++) {
            int s = 2 * j + (w >> 2);
            int rin = (w & 3) * 8 + (lane >> 3);
            int row = s * 64 + nh * 32 + rin;
            int g = (lane & 7) ^ (row & 7);
            gld_lds16((const char*)(Bb + (bcol + row) * (long)Ktot + (long)kt * 64) + g * 16,
                      (char*)lds + buf * 65536 + 32768 + j * 16384 + (w >> 2) * 8192 +
                          nh * 4096 + (w & 3) * 1024 + lane * 16);
        }
    };

    const int wr = w >> 2, wc = w & 3;          // 2 x 4 wave grid (128 x 64 out)
    const int fr = lane & 15, fq = lane >> 4;
    f32x4 acc[8][4] = {};
    short8 af[4][2], bf[2][2];

    // prologue: K0 full -> buf0; K1 {Amh0, Bnh0} -> buf1  (12 loads)
    stageA(0, 0, 0); stageB(0, 0, 0); stageA(0, 0, 1); stageB(0, 0, 1);
    stageA(1, 1, 0); stageB(1, 1, 0);
    VM8;                                         // retire buf0.{Amh0,Bnh0}
    __builtin_amdgcn_s_barrier();

    // steady iters: K-tiles (2i, 2i+1); stage (2i+1)'s tail + (2i+2),(2i+3)
    for (int i = 0; i < 15; i++) {
        const int t1 = 2 * i + 1, kn = 2 * i + 2;
        PHASE(0, 0, 0, { stageA(t1, 1, 1); stageB(t1, 1, 1); }, VM8)
        PHASE(0, 0, 1, { stageA(kn, 0, 0); }, VMNONE)
        PHASE(0, 1, 0, {}, VMNONE)
        PHASE(0, 1, 1, { stageB(kn, 0, 0); }, VM8)
        PHASE(1, 0, 0, { stageA(kn, 0, 1); stageB(kn, 0, 1); }, VM8)
        PHASE(1, 0, 1, { stageA(kn + 1, 1, 0); }, VMNONE)
        PHASE(1, 1, 0, {}, VMNONE)
        PHASE(1, 1, 1, { stageB(kn + 1, 1, 0); }, VM8)
    }
    // peeled final iter: K-tiles 30,31; only K31's tail staged; drain 8->4->0
    PHASE(0, 0, 0, { stageA(31, 1, 1); stageB(31, 1, 1); }, VM8)
    PHASE(0, 0, 1, {}, VMNONE)
    PHASE(0, 1, 0, {}, VMNONE)
    PHASE(0, 1, 1, {}, VM4)
    PHASE(1, 0, 0, {}, VM0)
    PHASE(1, 0, 1, {}, VMNONE)
    PHASE(1, 1, 0, {}, VMNONE)
    PHASE(1, 1, 1, {}, VMNONE)

    // epilogue: acc[m][n] <-> A rows (m>>2)*64+(m&3)*16, B rows (n>>1)*32+(n&1)*16
    const long crow0 = brow + wr * 128, ccol0 = bcol + wc * 64;
#pragma unroll
    for (int n = 0; n < 4; n++) {
        const long col = ccol0 + (n >> 1) * 32 + (n & 1) * 16 + fr;
        float bval = 0.f;
        if (MODE == 0) {
            const float* bp = (col >> 11) == 0 ? b0 : (col >> 11) == 1 ? b1 : b2;
            bval = bp[col & 2047];
        } else if (MODE == 1) bval = b0[col];
#pragma unroll
        for (int m = 0; m < 8; m++) {
#pragma unroll
            for (int r = 0; r < 4; r++) {
                const long row = crow0 + (m >> 2) * 64 + (m & 3) * 16 + fq * 4 + r;
                float v = acc[m][n][r] + bval;
                if (MODE == 0) {
                    const long slab = col >> 7;
                    ((short*)Cv)[slab * (2048L * 128) + row * 128 + (col & 127)] = f2bf(v);
                } else if (MODE == 1) {
                    ((short*)Cv)[row * 8192 + col] = f2bf(fmaxf(v, 0.f));
                } else {
                    ((float*)Cv)[(long)z * (2048L * 2048) + row * 2048 + col] = v;
                }
            }
        }
    }
}

// ---------------- flash attention v5: LDS-staged K/V shared by 8 waves ------
__global__ __launch_bounds__(512, 2) void attn_flash(const short* __restrict__ Q,
                                                     const short* __restrict__ Kc,
                                                     const short* __restrict__ VT,
                                                     float* __restrict__ O) {
    __shared__ short lds[32768];           // 64 KB: K0[8192] K1[8192] V[8192] P[8][1024]
    const int tid = threadIdx.x, lane = tid & 63, w = tid >> 6;
    const int bid = blockIdx.x;
    const int vid = (bid & 7) * 32 + (bid >> 3);   // XCD-chunked swizzle (256%8==0)
    const int h = vid >> 4, qt = vid & 15;
    const int fr = lane & 15, fq = lane >> 4;
    const long qbase = (long)qt * 128 + w * 16;
    const short* Qh = Q  + (long)h * N_TOK * DK;
    const short* Kh = Kc + (long)h * N_TOK * DK;
    const short* Vh = VT + (long)h * DK * N_TOK;
    short* Pw = lds + 24576 + w * 1024;

    short8 qf[4];
#pragma unroll
    for (int c = 0; c < 4; c++)
        qf[c] = *(const short8*)(Qh + (qbase + fr) * DK + c * 32 + fq * 8);

    float mrow = -1e30f, lrow = 0.f;
    f32x4 oacc[8] = {};
    const float C1 = 0.08838834764831845f * 1.4426950408889634f; // 1/sqrt(128)*log2e

    int wr_off[4], rd_off[2];
#pragma unroll
    for (int jc = 0; jc < 4; jc++)
        wr_off[jc] = (fr * 64 + jc * 16 + fq * 4) ^ ((fr & 7) << 3);
#pragma unroll
    for (int kc = 0; kc < 2; kc++)
        rd_off[kc] = (fr * 64 + kc * 32 + fq * 8) ^ ((fr & 7) << 3);
    int colKb[4], colVb[2];
#pragma unroll
    for (int c = 0; c < 4; c++) colKb[c] = (c * 64 + fq * 16) ^ ((fr & 7) << 4);
#pragma unroll
    for (int kc = 0; kc < 2; kc++) colVb[kc] = (kc * 64 + fq * 16) ^ ((fr & 7) << 4);

    auto stageK = [&](int kvt, int buf) {
        const char* Kg = (const char*)(Kh + (long)kvt * 64 * DK);
        char* Kd = (char*)(lds + buf * 8192);
#pragma unroll
        for (int i = 0; i < 2; i++) {
            int a = (w * 2 + i) * 1024 + (lane << 4);
            int src = a ^ (((a >> 8) & 7) << 4);
            gld_lds16(Kg + src, Kd + (w * 2 + i) * 1024);
        }
    };
    auto stageV = [&](int kvt) {
        char* Vd = (char*)(lds + 16384);
#pragma unroll
        for (int i = 0; i < 2; i++) {
            int a = (w * 2 + i) * 1024 + (lane << 4);
            int row = a >> 7;
            int inner = (a & 127) ^ ((row & 7) << 4);
            const char* src = (const char*)Vh + ((long)row * N_TOK + (long)kvt * 64) * 2 + inner;
            gld_lds16(src, Vd + (w * 2 + i) * 1024);
        }
    };

    const int NT = N_TOK / 64;
    stageK(0, 0);
    __syncthreads();

    for (int t = 0; t < NT; t++) {
        const int cur = t & 1;
        stageV(t);
        if (t + 1 < NT) stageK(t + 1, cur ^ 1);

        const char* Kcb = (const char*)(lds + cur * 8192);
        f32x4 s[4] = {};
#pragma unroll
        for (int jc = 0; jc < 4; jc++) {
            const char* rb = Kcb + (jc * 16 + fr) * 256;
#pragma unroll
            for (int c = 0; c < 4; c++) {
                short8 kf = *(const short8*)(rb + colKb[c]);
                s[jc] = __builtin_amdgcn_mfma_f32_16x16x32_bf16(kf, qf[c], s[jc], 0, 0, 0);
            }
        }

        float tm = -1e30f;
#pragma unroll
        for (int jc = 0; jc < 4; jc++)
#pragma unroll
            for (int r = 0; r < 4; r++) tm = fmaxf(tm, s[jc][r]);
        tm = fmaxf(tm, __shfl_xor(tm, 16));
        tm = fmaxf(tm, __shfl_xor(tm, 32));
        float nm = fmaxf(mrow, tm);
        float resc = exp2f(C1 * (mrow - nm));
        mrow = nm;
        float sum = 0.f;
#pragma unroll
        for (int jc = 0; jc < 4; jc++)
#pragma unroll
            for (int r = 0; r < 4; r++) {
                float p = exp2f(C1 * (s[jc][r] - nm));
                s[jc][r] = p;
                sum += p;
            }
        sum += __shfl_xor(sum, 16);
        sum += __shfl_xor(sum, 32);
        lrow = lrow * resc + sum;
#pragma unroll
        for (int f = 0; f < 8; f++)
#pragma unroll
            for (int r = 0; r < 4; r++) oacc[f][r] *= resc;

#pragma unroll
        for (int jc = 0; jc < 4; jc++) {
            s16x4 pk;
            pk[0] = f2bf(s[jc][0]); pk[1] = f2bf(s[jc][1]);
            pk[2] = f2bf(s[jc][2]); pk[3] = f2bf(s[jc][3]);
            *(s16x4*)(Pw + wr_off[jc]) = pk;
        }
        short8 pa[2];
#pragma unroll
        for (int kc = 0; kc < 2; kc++)
            pa[kc] = *(const short8*)(Pw + rd_off[kc]);

        __syncthreads();

        const char* Vcb = (const char*)(lds + 16384);
#pragma unroll
        for (int f = 0; f < 8; f++) {
            const char* rb = Vcb + (f * 16 + fr) * 128;
#pragma unroll
            for (int kc = 0; kc < 2; kc++) {
                short8 vf = *(const short8*)(rb + colVb[kc]);
                oacc[f] = __builtin_amdgcn_mfma_f32_16x16x32_bf16(vf, pa[kc], oacc[f], 0, 0, 0);
            }
        }
        __syncthreads();
    }

    const float inv = 1.f / lrow;
    const long row = qbase + fr;
#pragma unroll
    for (int f = 0; f < 8; f++) {
        float4 o;
        o.x = oacc[f][0] * inv; o.y = oacc[f][1] * inv;
        o.z = oacc[f][2] * inv; o.w = oacc[f][3] * inv;
        *(float4*)(O + row * (long)DMODEL + h * DK + f * 16 + fq * 4) = o;
    }
}

// ---------------- fused Add + LayerNorm (1 block = 1 row of 2048) -----------
template <bool WBF>
__global__ __launch_bounds__(256) void add_ln(const float* __restrict__ A,
                                              const float* __restrict__ B,
                                              const float* __restrict__ alpha,
                                              const float* __restrict__ beta,
                                              float* __restrict__ out,
                                              short* __restrict__ outbf) {
    const int row = blockIdx.x, t = threadIdx.x;
    const long base = (long)row * DMODEL;
    float4 va[2], vb[2];
    float s = 0.f, q = 0.f;
#pragma unroll
    for (int i = 0; i < 2; i++) {
        long off = base + (long)(t + i * 256) * 4;
        va[i] = *(const float4*)(A + off);
        vb[i] = *(const float4*)(B + off);
        float x0 = va[i].x + vb[i].x, x1 = va[i].y + vb[i].y;
        float x2 = va[i].z + vb[i].z, x3 = va[i].w + vb[i].w;
        s += x0 + x1 + x2 + x3;
        q += x0 * x0 + x1 * x1 + x2 * x2 + x3 * x3;
    }
#pragma unroll
    for (int o = 1; o < 64; o <<= 1) { s += __shfl_xor(s, o); q += __shfl_xor(q, o); }
    __shared__ float red[8];
    if ((t & 63) == 0) { red[t >> 6] = s; red[4 + (t >> 6)] = q; }
    __syncthreads();
    s = red[0] + red[1] + red[2] + red[3];
    q = red[4] + red[5] + red[6] + red[7];
    const float mean = s * (1.f / DMODEL);
    const float var = q * (1.f / DMODEL) - mean * mean;
    const float rstd = rsqrtf(var + 1e-5f);
#pragma unroll
    for (int i = 0; i < 2; i++) {
        long off = base + (long)(t + i * 256) * 4;
        float4 al = *(const float4*)(alpha + off);
        float4 be = *(const float4*)(beta + off);
        float x[4] = { va[i].x + vb[i].x, va[i].y + vb[i].y, va[i].z + vb[i].z, va[i].w + vb[i].w };
        float a[4] = { al.x, al.y, al.z, al.w };
        float b[4] = { be.x, be.y, be.z, be.w };
#pragma unroll
        for (int j = 0; j < 4; j++) {
            float o2 = (x[j] - mean) * rstd * a[j] + b[j];
            out[off + j] = o2;
            if (WBF) outbf[off + j] = f2bf(o2);
        }
    }
}

// ---------------- Add + LN2 with 4-slab split-K reduction + bias ------------
__global__ __launch_bounds__(256) void add_ln2_red(const float* __restrict__ H1,
                                                   const float* __restrict__ F4,
                                                   const float* __restrict__ b2,
                                                   const float* __restrict__ alpha,
                                                   const float* __restrict__ beta,
                                                   float* __restrict__ out) {
    const int row = blockIdx.x, t = threadIdx.x;
    const long base = (long)row * DMODEL;
    const long SL = (long)N_TOK * DMODEL;
    float x[8];
    float s = 0.f, q = 0.f;
#pragma unroll
    for (int i = 0; i < 2; i++) {
        long off = base + (long)(t + i * 256) * 4;
        int col = (t + i * 256) * 4;
        float4 a  = *(const float4*)(H1 + off);
        float4 f0 = *(const float4*)(F4 + off);
        float4 f1 = *(const float4*)(F4 + off + SL);
        float4 f2 = *(const float4*)(F4 + off + 2 * SL);
        float4 f3 = *(const float4*)(F4 + off + 3 * SL);
        float4 bb = *(const float4*)(b2 + col);
        x[i * 4 + 0] = a.x + f0.x + f1.x + f2.x + f3.x + bb.x;
        x[i * 4 + 1] = a.y + f0.y + f1.y + f2.y + f3.y + bb.y;
        x[i * 4 + 2] = a.z + f0.z + f1.z + f2.z + f3.z + bb.z;
        x[i * 4 + 3] = a.w + f0.w + f1.w + f2.w + f3.w + bb.w;
#pragma unroll
        for (int j = 0; j < 4; j++) { s += x[i * 4 + j]; q += x[i * 4 + j] * x[i * 4 + j]; }
    }
#pragma unroll
    for (int o = 1; o < 64; o <<= 1) { s += __shfl_xor(s, o); q += __shfl_xor(q, o); }
    __shared__ float red[8];
    if ((t & 63) == 0) { red[t >> 6] = s; red[4 + (t >> 6)] = q; }
    __syncthreads();
    s = red[0] + red[1] + red[2] + red[3];
    q = red[4] + red[5] + red[6] + red[7];
    const float mean = s * (1.f / DMODEL);
    const float var = q * (1.f / DMODEL) - mean * mean;
    const float rstd = rsqrtf(var + 1e-5f);
#pragma unroll
    for (int i = 0; i < 2; i++) {
        long off = base + (long)(t + i * 256) * 4;
        float4 al = *(const float4*)(alpha + off);
        float4 be = *(const float4*)(beta + off);
        float a[4] = { al.x, al.y, al.z, al.w };
        float b[4] = { be.x, be.y, be.z, be.w };
#pragma unroll
        for (int j = 0; j < 4; j++)
            out[off + j] = (x[i * 4 + j] - mean) * rstd * a[j] + b[j];
    }
}

extern "C" void kernel_launch(void* const* d_in, const int* in_sizes, int n_in,
                              void* d_out, int out_size, void* d_ws, size_t ws_size,
                              hipStream_t stream) {
    const float* X      = (const float*)d_in[0];
    const float* Wq     = (const float*)d_in[1];
    const float* bq     = (const float*)d_in[2];
    const float* Wk     = (const float*)d_in[3];
    const float* bk     = (const float*)d_in[4];
    const float* Wv     = (const float*)d_in[5];
    const float* bv     = (const float*)d_in[6];
    const float* alpha1 = (const float*)d_in[7];
    const float* beta1  = (const float*)d_in[8];
    const float* W1     = (const float*)d_in[9];
    const float* b1     = (const float*)d_in[10];
    const float* W2     = (const float*)d_in[11];
    const float* b2     = (const float*)d_in[12];
    const float* alpha2 = (const float*)d_in[13];
    const float* beta2  = (const float*)d_in[14];
    float* out = (float*)d_out;

    char* ws = (char*)d_ws;
    size_t off = 0;
    auto alloc = [&](size_t bytes) -> void* {
        void* p = ws + off;
        off += (bytes + 255) & ~(size_t)255;
        return p;
    };
    short* XBF   = (short*)alloc(2048UL * 2048 * 2);       // dead after QKV gemm
    short* WQKVT = (short*)alloc(48UL * 128 * 2048 * 2);   // = [6144][2048]; dead after QKV
    short* W1T   = (short*)alloc(8192UL * 2048 * 2);       // dead after FFN1
    short* W2T   = (short*)alloc(2048UL * 8192 * 2);
    short* QKV   = (short*)alloc(48UL * 2048 * 128 * 2);   // Q(0-15),K(16-31),V(32-47)
    short* VT    = (short*)alloc(16UL * 128 * 2048 * 2);
    float* ATTN  = (float*)alloc(2048UL * 2048 * 4);
    float* H1    = (float*)alloc(2048UL * 2048 * 4);
    short* H1BF  = (short*)alloc(2048UL * 2048 * 2);
    short* G     = (short*)alloc(2048UL * 8192 * 2);
    // F4 (64 MB, 4 split-K f32 slabs) aliases XBF+WQKVT+W1T (all dead by FFN2)
    float* F4 = (float*)XBF;

    // 1. casts / transposes
    cast_f32_bf16<<<2048, 256, 0, stream>>>(X, XBF, 2048 * 2048 / 8);
    transpose_cast<float><<<dim3(2, 32, 16), 256, 0, stream>>>(Wq, WQKVT,                    2048, 128, 2048L * 128, 128L * 2048);
    transpose_cast<float><<<dim3(2, 32, 16), 256, 0, stream>>>(Wk, WQKVT + 16L * 128 * 2048, 2048, 128, 2048L * 128, 128L * 2048);
    transpose_cast<float><<<dim3(2, 32, 16), 256, 0, stream>>>(Wv, WQKVT + 32L * 128 * 2048, 2048, 128, 2048L * 128, 128L * 2048);
    transpose_cast<float><<<dim3(128, 32, 1), 256, 0, stream>>>(W1, W1T, 2048, 8192, 0, 0);
    transpose_cast<float><<<dim3(32, 128, 1), 256, 0, stream>>>(W2, W2T, 8192, 2048, 0, 0);

    // 2. QKV fused GEMM: M=2048, N=6144 (TM=8, TN=24 -> 192 blocks)
    gemm256<0><<<192, 512, 0, stream>>>(XBF, WQKVT, QKV, bq, bk, bv, 2048, 8);

    // 3. V -> V^T per head
    transpose_cast<__hip_bfloat16><<<dim3(2, 32, 16), 256, 0, stream>>>(
        (const __hip_bfloat16*)(QKV + 32L * 2048 * 128), VT, 2048, 128, 2048L * 128, 128L * 2048);

    // 4. attention (256 blocks x 8 waves; LDS-staged K/V)
    attn_flash<<<256, 512, 0, stream>>>(QKV, QKV + 16L * 2048 * 128, VT, ATTN);

    // 5. Add & LN 1
    add_ln<true><<<2048, 256, 0, stream>>>(X, ATTN, alpha1, beta1, H1, H1BF);

    // 6. FFN: FFN1 M=2048 N=8192 (256 blocks); FFN2 split-K=4 (256 blocks)
    gemm256<1><<<256, 512, 0, stream>>>(H1BF, W1T, G, b1, nullptr, nullptr, 2048, 8);
    gemm256<2><<<256, 512, 0, stream>>>(G, W2T, F4, nullptr, nullptr, nullptr, 8192, 8);

    // 7. Add + reduce + LN 2 -> output
    add_ln2_red<<<2048, 256, 0, stream>>>(H1, F4, b2, alpha2, beta2, out);
}

// Round 11
// 378.788 us; speedup vs baseline: 1.6692x; 1.0127x over previous
//
#include <hip/hip_runtime.h>
#include <hip/hip_bf16.h>

#define N_TOK 2048
#define DMODEL 2048
#define NH 16
#define DK 128
#define DFF 8192

typedef __attribute__((ext_vector_type(8))) short short8;
typedef __attribute__((ext_vector_type(4))) short s16x4;
typedef __attribute__((ext_vector_type(4))) float f32x4;

__device__ __forceinline__ short f2bf(float f) {
    unsigned int x = __builtin_bit_cast(unsigned int, f);
    unsigned int r = (x + 0x7fffu + ((x >> 16) & 1u)) >> 16;
    return (short)r;
}

// ---------------- cast X (f32 -> bf16), 8 elems/thread ----------------
__global__ __launch_bounds__(256) void cast_f32_bf16(const float* __restrict__ in,
                                                     short* __restrict__ out, int n8) {
    int i = blockIdx.x * 256 + threadIdx.x;
    if (i >= n8) return;
    const float4* p = (const float4*)in + (size_t)i * 2;
    float4 a = p[0], b = p[1];
    short8 o;
    o[0] = f2bf(a.x); o[1] = f2bf(a.y); o[2] = f2bf(a.z); o[3] = f2bf(a.w);
    o[4] = f2bf(b.x); o[5] = f2bf(b.y); o[6] = f2bf(b.z); o[7] = f2bf(b.w);
    *(short8*)(out + (size_t)i * 8) = o;
}

// ---------------- transpose + cast to bf16 (64x64 LDS tiles) ----------------
template <typename TIN>
__global__ __launch_bounds__(256) void transpose_cast(const TIN* __restrict__ in,
                                                      short* __restrict__ out,
                                                      int R, int C, long sIn, long sOut) {
    __shared__ float t[64][65];
    in  += (long)blockIdx.z * sIn;
    out += (long)blockIdx.z * sOut;
    int tx = threadIdx.x & 63, ty = threadIdx.x >> 6;
    long r0 = (long)blockIdx.y * 64, c0 = (long)blockIdx.x * 64;
    for (int i = 0; i < 16; i++) {
        int r = ty + i * 4;
        t[r][tx] = (float)in[(r0 + r) * (long)C + c0 + tx];
    }
    __syncthreads();
    for (int i = 0; i < 16; i++) {
        int r = ty + i * 4;
        out[(c0 + r) * (long)R + r0 + tx] = f2bf(t[tx][r]);
    }
}

// ---------------- async global->LDS helper ----------------
__device__ __forceinline__ void gld_lds16(const void* g, void* l) {
    __builtin_amdgcn_global_load_lds(
        (const __attribute__((address_space(1))) void*)g,
        (__attribute__((address_space(3))) void*)l, 16, 0, 0);
}

// ======== 256x256 bf16 GEMM, BK=64, 8 waves, 8-phase, B-read-once ===========
// B pre-transposed [n][k]. LDS 128 KB = 2 bufs x (A[256][64] + B[256][64]).
// B-frags for a K-tile cached in regs (bf[2][..]) -> each LDS byte read ONCE
// (24KB/wave/K-tile, was 32). Reads spread: P0 af0+bf0(12), P1 bf1(4),
// P2 af1(8), P3 none. Stages at P1/P2/P3 (buf0) and P5/P6/P7 (buf1) — every
// stage-write barrier-separated from its region's last read. VM8 at P3/P7
// retires exactly the other buffer's 8 loads before they're read.
#define VM8 asm volatile("s_waitcnt vmcnt(8)" ::: "memory")
#define VM0 asm volatile("s_waitcnt vmcnt(0)" ::: "memory")
#define VMNONE ((void)0)

// RA: read af (for MH); RBNH: 0/1 = read bf[RBNH], 2 = none.
#define PHASE(BUF, MH, NHI, RA, RBNH, STAGE_STMT, VMSTMT)                       \
  {                                                                             \
    if (RA) {                                                                   \
      _Pragma("unroll") for (int mp = 0; mp < 4; mp++)                          \
        _Pragma("unroll") for (int kk = 0; kk < 2; kk++) {                      \
          int rowA = wr * 128 + (MH) * 64 + mp * 16 + fr;                       \
          af[mp][kk] = *(const short8*)((const char*)lds + (BUF) * 65536 +      \
                         rowA * 128 + (((kk * 4 + fq) ^ (rowA & 7)) << 4));     \
        }                                                                       \
    }                                                                           \
    if ((RBNH) < 2) {                                                           \
      _Pragma("unroll") for (int np = 0; np < 2; np++)                          \
        _Pragma("unroll") for (int kk = 0; kk < 2; kk++) {                      \
          int rowB = wc * 64 + (RBNH) * 32 + np * 16 + fr;                      \
          bf[(RBNH) & 1][np][kk] =                                              \
              *(const short8*)((const char*)lds + (BUF) * 65536 + 32768 +       \
                  rowB * 128 + (((kk * 4 + fq) ^ (rowB & 7)) << 4));            \
        }                                                                       \
    }                                                                           \
    STAGE_STMT;                                                                 \
    __builtin_amdgcn_s_barrier();                                               \
    asm volatile("s_waitcnt lgkmcnt(0)" ::: "memory");                          \
    __builtin_amdgcn_sched_barrier(0);                                          \
    __builtin_amdgcn_s_setprio(1);                                              \
    _Pragma("unroll") for (int mp = 0; mp < 4; mp++)                            \
      _Pragma("unroll") for (int np = 0; np < 2; np++)                          \
        _Pragma("unroll") for (int kk = 0; kk < 2; kk++)                        \
          acc[(MH) * 4 + mp][(NHI) * 2 + np] =                                  \
              __builtin_amdgcn_mfma_f32_16x16x32_bf16(                          \
                  af[mp][kk], bf[NHI][np][kk], acc[(MH) * 4 + mp][(NHI) * 2 + np],\
                  0, 0, 0);                                                     \
    __builtin_amdgcn_s_setprio(0);                                              \
    VMSTMT;                                                                     \
    __builtin_amdgcn_sched_barrier(0);                                          \
    __builtin_amdgcn_s_barrier();                                               \
    __builtin_amdgcn_sched_barrier(0);                                          \
  }

template <int MODE>
__global__ __launch_bounds__(512, 2) void gemm256(const short* __restrict__ A,
                                                  const short* __restrict__ Bt,
                                                  void* __restrict__ Cv,
                                                  const float* __restrict__ b0,
                                                  const float* __restrict__ b1,
                                                  const float* __restrict__ b2,
                                                  int Ktot, int TM) {
    __shared__ short lds[65536];   // 128 KB
    const int tid = threadIdx.x, lane = tid & 63, w = tid >> 6;
    const int T = gridDim.x, bid = blockIdx.x;
    const int vbid = (bid & 7) * (T >> 3) + (bid >> 3);   // XCD chunking
    const int mt = vbid % TM;
    const int rest = vbid / TM;
    int nt = rest, z = 0;
    if (MODE == 2) { nt = rest & 7; z = rest >> 3; }
    const long brow = (long)mt * 256, bcol = (long)nt * 256;
    const short* Ab = A + (MODE == 2 ? (long)z * 2048 : 0);
    const short* Bb = Bt + (MODE == 2 ? (long)z * 2048 : 0);

    // region staging: 16KB units, 2 gld_lds/thread, linear LDS dest,
    // inverse swizzle on the GLOBAL source (granule ^ (row&7)).
    auto stageA = [&](int kt, int buf, int mh) {
#pragma unroll
        for (int j = 0; j < 2; j++) {
            int row = mh * 64 + j * 128 + (tid >> 3);
            int g = (lane & 7) ^ (row & 7);
            gld_lds16((const char*)(Ab + (brow + row) * (long)Ktot + (long)kt * 64) + g * 16,
                      (char*)lds + buf * 65536 + mh * 8192 + j * 16384 + w * 1024 + lane * 16);
        }
    };
    auto stageB = [&](int kt, int buf, int nh) {
#pragma unroll
        for (int j = 0; j < 2; j++) {
            int s = 2 * j + (w >> 2);
            int rin = (w & 3) * 8 + (lane >> 3);
            int row = s * 64 + nh * 32 + rin;
            int g = (lane & 7) ^ (row & 7);
            gld_lds16((const char*)(Bb + (bcol + row) * (long)Ktot + (long)kt * 64) + g * 16,
                      (char*)lds + buf * 65536 + 32768 + j * 16384 + (w >> 2) * 8192 +
                          nh * 4096 + (w & 3) * 1024 + lane * 16);
        }
    };

    const int wr = w >> 2, wc = w & 3;          // 2 x 4 wave grid (128 x 64 out)
    const int fr = lane & 15, fq = lane >> 4;
    f32x4 acc[8][4] = {};
    short8 af[4][2], bf[2][2][2];

    // prologue: full K0 -> buf0, full K1 -> buf1 (16 loads)
    stageA(0, 0, 0); stageB(0, 0, 0); stageB(0, 0, 1); stageA(0, 0, 1);
    stageA(1, 1, 0); stageB(1, 1, 0); stageB(1, 1, 1); stageA(1, 1, 1);
    VM8;                                         // buf0's 8 retired
    __builtin_amdgcn_s_barrier();

    // steady iters: compute tiles (2i, 2i+1); stage tiles (2i+2, 2i+3)
    for (int i = 0; i < 15; i++) {
        const int kn = 2 * i + 2;
        PHASE(0, 0, 0, 1, 0, {}, VMNONE)                                   // af0+bf0
        PHASE(0, 0, 1, 0, 1, { stageA(kn, 0, 0); stageB(kn, 0, 0); }, VMNONE) // bf1
        PHASE(0, 1, 0, 1, 2, { stageB(kn, 0, 1); }, VMNONE)                // af1
        PHASE(0, 1, 1, 0, 2, { stageA(kn, 0, 1); }, VM8)
        PHASE(1, 0, 0, 1, 0, {}, VMNONE)
        PHASE(1, 0, 1, 0, 1, { stageA(kn + 1, 1, 0); stageB(kn + 1, 1, 0); }, VMNONE)
        PHASE(1, 1, 0, 1, 2, { stageB(kn + 1, 1, 1); }, VMNONE)
        PHASE(1, 1, 1, 0, 2, { stageA(kn + 1, 1, 1); }, VM8)
    }
    // peeled final iter: tiles 30,31; no staging; drain tile-31 loads at P3
    PHASE(0, 0, 0, 1, 0, {}, VMNONE)
    PHASE(0, 0, 1, 0, 1, {}, VMNONE)
    PHASE(0, 1, 0, 1, 2, {}, VMNONE)
    PHASE(0, 1, 1, 0, 2, {}, VM0)
    PHASE(1, 0, 0, 1, 0, {}, VMNONE)
    PHASE(1, 0, 1, 0, 1, {}, VMNONE)
    PHASE(1, 1, 0, 1, 2, {}, VMNONE)
    PHASE(1, 1, 1, 0, 2, {}, VMNONE)

    // epilogue: acc[m][n] <-> A rows (m>>2)*64+(m&3)*16, B cols (n>>1)*32+(n&1)*16
    const long crow0 = brow + wr * 128, ccol0 = bcol + wc * 64;
#pragma unroll
    for (int n = 0; n < 4; n++) {
        const long col = ccol0 + (n >> 1) * 32 + (n & 1) * 16 + fr;
        float bval = 0.f;
        if (MODE == 0) {
            const float* bp = (col >> 11) == 0 ? b0 : (col >> 11) == 1 ? b1 : b2;
            bval = bp[col & 2047];
        } else if (MODE == 1) bval = b0[col];
#pragma unroll
        for (int m = 0; m < 8; m++) {
#pragma unroll
            for (int r = 0; r < 4; r++) {
                const long row = crow0 + (m >> 2) * 64 + (m & 3) * 16 + fq * 4 + r;
                float v = acc[m][n][r] + bval;
                if (MODE == 0) {
                    const long slab = col >> 7;
                    ((short*)Cv)[slab * (2048L * 128) + row * 128 + (col & 127)] = f2bf(v);
                } else if (MODE == 1) {
                    ((short*)Cv)[row * 8192 + col] = f2bf(fmaxf(v, 0.f));
                } else {
                    ((float*)Cv)[(long)z * (2048L * 2048) + row * 2048 + col] = v;
                }
            }
        }
    }
}

// ---------------- flash attention v5: LDS-staged K/V shared by 8 waves ------
__global__ __launch_bounds__(512, 2) void attn_flash(const short* __restrict__ Q,
                                                     const short* __restrict__ Kc,
                                                     const short* __restrict__ VT,
                                                     float* __restrict__ O) {
    __shared__ short lds[32768];           // 64 KB: K0[8192] K1[8192] V[8192] P[8][1024]
    const int tid = threadIdx.x, lane = tid & 63, w = tid >> 6;
    const int bid = blockIdx.x;
    const int vid = (bid & 7) * 32 + (bid >> 3);   // XCD-chunked swizzle (256%8==0)
    const int h = vid >> 4, qt = vid & 15;
    const int fr = lane & 15, fq = lane >> 4;
    const long qbase = (long)qt * 128 + w * 16;
    const short* Qh = Q  + (long)h * N_TOK * DK;
    const short* Kh = Kc + (long)h * N_TOK * DK;
    const short* Vh = VT + (long)h * DK * N_TOK;
    short* Pw = lds + 24576 + w * 1024;

    short8 qf[4];
#pragma unroll
    for (int c = 0; c < 4; c++)
        qf[c] = *(const short8*)(Qh + (qbase + fr) * DK + c * 32 + fq * 8);

    float mrow = -1e30f, lrow = 0.f;
    f32x4 oacc[8] = {};
    const float C1 = 0.08838834764831845f * 1.4426950408889634f; // 1/sqrt(128)*log2e

    int wr_off[4], rd_off[2];
#pragma unroll
    for (int jc = 0; jc < 4; jc++)
        wr_off[jc] = (fr * 64 + jc * 16 + fq * 4) ^ ((fr & 7) << 3);
#pragma unroll
    for (int kc = 0; kc < 2; kc++)
        rd_off[kc] = (fr * 64 + kc * 32 + fq * 8) ^ ((fr & 7) << 3);
    int colKb[4], colVb[2];
#pragma unroll
    for (int c = 0; c < 4; c++) colKb[c] = (c * 64 + fq * 16) ^ ((fr & 7) << 4);
#pragma unroll
    for (int kc = 0; kc < 2; kc++) colVb[kc] = (kc * 64 + fq * 16) ^ ((fr & 7) << 4);

    auto stageK = [&](int kvt, int buf) {
        const char* Kg = (const char*)(Kh + (long)kvt * 64 * DK);
        char* Kd = (char*)(lds + buf * 8192);
#pragma unroll
        for (int i = 0; i < 2; i++) {
            int a = (w * 2 + i) * 1024 + (lane << 4);
            int src = a ^ (((a >> 8) & 7) << 4);
            gld_lds16(Kg + src, Kd + (w * 2 + i) * 1024);
        }
    };
    auto stageV = [&](int kvt) {
        char* Vd = (char*)(lds + 16384);
#pragma unroll
        for (int i = 0; i < 2; i++) {
            int a = (w * 2 + i) * 1024 + (lane << 4);
            int row = a >> 7;
            int inner = (a & 127) ^ ((row & 7) << 4);
            const char* src = (const char*)Vh + ((long)row * N_TOK + (long)kvt * 64) * 2 + inner;
            gld_lds16(src, Vd + (w * 2 + i) * 1024);
        }
    };

    const int NT = N_TOK / 64;
    stageK(0, 0);
    __syncthreads();

    for (int t = 0; t < NT; t++) {
        const int cur = t & 1;
        stageV(t);
        if (t + 1 < NT) stageK(t + 1, cur ^ 1);

        const char* Kcb = (const char*)(lds + cur * 8192);
        f32x4 s[4] = {};
#pragma unroll
        for (int jc = 0; jc < 4; jc++) {
            const char* rb = Kcb + (jc * 16 + fr) * 256;
#pragma unroll
            for (int c = 0; c < 4; c++) {
                short8 kf = *(const short8*)(rb + colKb[c]);
                s[jc] = __builtin_amdgcn_mfma_f32_16x16x32_bf16(kf, qf[c], s[jc], 0, 0, 0);
            }
        }

        float tm = -1e30f;
#pragma unroll
        for (int jc = 0; jc < 4; jc++)
#pragma unroll
            for (int r = 0; r < 4; r++) tm = fmaxf(tm, s[jc][r]);
        tm = fmaxf(tm, __shfl_xor(tm, 16));
        tm = fmaxf(tm, __shfl_xor(tm, 32));
        float nm = fmaxf(mrow, tm);
        float resc = exp2f(C1 * (mrow - nm));
        mrow = nm;
        float sum = 0.f;
#pragma unroll
        for (int jc = 0; jc < 4; jc++)
#pragma unroll
            for (int r = 0; r < 4; r++) {
                float p = exp2f(C1 * (s[jc][r] - nm));
                s[jc][r] = p;
                sum += p;
            }
        sum += __shfl_xor(sum, 16);
        sum += __shfl_xor(sum, 32);
        lrow = lrow * resc + sum;
#pragma unroll
        for (int f = 0; f < 8; f++)
#pragma unroll
            for (int r = 0; r < 4; r++) oacc[f][r] *= resc;

#pragma unroll
        for (int jc = 0; jc < 4; jc++) {
            s16x4 pk;
            pk[0] = f2bf(s[jc][0]); pk[1] = f2bf(s[jc][1]);
            pk[2] = f2bf(s[jc][2]); pk[3] = f2bf(s[jc][3]);
            *(s16x4*)(Pw + wr_off[jc]) = pk;
        }
        short8 pa[2];
#pragma unroll
        for (int kc = 0; kc < 2; kc++)
            pa[kc] = *(const short8*)(Pw + rd_off[kc]);

        __syncthreads();

        const char* Vcb = (const char*)(lds + 16384);
#pragma unroll
        for (int f = 0; f < 8; f++) {
            const char* rb = Vcb + (f * 16 + fr) * 128;
#pragma unroll
            for (int kc = 0; kc < 2; kc++) {
                short8 vf = *(const short8*)(rb + colVb[kc]);
                oacc[f] = __builtin_amdgcn_mfma_f32_16x16x32_bf16(vf, pa[kc], oacc[f], 0, 0, 0);
            }
        }
        __syncthreads();
    }

    const float inv = 1.f / lrow;
    const long row = qbase + fr;
#pragma unroll
    for (int f = 0; f < 8; f++) {
        float4 o;
        o.x = oacc[f][0] * inv; o.y = oacc[f][1] * inv;
        o.z = oacc[f][2] * inv; o.w = oacc[f][3] * inv;
        *(float4*)(O + row * (long)DMODEL + h * DK + f * 16 + fq * 4) = o;
    }
}

// ---------------- fused Add + LayerNorm (1 block = 1 row of 2048) -----------
template <bool WBF>
__global__ __launch_bounds__(256) void add_ln(const float* __restrict__ A,
                                              const float* __restrict__ B,
                                              const float* __restrict__ alpha,
                                              const float* __restrict__ beta,
                                              float* __restrict__ out,
                                              short* __restrict__ outbf) {
    const int row = blockIdx.x, t = threadIdx.x;
    const long base = (long)row * DMODEL;
    float4 va[2], vb[2];
    float s = 0.f, q = 0.f;
#pragma unroll
    for (int i = 0; i < 2; i++) {
        long off = base + (long)(t + i * 256) * 4;
        va[i] = *(const float4*)(A + off);
        vb[i] = *(const float4*)(B + off);
        float x0 = va[i].x + vb[i].x, x1 = va[i].y + vb[i].y;
        float x2 = va[i].z + vb[i].z, x3 = va[i].w + vb[i].w;
        s += x0 + x1 + x2 + x3;
        q += x0 * x0 + x1 * x1 + x2 * x2 + x3 * x3;
    }
#pragma unroll
    for (int o = 1; o < 64; o <<= 1) { s += __shfl_xor(s, o); q += __shfl_xor(q, o); }
    __shared__ float red[8];
    if ((t & 63) == 0) { red[t >> 6] = s; red[4 + (t >> 6)] = q; }
    __syncthreads();
    s = red[0] + red[1] + red[2] + red[3];
    q = red[4] + red[5] + red[6] + red[7];
    const float mean = s * (1.f / DMODEL);
    const float var = q * (1.f / DMODEL) - mean * mean;
    const float rstd = rsqrtf(var + 1e-5f);
#pragma unroll
    for (int i = 0; i < 2; i++) {
        long off = base + (long)(t + i * 256) * 4;
        float4 al = *(const float4*)(alpha + off);
        float4 be = *(const float4*)(beta + off);
        float x[4] = { va[i].x + vb[i].x, va[i].y + vb[i].y, va[i].z + vb[i].z, va[i].w + vb[i].w };
        float a[4] = { al.x, al.y, al.z, al.w };
        float b[4] = { be.x, be.y, be.z, be.w };
#pragma unroll
        for (int j = 0; j < 4; j++) {
            float o2 = (x[j] - mean) * rstd * a[j] + b[j];
            out[off + j] = o2;
            if (WBF) outbf[off + j] = f2bf(o2);
        }
    }
}

// ---------------- Add + LN2 with 4-slab split-K reduction + bias ------------
__global__ __launch_bounds__(256) void add_ln2_red(const float* __restrict__ H1,
                                                   const float* __restrict__ F4,
                                                   const float* __restrict__ b2,
                                                   const float* __restrict__ alpha,
                                                   const float* __restrict__ beta,
                                                   float* __restrict__ out) {
    const int row = blockIdx.x, t = threadIdx.x;
    const long base = (long)row * DMODEL;
    const long SL = (long)N_TOK * DMODEL;
    float x[8];
    float s = 0.f, q = 0.f;
#pragma unroll
    for (int i = 0; i < 2; i++) {
        long off = base + (long)(t + i * 256) * 4;
        int col = (t + i * 256) * 4;
        float4 a  = *(const float4*)(H1 + off);
        float4 f0 = *(const float4*)(F4 + off);
        float4 f1 = *(const float4*)(F4 + off + SL);
        float4 f2 = *(const float4*)(F4 + off + 2 * SL);
        float4 f3 = *(const float4*)(F4 + off + 3 * SL);
        float4 bb = *(const float4*)(b2 + col);
        x[i * 4 + 0] = a.x + f0.x + f1.x + f2.x + f3.x + bb.x;
        x[i * 4 + 1] = a.y + f0.y + f1.y + f2.y + f3.y + bb.y;
        x[i * 4 + 2] = a.z + f0.z + f1.z + f2.z + f3.z + bb.z;
        x[i * 4 + 3] = a.w + f0.w + f1.w + f2.w + f3.w + bb.w;
#pragma unroll
        for (int j = 0; j < 4; j++) { s += x[i * 4 + j]; q += x[i * 4 + j] * x[i * 4 + j]; }
    }
#pragma unroll
    for (int o = 1; o < 64; o <<= 1) { s += __shfl_xor(s, o); q += __shfl_xor(q, o); }
    __shared__ float red[8];
    if ((t & 63) == 0) { red[t >> 6] = s; red[4 + (t >> 6)] = q; }
    __syncthreads();
    s = red[0] + red[1] + red[2] + red[3];
    q = red[4] + red[5] + red[6] + red[7];
    const float mean = s * (1.f / DMODEL);
    const float var = q * (1.f / DMODEL) - mean * mean;
    const float rstd = rsqrtf(var + 1e-5f);
#pragma unroll
    for (int i = 0; i < 2; i++) {
        long off = base + (long)(t + i * 256) * 4;
        float4 al = *(const float4*)(alpha + off);
        float4 be = *(const float4*)(beta + off);
        float a[4] = { al.x, al.y, al.z, al.w };
        float b[4] = { be.x, be.y, be.z, be.w };
#pragma unroll
        for (int j = 0; j < 4; j++)
            out[off + j] = (x[i * 4 + j] - mean) * rstd * a[j] + b[j];
    }
}

extern "C" void kernel_launch(void* const* d_in, const int* in_sizes, int n_in,
                              void* d_out, int out_size, void* d_ws, size_t ws_size,
                              hipStream_t stream) {
    const float* X      = (const float*)d_in[0];
    const float* Wq     = (const float*)d_in[1];
    const float* bq     = (const float*)d_in[2];
    const float* Wk     = (const float*)d_in[3];
    const float* bk     = (const float*)d_in[4];
    const float* Wv     = (const float*)d_in[5];
    const float* bv     = (const float*)d_in[6];
    const float* alpha1 = (const float*)d_in[7];
    const float* beta1  = (const float*)d_in[8];
    const float* W1     = (const float*)d_in[9];
    const float* b1     = (const float*)d_in[10];
    const float* W2     = (const float*)d_in[11];
    const float* b2     = (const float*)d_in[12];
    const float* alpha2 = (const float*)d_in[13];
    const float* beta2  = (const float*)d_in[14];
    float* out = (float*)d_out;

    char* ws = (char*)d_ws;
    size_t off = 0;
    auto alloc = [&](size_t bytes) -> void* {
        void* p = ws + off;
        off += (bytes + 255) & ~(size_t)255;
        return p;
    };
    short* XBF   = (short*)alloc(2048UL * 2048 * 2);       // dead after QKV gemm
    short* WQKVT = (short*)alloc(48UL * 128 * 2048 * 2);   // = [6144][2048]; dead after QKV
    short* W1T   = (short*)alloc(8192UL * 2048 * 2);       // dead after FFN1
    short* W2T   = (short*)alloc(2048UL * 8192 * 2);
    short* QKV   = (short*)alloc(48UL * 2048 * 128 * 2);   // Q(0-15),K(16-31),V(32-47)
    short* VT    = (short*)alloc(16UL * 128 * 2048 * 2);
    float* ATTN  = (float*)alloc(2048UL * 2048 * 4);
    float* H1    = (float*)alloc(2048UL * 2048 * 4);
    short* H1BF  = (short*)alloc(2048UL * 2048 * 2);
    short* G     = (short*)alloc(2048UL * 8192 * 2);
    // F4 (64 MB, 4 split-K f32 slabs) aliases XBF+WQKVT+W1T (all dead by FFN2)
    float* F4 = (float*)XBF;

    // 1. casts / transposes
    cast_f32_bf16<<<2048, 256, 0, stream>>>(X, XBF, 2048 * 2048 / 8);
    transpose_cast<float><<<dim3(2, 32, 16), 256, 0, stream>>>(Wq, WQKVT,                    2048, 128, 2048L * 128, 128L * 2048);
    transpose_cast<float><<<dim3(2, 32, 16), 256, 0, stream>>>(Wk, WQKVT + 16L * 128 * 2048, 2048, 128, 2048L * 128, 128L * 2048);
    transpose_cast<float><<<dim3(2, 32, 16), 256, 0, stream>>>(Wv, WQKVT + 32L * 128 * 2048, 2048, 128, 2048L * 128, 128L * 2048);
    transpose_cast<float><<<dim3(128, 32, 1), 256, 0, stream>>>(W1, W1T, 2048, 8192, 0, 0);
    transpose_cast<float><<<dim3(32, 128, 1), 256, 0, stream>>>(W2, W2T, 8192, 2048, 0, 0);

    // 2. QKV fused GEMM: M=2048, N=6144 (TM=8, TN=24 -> 192 blocks)
    gemm256<0><<<192, 512, 0, stream>>>(XBF, WQKVT, QKV, bq, bk, bv, 2048, 8);

    // 3. V -> V^T per head
    transpose_cast<__hip_bfloat16><<<dim3(2, 32, 16), 256, 0, stream>>>(
        (const __hip_bfloat16*)(QKV + 32L * 2048 * 128), VT, 2048, 128, 2048L * 128, 128L * 2048);

    // 4. attention (256 blocks x 8 waves; LDS-staged K/V)
    attn_flash<<<256, 512, 0, stream>>>(QKV, QKV + 16L * 2048 * 128, VT, ATTN);

    // 5. Add & LN 1
    add_ln<true><<<2048, 256, 0, stream>>>(X, ATTN, alpha1, beta1, H1, H1BF);

    // 6. FFN: FFN1 M=2048 N=8192 (256 blocks); FFN2 split-K=4 (256 blocks)
    gemm256<1><<<256, 512, 0, stream>>>(H1BF, W1T, G, b1, nullptr, nullptr, 2048, 8);
    gemm256<2><<<256, 512, 0, stream>>>(G, W2T, F4, nullptr, nullptr, nullptr, 8192, 8);

    // 7. Add + reduce + LN 2 -> output
    add_ln2_red<<<2048, 256, 0, stream>>>(H1, F4, b2, alpha2, beta2, out);
}

// Round 12
// 371.650 us; speedup vs baseline: 1.7013x; 1.0192x over previous
//
#include <hip/hip_runtime.h>
#include <hip/hip_bf16.h>

#define N_TOK 2048
#define DMODEL 2048
#define NH 16
#define DK 128
#define DFF 8192

typedef __attribute__((ext_vector_type(8))) short short8;
typedef __attribute__((ext_vector_type(4))) short s16x4;
typedef __attribute__((ext_vector_type(4))) float f32x4;

__device__ __forceinline__ short f2bf(float f) {
    unsigned int x = __builtin_bit_cast(unsigned int, f);
    unsigned int r = (x + 0x7fffu + ((x >> 16) & 1u)) >> 16;
    return (short)r;
}
__device__ __forceinline__ float bf2f(short s) {
    unsigned int u = ((unsigned int)(unsigned short)s) << 16;
    return __builtin_bit_cast(float, u);
}

// ---------------- cast X (f32 -> bf16), 8 elems/thread ----------------
__global__ __launch_bounds__(256) void cast_f32_bf16(const float* __restrict__ in,
                                                     short* __restrict__ out, int n8) {
    int i = blockIdx.x * 256 + threadIdx.x;
    if (i >= n8) return;
    const float4* p = (const float4*)in + (size_t)i * 2;
    float4 a = p[0], b = p[1];
    short8 o;
    o[0] = f2bf(a.x); o[1] = f2bf(a.y); o[2] = f2bf(a.z); o[3] = f2bf(a.w);
    o[4] = f2bf(b.x); o[5] = f2bf(b.y); o[6] = f2bf(b.z); o[7] = f2bf(b.w);
    *(short8*)(out + (size_t)i * 8) = o;
}

// ------- transpose + cast to bf16 (64x64 LDS tiles, short8 writes) ----------
template <typename TIN>
__global__ __launch_bounds__(256) void transpose_cast(const TIN* __restrict__ in,
                                                      short* __restrict__ out,
                                                      int R, int C, long sIn, long sOut) {
    __shared__ float t[64][65];
    in  += (long)blockIdx.z * sIn;
    out += (long)blockIdx.z * sOut;
    const int tid = threadIdx.x;
    int tx = tid & 63, ty = tid >> 6;
    long r0 = (long)blockIdx.y * 64, c0 = (long)blockIdx.x * 64;
    for (int i = 0; i < 16; i++) {
        int r = ty + i * 4;
        t[r][tx] = (float)in[(r0 + r) * (long)C + c0 + tx];
    }
    __syncthreads();
    // each thread writes 8 consecutive out-elements (vectorized, 16B/lane)
#pragma unroll
    for (int p = 0; p < 2; p++) {
        int c = (tid >> 3) + p * 32;
        int r8 = (tid & 7) * 8;
        short8 v;
#pragma unroll
        for (int j = 0; j < 8; j++) v[j] = f2bf(t[r8 + j][c]);
        *(short8*)(out + (c0 + c) * (long)R + r0 + r8) = v;
    }
}

// ---------------- async global->LDS helper ----------------
__device__ __forceinline__ void gld_lds16(const void* g, void* l) {
    __builtin_amdgcn_global_load_lds(
        (const __attribute__((address_space(1))) void*)g,
        (__attribute__((address_space(3))) void*)l, 16, 0, 0);
}

// ======== 256x256 bf16 GEMM, BK=64, 8 waves, 8-phase, B-read-once ===========
// (unchanged from R11 — plateaued at ~820-850 TF; MODE 2 now bf16 slabs)
#define VM8 asm volatile("s_waitcnt vmcnt(8)" ::: "memory")
#define VM0 asm volatile("s_waitcnt vmcnt(0)" ::: "memory")
#define VMNONE ((void)0)

#define PHASE(BUF, MH, NHI, RA, RBNH, STAGE_STMT, VMSTMT)                       \
  {                                                                             \
    if (RA) {                                                                   \
      _Pragma("unroll") for (int mp = 0; mp < 4; mp++)                          \
        _Pragma("unroll") for (int kk = 0; kk < 2; kk++) {                      \
          int rowA = wr * 128 + (MH) * 64 + mp * 16 + fr;                       \
          af[mp][kk] = *(const short8*)((const char*)lds + (BUF) * 65536 +      \
                         rowA * 128 + (((kk * 4 + fq) ^ (rowA & 7)) << 4));     \
        }                                                                       \
    }                                                                           \
    if ((RBNH) < 2) {                                                           \
      _Pragma("unroll") for (int np = 0; np < 2; np++)                          \
        _Pragma("unroll") for (int kk = 0; kk < 2; kk++) {                      \
          int rowB = wc * 64 + (RBNH) * 32 + np * 16 + fr;                      \
          bf[(RBNH) & 1][np][kk] =                                              \
              *(const short8*)((const char*)lds + (BUF) * 65536 + 32768 +       \
                  rowB * 128 + (((kk * 4 + fq) ^ (rowB & 7)) << 4));            \
        }                                                                       \
    }                                                                           \
    STAGE_STMT;                                                                 \
    __builtin_amdgcn_s_barrier();                                               \
    asm volatile("s_waitcnt lgkmcnt(0)" ::: "memory");                          \
    __builtin_amdgcn_sched_barrier(0);                                          \
    __builtin_amdgcn_s_setprio(1);                                              \
    _Pragma("unroll") for (int mp = 0; mp < 4; mp++)                            \
      _Pragma("unroll") for (int np = 0; np < 2; np++)                          \
        _Pragma("unroll") for (int kk = 0; kk < 2; kk++)                        \
          acc[(MH) * 4 + mp][(NHI) * 2 + np] =                                  \
              __builtin_amdgcn_mfma_f32_16x16x32_bf16(                          \
                  af[mp][kk], bf[NHI][np][kk], acc[(MH) * 4 + mp][(NHI) * 2 + np],\
                  0, 0, 0);                                                     \
    __builtin_amdgcn_s_setprio(0);                                              \
    VMSTMT;                                                                     \
    __builtin_amdgcn_sched_barrier(0);                                          \
    __builtin_amdgcn_s_barrier();                                               \
    __builtin_amdgcn_sched_barrier(0);                                          \
  }

template <int MODE>
__global__ __launch_bounds__(512, 2) void gemm256(const short* __restrict__ A,
                                                  const short* __restrict__ Bt,
                                                  void* __restrict__ Cv,
                                                  const float* __restrict__ b0,
                                                  const float* __restrict__ b1,
                                                  const float* __restrict__ b2,
                                                  int Ktot, int TM) {
    __shared__ short lds[65536];   // 128 KB
    const int tid = threadIdx.x, lane = tid & 63, w = tid >> 6;
    const int T = gridDim.x, bid = blockIdx.x;
    const int vbid = (bid & 7) * (T >> 3) + (bid >> 3);   // XCD chunking
    const int mt = vbid % TM;
    const int rest = vbid / TM;
    int nt = rest, z = 0;
    if (MODE == 2) { nt = rest & 7; z = rest >> 3; }
    const long brow = (long)mt * 256, bcol = (long)nt * 256;
    const short* Ab = A + (MODE == 2 ? (long)z * 2048 : 0);
    const short* Bb = Bt + (MODE == 2 ? (long)z * 2048 : 0);

    auto stageA = [&](int kt, int buf, int mh) {
#pragma unroll
        for (int j = 0; j < 2; j++) {
            int row = mh * 64 + j * 128 + (tid >> 3);
            int g = (lane & 7) ^ (row & 7);
            gld_lds16((const char*)(Ab + (brow + row) * (long)Ktot + (long)kt * 64) + g * 16,
                      (char*)lds + buf * 65536 + mh * 8192 + j * 16384 + w * 1024 + lane * 16);
        }
    };
    auto stageB = [&](int kt, int buf, int nh) {
#pragma unroll
        for (int j = 0; j < 2; j++) {
            int s = 2 * j + (w >> 2);
            int rin = (w & 3) * 8 + (lane >> 3);
            int row = s * 64 + nh * 32 + rin;
            int g = (lane & 7) ^ (row & 7);
            gld_lds16((const char*)(Bb + (bcol + row) * (long)Ktot + (long)kt * 64) + g * 16,
                      (char*)lds + buf * 65536 + 32768 + j * 16384 + (w >> 2) * 8192 +
                          nh * 4096 + (w & 3) * 1024 + lane * 16);
        }
    };

    const int wr = w >> 2, wc = w & 3;          // 2 x 4 wave grid (128 x 64 out)
    const int fr = lane & 15, fq = lane >> 4;
    f32x4 acc[8][4] = {};
    short8 af[4][2], bf[2][2][2];

    stageA(0, 0, 0); stageB(0, 0, 0); stageB(0, 0, 1); stageA(0, 0, 1);
    stageA(1, 1, 0); stageB(1, 1, 0); stageB(1, 1, 1); stageA(1, 1, 1);
    VM8;
    __builtin_amdgcn_s_barrier();

    for (int i = 0; i < 15; i++) {
        const int kn = 2 * i + 2;
        PHASE(0, 0, 0, 1, 0, {}, VMNONE)
        PHASE(0, 0, 1, 0, 1, { stageA(kn, 0, 0); stageB(kn, 0, 0); }, VMNONE)
        PHASE(0, 1, 0, 1, 2, { stageB(kn, 0, 1); }, VMNONE)
        PHASE(0, 1, 1, 0, 2, { stageA(kn, 0, 1); }, VM8)
        PHASE(1, 0, 0, 1, 0, {}, VMNONE)
        PHASE(1, 0, 1, 0, 1, { stageA(kn + 1, 1, 0); stageB(kn + 1, 1, 0); }, VMNONE)
        PHASE(1, 1, 0, 1, 2, { stageB(kn + 1, 1, 1); }, VMNONE)
        PHASE(1, 1, 1, 0, 2, { stageA(kn + 1, 1, 1); }, VM8)
    }
    PHASE(0, 0, 0, 1, 0, {}, VMNONE)
    PHASE(0, 0, 1, 0, 1, {}, VMNONE)
    PHASE(0, 1, 0, 1, 2, {}, VMNONE)
    PHASE(0, 1, 1, 0, 2, {}, VM0)
    PHASE(1, 0, 0, 1, 0, {}, VMNONE)
    PHASE(1, 0, 1, 0, 1, {}, VMNONE)
    PHASE(1, 1, 0, 1, 2, {}, VMNONE)
    PHASE(1, 1, 1, 0, 2, {}, VMNONE)

    const long crow0 = brow + wr * 128, ccol0 = bcol + wc * 64;
#pragma unroll
    for (int n = 0; n < 4; n++) {
        const long col = ccol0 + (n >> 1) * 32 + (n & 1) * 16 + fr;
        float bval = 0.f;
        if (MODE == 0) {
            const float* bp = (col >> 11) == 0 ? b0 : (col >> 11) == 1 ? b1 : b2;
            bval = bp[col & 2047];
        } else if (MODE == 1) bval = b0[col];
#pragma unroll
        for (int m = 0; m < 8; m++) {
#pragma unroll
            for (int r = 0; r < 4; r++) {
                const long row = crow0 + (m >> 2) * 64 + (m & 3) * 16 + fq * 4 + r;
                float v = acc[m][n][r] + bval;
                if (MODE == 0) {
                    const long slab = col >> 7;
                    ((short*)Cv)[slab * (2048L * 128) + row * 128 + (col & 127)] = f2bf(v);
                } else if (MODE == 1) {
                    ((short*)Cv)[row * 8192 + col] = f2bf(fmaxf(v, 0.f));
                } else {
                    ((short*)Cv)[(long)z * (2048L * 2048) + row * 2048 + col] = f2bf(v);
                }
            }
        }
    }
}

// ------- flash attention v6: 4-deep K/V rings, 1 barrier/iter, vmcnt(8) -----
// Q,K: [H][N][DK] bf16.  VT: [H][DK][N] bf16.  O: [N][DMODEL] f32.
// LDS 144KB: K[4][64][128] | V[4][128][64] | P[8][1024]. Stages issued
// post-PV, 3 tiles ahead; single raw s_barrier between softmax and PV.
// FIFO-traced: prologue 14 loads -> vmcnt(12); steady vmcnt(8) keeps the
// newest 8 (K(t+2..t+3), V(t+1..t+2)) in flight; t >= NT-4 drains (vmcnt 0).
__global__ __launch_bounds__(512, 2) void attn_flash(const short* __restrict__ Q,
                                                     const short* __restrict__ Kc,
                                                     const short* __restrict__ VT,
                                                     float* __restrict__ O) {
    __shared__ short lds[73728];   // 144 KB
    const int tid = threadIdx.x, lane = tid & 63, w = tid >> 6;
    const int bid = blockIdx.x;
    const int vid = (bid & 7) * 32 + (bid >> 3);   // XCD-chunked swizzle
    const int h = vid >> 4, qt = vid & 15;
    const int fr = lane & 15, fq = lane >> 4;
    const long qbase = (long)qt * 128 + w * 16;
    const short* Qh = Q  + (long)h * N_TOK * DK;
    const short* Kh = Kc + (long)h * N_TOK * DK;
    const short* Vh = VT + (long)h * DK * N_TOK;
    short* Pw = lds + 65536 + w * 1024;

    short8 qf[4];
#pragma unroll
    for (int c = 0; c < 4; c++)
        qf[c] = *(const short8*)(Qh + (qbase + fr) * DK + c * 32 + fq * 8);

    float mrow = -1e30f, lrow = 0.f;
    f32x4 oacc[8] = {};
    const float C1 = 0.08838834764831845f * 1.4426950408889634f; // 1/sqrt(128)*log2e

    int wr_off[4], rd_off[2];
#pragma unroll
    for (int jc = 0; jc < 4; jc++)
        wr_off[jc] = (fr * 64 + jc * 16 + fq * 4) ^ ((fr & 7) << 3);
#pragma unroll
    for (int kc = 0; kc < 2; kc++)
        rd_off[kc] = (fr * 64 + kc * 32 + fq * 8) ^ ((fr & 7) << 3);
    int colKb[4], colVb[2];
#pragma unroll
    for (int c = 0; c < 4; c++) colKb[c] = (c * 64 + fq * 16) ^ ((fr & 7) << 4);
#pragma unroll
    for (int kc = 0; kc < 2; kc++) colVb[kc] = (kc * 64 + fq * 16) ^ ((fr & 7) << 4);

    auto stageK = [&](int kvt) {
        const int buf = kvt & 3;
        const char* Kg = (const char*)(Kh + (long)kvt * 64 * DK);
        char* Kd = (char*)lds + buf * 16384;
#pragma unroll
        for (int i = 0; i < 2; i++) {
            int a = (w * 2 + i) * 1024 + (lane << 4);
            int src = a ^ (((a >> 8) & 7) << 4);
            gld_lds16(Kg + src, Kd + (w * 2 + i) * 1024);
        }
    };
    auto stageV = [&](int kvt) {
        const int buf = kvt & 3;
        char* Vd = (char*)lds + 65536 + buf * 16384;
#pragma unroll
        for (int i = 0; i < 2; i++) {
            int a = (w * 2 + i) * 1024 + (lane << 4);
            int row = a >> 7;
            int inner = (a & 127) ^ ((row & 7) << 4);
            const char* src = (const char*)Vh + ((long)row * N_TOK + (long)kvt * 64) * 2 + inner;
            gld_lds16(src, Vd + (w * 2 + i) * 1024);
        }
    };

    const int NT = N_TOK / 64;   // 32
    // prologue: K0 V0 K1 V1 K2 V2 K3 (14 loads); oldest 2 (K0) before loop
    stageK(0); stageV(0); stageK(1); stageV(1); stageK(2); stageV(2); stageK(3);
    asm volatile("s_waitcnt vmcnt(12)" ::: "memory");
    __builtin_amdgcn_s_barrier();
    __builtin_amdgcn_sched_barrier(0);

    for (int t = 0; t < NT; t++) {
        // --- QK^T from K[t&3] ---
        const char* Kcb = (const char*)lds + (t & 3) * 16384;
        f32x4 s[4] = {};
#pragma unroll
        for (int jc = 0; jc < 4; jc++) {
            const char* rb = Kcb + (jc * 16 + fr) * 256;
#pragma unroll
            for (int c = 0; c < 4; c++) {
                short8 kf = *(const short8*)(rb + colKb[c]);
                s[jc] = __builtin_amdgcn_mfma_f32_16x16x32_bf16(kf, qf[c], s[jc], 0, 0, 0);
            }
        }

        // --- online softmax (lane owns q-row fr) ---
        float tm = -1e30f;
#pragma unroll
        for (int jc = 0; jc < 4; jc++)
#pragma unroll
            for (int r = 0; r < 4; r++) tm = fmaxf(tm, s[jc][r]);
        tm = fmaxf(tm, __shfl_xor(tm, 16));
        tm = fmaxf(tm, __shfl_xor(tm, 32));
        float nm = fmaxf(mrow, tm);
        float resc = exp2f(C1 * (mrow - nm));
        mrow = nm;
        float sum = 0.f;
#pragma unroll
        for (int jc = 0; jc < 4; jc++)
#pragma unroll
            for (int r = 0; r < 4; r++) {
                float p = exp2f(C1 * (s[jc][r] - nm));
                s[jc][r] = p;
                sum += p;
            }
        sum += __shfl_xor(sum, 16);
        sum += __shfl_xor(sum, 32);
        lrow = lrow * resc + sum;
#pragma unroll
        for (int f = 0; f < 8; f++)
#pragma unroll
            for (int r = 0; r < 4; r++) oacc[f][r] *= resc;

        // --- P bounce (per-wave region; same-wave lgkm ordering) ---
#pragma unroll
        for (int jc = 0; jc < 4; jc++) {
            s16x4 pk;
            pk[0] = f2bf(s[jc][0]); pk[1] = f2bf(s[jc][1]);
            pk[2] = f2bf(s[jc][2]); pk[3] = f2bf(s[jc][3]);
            *(s16x4*)(Pw + wr_off[jc]) = pk;
        }
        short8 pa[2];
#pragma unroll
        for (int kc = 0; kc < 2; kc++)
            pa[kc] = *(const short8*)(Pw + rd_off[kc]);

        // --- single barrier: V(t)/K(t+1) landed (counted), QK(t) readers done
        if (t < NT - 4) asm volatile("s_waitcnt vmcnt(8)" ::: "memory");
        else            asm volatile("s_waitcnt vmcnt(0)" ::: "memory");
        __builtin_amdgcn_sched_barrier(0);
        __builtin_amdgcn_s_barrier();
        __builtin_amdgcn_sched_barrier(0);

        // --- PV from V[t&3] ---
        const char* Vcb = (const char*)lds + 65536 + (t & 3) * 16384;
#pragma unroll
        for (int f = 0; f < 8; f++) {
            const char* rb = Vcb + (f * 16 + fr) * 128;
#pragma unroll
            for (int kc = 0; kc < 2; kc++) {
                short8 vf = *(const short8*)(rb + colVb[kc]);
                oacc[f] = __builtin_amdgcn_mfma_f32_16x16x32_bf16(vf, pa[kc], oacc[f], 0, 0, 0);
            }
        }

        // --- prefetch 3-4 tiles ahead (post-PV; safe vs barrier(t)) ---
        if (t + 4 < NT) stageK(t + 4);
        if (t + 3 < NT) stageV(t + 3);
    }

    const float inv = 1.f / lrow;
    const long row = qbase + fr;
#pragma unroll
    for (int f = 0; f < 8; f++) {
        float4 o;
        o.x = oacc[f][0] * inv; o.y = oacc[f][1] * inv;
        o.z = oacc[f][2] * inv; o.w = oacc[f][3] * inv;
        *(float4*)(O + row * (long)DMODEL + h * DK + f * 16 + fq * 4) = o;
    }
}

// ---------------- fused Add + LayerNorm (1 block = 1 row of 2048) -----------
template <bool WBF>
__global__ __launch_bounds__(256) void add_ln(const float* __restrict__ A,
                                              const float* __restrict__ B,
                                              const float* __restrict__ alpha,
                                              const float* __restrict__ beta,
                                              float* __restrict__ out,
                                              short* __restrict__ outbf) {
    const int row = blockIdx.x, t = threadIdx.x;
    const long base = (long)row * DMODEL;
    float4 va[2], vb[2];
    float s = 0.f, q = 0.f;
#pragma unroll
    for (int i = 0; i < 2; i++) {
        long off = base + (long)(t + i * 256) * 4;
        va[i] = *(const float4*)(A + off);
        vb[i] = *(const float4*)(B + off);
        float x0 = va[i].x + vb[i].x, x1 = va[i].y + vb[i].y;
        float x2 = va[i].z + vb[i].z, x3 = va[i].w + vb[i].w;
        s += x0 + x1 + x2 + x3;
        q += x0 * x0 + x1 * x1 + x2 * x2 + x3 * x3;
    }
#pragma unroll
    for (int o = 1; o < 64; o <<= 1) { s += __shfl_xor(s, o); q += __shfl_xor(q, o); }
    __shared__ float red[8];
    if ((t & 63) == 0) { red[t >> 6] = s; red[4 + (t >> 6)] = q; }
    __syncthreads();
    s = red[0] + red[1] + red[2] + red[3];
    q = red[4] + red[5] + red[6] + red[7];
    const float mean = s * (1.f / DMODEL);
    const float var = q * (1.f / DMODEL) - mean * mean;
    const float rstd = rsqrtf(var + 1e-5f);
#pragma unroll
    for (int i = 0; i < 2; i++) {
        long off = base + (long)(t + i * 256) * 4;
        float4 al = *(const float4*)(alpha + off);
        float4 be = *(const float4*)(beta + off);
        float x[4] = { va[i].x + vb[i].x, va[i].y + vb[i].y, va[i].z + vb[i].z, va[i].w + vb[i].w };
        float a[4] = { al.x, al.y, al.z, al.w };
        float b[4] = { be.x, be.y, be.z, be.w };
#pragma unroll
        for (int j = 0; j < 4; j++) {
            float o2 = (x[j] - mean) * rstd * a[j] + b[j];
            out[off + j] = o2;
            if (WBF) outbf[off + j] = f2bf(o2);
        }
    }
}

// -------- Add + LN2 with 4-slab (bf16) split-K reduction + bias -------------
__global__ __launch_bounds__(256) void add_ln2_red(const float* __restrict__ H1,
                                                   const short* __restrict__ F4,
                                                   const float* __restrict__ b2,
                                                   const float* __restrict__ alpha,
                                                   const float* __restrict__ beta,
                                                   float* __restrict__ out) {
    const int row = blockIdx.x, t = threadIdx.x;
    const long base = (long)row * DMODEL;
    const long SL = (long)N_TOK * DMODEL;
    float x[8];
    float s = 0.f, q = 0.f;
#pragma unroll
    for (int i = 0; i < 2; i++) {
        long off = base + (long)(t + i * 256) * 4;
        int col = (t + i * 256) * 4;
        float4 a  = *(const float4*)(H1 + off);
        s16x4 f0 = *(const s16x4*)(F4 + off);
        s16x4 f1 = *(const s16x4*)(F4 + off + SL);
        s16x4 f2 = *(const s16x4*)(F4 + off + 2 * SL);
        s16x4 f3 = *(const s16x4*)(F4 + off + 3 * SL);
        float4 bb = *(const float4*)(b2 + col);
        float xa[4] = { a.x + bb.x, a.y + bb.y, a.z + bb.z, a.w + bb.w };
#pragma unroll
        for (int j = 0; j < 4; j++) {
            float v = xa[j] + bf2f(f0[j]) + bf2f(f1[j]) + bf2f(f2[j]) + bf2f(f3[j]);
            x[i * 4 + j] = v;
            s += v; q += v * v;
        }
    }
#pragma unroll
    for (int o = 1; o < 64; o <<= 1) { s += __shfl_xor(s, o); q += __shfl_xor(q, o); }
    __shared__ float red[8];
    if ((t & 63) == 0) { red[t >> 6] = s; red[4 + (t >> 6)] = q; }
    __syncthreads();
    s = red[0] + red[1] + red[2] + red[3];
    q = red[4] + red[5] + red[6] + red[7];
    const float mean = s * (1.f / DMODEL);
    const float var = q * (1.f / DMODEL) - mean * mean;
    const float rstd = rsqrtf(var + 1e-5f);
#pragma unroll
    for (int i = 0; i < 2; i++) {
        long off = base + (long)(t + i * 256) * 4;
        float4 al = *(const float4*)(alpha + off);
        float4 be = *(const float4*)(beta + off);
        float a[4] = { al.x, al.y, al.z, al.w };
        float b[4] = { be.x, be.y, be.z, be.w };
#pragma unroll
        for (int j = 0; j < 4; j++)
            out[off + j] = (x[i * 4 + j] - mean) * rstd * a[j] + b[j];
    }
}

extern "C" void kernel_launch(void* const* d_in, const int* in_sizes, int n_in,
                              void* d_out, int out_size, void* d_ws, size_t ws_size,
                              hipStream_t stream) {
    const float* X      = (const float*)d_in[0];
    const float* Wq     = (const float*)d_in[1];
    const float* bq     = (const float*)d_in[2];
    const float* Wk     = (const float*)d_in[3];
    const float* bk     = (const float*)d_in[4];
    const float* Wv     = (const float*)d_in[5];
    const float* bv     = (const float*)d_in[6];
    const float* alpha1 = (const float*)d_in[7];
    const float* beta1  = (const float*)d_in[8];
    const float* W1     = (const float*)d_in[9];
    const float* b1     = (const float*)d_in[10];
    const float* W2     = (const float*)d_in[11];
    const float* b2     = (const float*)d_in[12];
    const float* alpha2 = (const float*)d_in[13];
    const float* beta2  = (const float*)d_in[14];
    float* out = (float*)d_out;

    char* ws = (char*)d_ws;
    size_t off = 0;
    auto alloc = [&](size_t bytes) -> void* {
        void* p = ws + off;
        off += (bytes + 255) & ~(size_t)255;
        return p;
    };
    short* XBF   = (short*)alloc(2048UL * 2048 * 2);       // dead after QKV gemm
    short* WQKVT = (short*)alloc(48UL * 128 * 2048 * 2);   // = [6144][2048]; dead after QKV
    short* W1T   = (short*)alloc(8192UL * 2048 * 2);       // dead after FFN1
    short* W2T   = (short*)alloc(2048UL * 8192 * 2);
    short* QKV   = (short*)alloc(48UL * 2048 * 128 * 2);   // Q(0-15),K(16-31),V(32-47)
    short* VT    = (short*)alloc(16UL * 128 * 2048 * 2);
    float* ATTN  = (float*)alloc(2048UL * 2048 * 4);
    float* H1    = (float*)alloc(2048UL * 2048 * 4);
    short* H1BF  = (short*)alloc(2048UL * 2048 * 2);
    short* G     = (short*)alloc(2048UL * 8192 * 2);
    // F4 (32 MB, 4 bf16 split-K slabs) aliases XBF+WQKVT (dead by FFN2)
    short* F4 = XBF;

    // 1. casts / transposes
    cast_f32_bf16<<<2048, 256, 0, stream>>>(X, XBF, 2048 * 2048 / 8);
    transpose_cast<float><<<dim3(2, 32, 16), 256, 0, stream>>>(Wq, WQKVT,                    2048, 128, 2048L * 128, 128L * 2048);
    transpose_cast<float><<<dim3(2, 32, 16), 256, 0, stream>>>(Wk, WQKVT + 16L * 128 * 2048, 2048, 128, 2048L * 128, 128L * 2048);
    transpose_cast<float><<<dim3(2, 32, 16), 256, 0, stream>>>(Wv, WQKVT + 32L * 128 * 2048, 2048, 128, 2048L * 128, 128L * 2048);
    transpose_cast<float><<<dim3(128, 32, 1), 256, 0, stream>>>(W1, W1T, 2048, 8192, 0, 0);
    transpose_cast<float><<<dim3(32, 128, 1), 256, 0, stream>>>(W2, W2T, 8192, 2048, 0, 0);

    // 2. QKV fused GEMM: M=2048, N=6144 (TM=8, TN=24 -> 192 blocks)
    gemm256<0><<<192, 512, 0, stream>>>(XBF, WQKVT, QKV, bq, bk, bv, 2048, 8);

    // 3. V -> V^T per head
    transpose_cast<__hip_bfloat16><<<dim3(2, 32, 16), 256, 0, stream>>>(
        (const __hip_bfloat16*)(QKV + 32L * 2048 * 128), VT, 2048, 128, 2048L * 128, 128L * 2048);

    // 4. attention (256 blocks x 8 waves; 4-deep pipelined K/V)
    attn_flash<<<256, 512, 0, stream>>>(QKV, QKV + 16L * 2048 * 128, VT, ATTN);

    // 5. Add & LN 1
    add_ln<true><<<2048, 256, 0, stream>>>(X, ATTN, alpha1, beta1, H1, H1BF);

    // 6. FFN: FFN1 M=2048 N=8192 (256 blocks); FFN2 split-K=4 (256 blocks)
    gemm256<1><<<256, 512, 0, stream>>>(H1BF, W1T, G, b1, nullptr, nullptr, 2048, 8);
    gemm256<2><<<256, 512, 0, stream>>>(G, W2T, F4, nullptr, nullptr, nullptr, 8192, 8);

    // 7. Add + reduce + LN 2 -> output
    add_ln2_red<<<2048, 256, 0, stream>>>(H1, F4, b2, alpha2, beta2, out);
}

// Round 13
// 368.197 us; speedup vs baseline: 1.7173x; 1.0094x over previous
//
#include <hip/hip_runtime.h>
#include <hip/hip_bf16.h>

#define N_TOK 2048
#define DMODEL 2048
#define NH 16
#define DK 128
#define DFF 8192

typedef __attribute__((ext_vector_type(8))) short short8;
typedef __attribute__((ext_vector_type(4))) short s16x4;
typedef __attribute__((ext_vector_type(4))) float f32x4;

__device__ __forceinline__ short f2bf(float f) {
    unsigned int x = __builtin_bit_cast(unsigned int, f);
    unsigned int r = (x + 0x7fffu + ((x >> 16) & 1u)) >> 16;
    return (short)r;
}
__device__ __forceinline__ float bf2f(short s) {
    unsigned int u = ((unsigned int)(unsigned short)s) << 16;
    return __builtin_bit_cast(float, u);
}

// ---------------- cast X (f32 -> bf16), 8 elems/thread ----------------
__global__ __launch_bounds__(256) void cast_f32_bf16(const float* __restrict__ in,
                                                     short* __restrict__ out, int n8) {
    int i = blockIdx.x * 256 + threadIdx.x;
    if (i >= n8) return;
    const float4* p = (const float4*)in + (size_t)i * 2;
    float4 a = p[0], b = p[1];
    short8 o;
    o[0] = f2bf(a.x); o[1] = f2bf(a.y); o[2] = f2bf(a.z); o[3] = f2bf(a.w);
    o[4] = f2bf(b.x); o[5] = f2bf(b.y); o[6] = f2bf(b.z); o[7] = f2bf(b.w);
    *(short8*)(out + (size_t)i * 8) = o;
}

// --- transpose + cast to bf16 (64x64 LDS tiles, 16B reads + short8 writes) --
template <typename TIN>
__global__ __launch_bounds__(256) void transpose_cast(const TIN* __restrict__ in,
                                                      short* __restrict__ out,
                                                      int R, int C, long sIn, long sOut) {
    __shared__ float t[64][65];
    in  += (long)blockIdx.z * sIn;
    out += (long)blockIdx.z * sOut;
    const int tid = threadIdx.x;
    long r0 = (long)blockIdx.y * 64, c0 = (long)blockIdx.x * 64;
    // read: each thread loads 16B chunks (float4 or 8xbf16)
    if constexpr (sizeof(TIN) == 4) {
#pragma unroll
        for (int i = 0; i < 4; i++) {
            int r = (tid >> 4) + i * 16;
            int c = (tid & 15) * 4;
            float4 v = *(const float4*)((const float*)in + (r0 + r) * (long)C + c0 + c);
            t[r][c + 0] = v.x; t[r][c + 1] = v.y; t[r][c + 2] = v.z; t[r][c + 3] = v.w;
        }
    } else {
#pragma unroll
        for (int i = 0; i < 2; i++) {
            int r = (tid >> 3) + i * 32;
            int c = (tid & 7) * 8;
            short8 v = *(const short8*)((const short*)in + (r0 + r) * (long)C + c0 + c);
#pragma unroll
            for (int j = 0; j < 8; j++) t[r][c + j] = bf2f(v[j]);
        }
    }
    __syncthreads();
    // write: each thread writes 8 consecutive out-elements (16B/lane)
#pragma unroll
    for (int p = 0; p < 2; p++) {
        int c = (tid >> 3) + p * 32;
        int r8 = (tid & 7) * 8;
        short8 v;
#pragma unroll
        for (int j = 0; j < 8; j++) v[j] = f2bf(t[r8 + j][c]);
        *(short8*)(out + (c0 + c) * (long)R + r0 + r8) = v;
    }
}

// ---------------- async global->LDS helper ----------------
__device__ __forceinline__ void gld_lds16(const void* g, void* l) {
    __builtin_amdgcn_global_load_lds(
        (const __attribute__((address_space(1))) void*)g,
        (__attribute__((address_space(3))) void*)l, 16, 0, 0);
}

// ======== 256x256 bf16 GEMM, BK=64, 8 waves, 8-phase, B-read-once ===========
// PHASE un-pinned (R13): no inline lgkmcnt(0)/sched_barrier — compiler's
// dependency-tracked lgkmcnt(N) lets MFMAs start as fragments arrive.
// Raw s_barrier is still an LDS fence (no read hoisting); manual counted
// vmcnt still required (compiler doesn't track gld_lds->LDS deps).
#define VM8 asm volatile("s_waitcnt vmcnt(8)" ::: "memory")
#define VM0 asm volatile("s_waitcnt vmcnt(0)" ::: "memory")
#define VMNONE ((void)0)

#define PHASE(BUF, MH, NHI, RA, RBNH, STAGE_STMT, VMSTMT)                       \
  {                                                                             \
    if (RA) {                                                                   \
      _Pragma("unroll") for (int mp = 0; mp < 4; mp++)                          \
        _Pragma("unroll") for (int kk = 0; kk < 2; kk++) {                      \
          int rowA = wr * 128 + (MH) * 64 + mp * 16 + fr;                       \
          af[mp][kk] = *(const short8*)((const char*)lds + (BUF) * 65536 +      \
                         rowA * 128 + (((kk * 4 + fq) ^ (rowA & 7)) << 4));     \
        }                                                                       \
    }                                                                           \
    if ((RBNH) < 2) {                                                           \
      _Pragma("unroll") for (int np = 0; np < 2; np++)                          \
        _Pragma("unroll") for (int kk = 0; kk < 2; kk++) {                      \
          int rowB = wc * 64 + (RBNH) * 32 + np * 16 + fr;                      \
          bf[(RBNH) & 1][np][kk] =                                              \
              *(const short8*)((const char*)lds + (BUF) * 65536 + 32768 +       \
                  rowB * 128 + (((kk * 4 + fq) ^ (rowB & 7)) << 4));            \
        }                                                                       \
    }                                                                           \
    STAGE_STMT;                                                                 \
    __builtin_amdgcn_s_barrier();                                               \
    __builtin_amdgcn_s_setprio(1);                                              \
    _Pragma("unroll") for (int mp = 0; mp < 4; mp++)                            \
      _Pragma("unroll") for (int np = 0; np < 2; np++)                          \
        _Pragma("unroll") for (int kk = 0; kk < 2; kk++)                        \
          acc[(MH) * 4 + mp][(NHI) * 2 + np] =                                  \
              __builtin_amdgcn_mfma_f32_16x16x32_bf16(                          \
                  af[mp][kk], bf[NHI][np][kk], acc[(MH) * 4 + mp][(NHI) * 2 + np],\
                  0, 0, 0);                                                     \
    __builtin_amdgcn_s_setprio(0);                                              \
    VMSTMT;                                                                     \
    __builtin_amdgcn_s_barrier();                                               \
  }

template <int MODE>
__global__ __launch_bounds__(512, 2) void gemm256(const short* __restrict__ A,
                                                  const short* __restrict__ Bt,
                                                  void* __restrict__ Cv,
                                                  const float* __restrict__ b0,
                                                  const float* __restrict__ b1,
                                                  const float* __restrict__ b2,
                                                  int Ktot, int TM) {
    __shared__ short lds[65536];   // 128 KB
    const int tid = threadIdx.x, lane = tid & 63, w = tid >> 6;
    const int T = gridDim.x, bid = blockIdx.x;
    const int vbid = (bid & 7) * (T >> 3) + (bid >> 3);   // XCD chunking
    const int mt = vbid % TM;
    const int rest = vbid / TM;
    int nt = rest, z = 0;
    if (MODE == 2) { nt = rest & 7; z = rest >> 3; }
    const long brow = (long)mt * 256, bcol = (long)nt * 256;
    const short* Ab = A + (MODE == 2 ? (long)z * 2048 : 0);
    const short* Bb = Bt + (MODE == 2 ? (long)z * 2048 : 0);

    auto stageA = [&](int kt, int buf, int mh) {
#pragma unroll
        for (int j = 0; j < 2; j++) {
            int row = mh * 64 + j * 128 + (tid >> 3);
            int g = (lane & 7) ^ (row & 7);
            gld_lds16((const char*)(Ab + (brow + row) * (long)Ktot + (long)kt * 64) + g * 16,
                      (char*)lds + buf * 65536 + mh * 8192 + j * 16384 + w * 1024 + lane * 16);
        }
    };
    auto stageB = [&](int kt, int buf, int nh) {
#pragma unroll
        for (int j = 0; j < 2; j++) {
            int s = 2 * j + (w >> 2);
            int rin = (w & 3) * 8 + (lane >> 3);
            int row = s * 64 + nh * 32 + rin;
            int g = (lane & 7) ^ (row & 7);
            gld_lds16((const char*)(Bb + (bcol + row) * (long)Ktot + (long)kt * 64) + g * 16,
                      (char*)lds + buf * 65536 + 32768 + j * 16384 + (w >> 2) * 8192 +
                          nh * 4096 + (w & 3) * 1024 + lane * 16);
        }
    };

    const int wr = w >> 2, wc = w & 3;          // 2 x 4 wave grid (128 x 64 out)
    const int fr = lane & 15, fq = lane >> 4;
    f32x4 acc[8][4] = {};
    short8 af[4][2], bf[2][2][2];

    stageA(0, 0, 0); stageB(0, 0, 0); stageB(0, 0, 1); stageA(0, 0, 1);
    stageA(1, 1, 0); stageB(1, 1, 0); stageB(1, 1, 1); stageA(1, 1, 1);
    VM8;
    __builtin_amdgcn_s_barrier();

    for (int i = 0; i < 15; i++) {
        const int kn = 2 * i + 2;
        PHASE(0, 0, 0, 1, 0, {}, VMNONE)
        PHASE(0, 0, 1, 0, 1, { stageA(kn, 0, 0); stageB(kn, 0, 0); }, VMNONE)
        PHASE(0, 1, 0, 1, 2, { stageB(kn, 0, 1); }, VMNONE)
        PHASE(0, 1, 1, 0, 2, { stageA(kn, 0, 1); }, VM8)
        PHASE(1, 0, 0, 1, 0, {}, VMNONE)
        PHASE(1, 0, 1, 0, 1, { stageA(kn + 1, 1, 0); stageB(kn + 1, 1, 0); }, VMNONE)
        PHASE(1, 1, 0, 1, 2, { stageB(kn + 1, 1, 1); }, VMNONE)
        PHASE(1, 1, 1, 0, 2, { stageA(kn + 1, 1, 1); }, VM8)
    }
    PHASE(0, 0, 0, 1, 0, {}, VMNONE)
    PHASE(0, 0, 1, 0, 1, {}, VMNONE)
    PHASE(0, 1, 0, 1, 2, {}, VMNONE)
    PHASE(0, 1, 1, 0, 2, {}, VM0)
    PHASE(1, 0, 0, 1, 0, {}, VMNONE)
    PHASE(1, 0, 1, 0, 1, {}, VMNONE)
    PHASE(1, 1, 0, 1, 2, {}, VMNONE)
    PHASE(1, 1, 1, 0, 2, {}, VMNONE)

    const long crow0 = brow + wr * 128, ccol0 = bcol + wc * 64;
#pragma unroll
    for (int n = 0; n < 4; n++) {
        const long col = ccol0 + (n >> 1) * 32 + (n & 1) * 16 + fr;
        float bval = 0.f;
        if (MODE == 0) {
            const float* bp = (col >> 11) == 0 ? b0 : (col >> 11) == 1 ? b1 : b2;
            bval = bp[col & 2047];
        } else if (MODE == 1) bval = b0[col];
#pragma unroll
        for (int m = 0; m < 8; m++) {
#pragma unroll
            for (int r = 0; r < 4; r++) {
                const long row = crow0 + (m >> 2) * 64 + (m & 3) * 16 + fq * 4 + r;
                float v = acc[m][n][r] + bval;
                if (MODE == 0) {
                    const long slab = col >> 7;
                    ((short*)Cv)[slab * (2048L * 128) + row * 128 + (col & 127)] = f2bf(v);
                } else if (MODE == 1) {
                    ((short*)Cv)[row * 8192 + col] = f2bf(fmaxf(v, 0.f));
                } else {
                    ((short*)Cv)[(long)z * (2048L * 2048) + row * 2048 + col] = f2bf(v);
                }
            }
        }
    }
}

// ------- flash attention v6: 4-deep K/V rings, 1 barrier/iter, vmcnt(8) -----
__global__ __launch_bounds__(512, 2) void attn_flash(const short* __restrict__ Q,
                                                     const short* __restrict__ Kc,
                                                     const short* __restrict__ VT,
                                                     float* __restrict__ O) {
    __shared__ short lds[73728];   // 144 KB
    const int tid = threadIdx.x, lane = tid & 63, w = tid >> 6;
    const int bid = blockIdx.x;
    const int vid = (bid & 7) * 32 + (bid >> 3);   // XCD-chunked swizzle
    const int h = vid >> 4, qt = vid & 15;
    const int fr = lane & 15, fq = lane >> 4;
    const long qbase = (long)qt * 128 + w * 16;
    const short* Qh = Q  + (long)h * N_TOK * DK;
    const short* Kh = Kc + (long)h * N_TOK * DK;
    const short* Vh = VT + (long)h * DK * N_TOK;
    short* Pw = lds + 65536 + w * 1024;

    short8 qf[4];
#pragma unroll
    for (int c = 0; c < 4; c++)
        qf[c] = *(const short8*)(Qh + (qbase + fr) * DK + c * 32 + fq * 8);

    float mrow = -1e30f, lrow = 0.f;
    f32x4 oacc[8] = {};
    const float C1 = 0.08838834764831845f * 1.4426950408889634f; // 1/sqrt(128)*log2e

    int wr_off[4], rd_off[2];
#pragma unroll
    for (int jc = 0; jc < 4; jc++)
        wr_off[jc] = (fr * 64 + jc * 16 + fq * 4) ^ ((fr & 7) << 3);
#pragma unroll
    for (int kc = 0; kc < 2; kc++)
        rd_off[kc] = (fr * 64 + kc * 32 + fq * 8) ^ ((fr & 7) << 3);
    int colKb[4], colVb[2];
#pragma unroll
    for (int c = 0; c < 4; c++) colKb[c] = (c * 64 + fq * 16) ^ ((fr & 7) << 4);
#pragma unroll
    for (int kc = 0; kc < 2; kc++) colVb[kc] = (kc * 64 + fq * 16) ^ ((fr & 7) << 4);

    auto stageK = [&](int kvt) {
        const int buf = kvt & 3;
        const char* Kg = (const char*)(Kh + (long)kvt * 64 * DK);
        char* Kd = (char*)lds + buf * 16384;
#pragma unroll
        for (int i = 0; i < 2; i++) {
            int a = (w * 2 + i) * 1024 + (lane << 4);
            int src = a ^ (((a >> 8) & 7) << 4);
            gld_lds16(Kg + src, Kd + (w * 2 + i) * 1024);
        }
    };
    auto stageV = [&](int kvt) {
        const int buf = kvt & 3;
        char* Vd = (char*)lds + 65536 + buf * 16384;
#pragma unroll
        for (int i = 0; i < 2; i++) {
            int a = (w * 2 + i) * 1024 + (lane << 4);
            int row = a >> 7;
            int inner = (a & 127) ^ ((row & 7) << 4);
            const char* src = (const char*)Vh + ((long)row * N_TOK + (long)kvt * 64) * 2 + inner;
            gld_lds16(src, Vd + (w * 2 + i) * 1024);
        }
    };

    const int NT = N_TOK / 64;   // 32
    stageK(0); stageV(0); stageK(1); stageV(1); stageK(2); stageV(2); stageK(3);
    asm volatile("s_waitcnt vmcnt(12)" ::: "memory");
    __builtin_amdgcn_s_barrier();
    __builtin_amdgcn_sched_barrier(0);

    for (int t = 0; t < NT; t++) {
        const char* Kcb = (const char*)lds + (t & 3) * 16384;
        f32x4 s[4] = {};
#pragma unroll
        for (int jc = 0; jc < 4; jc++) {
            const char* rb = Kcb + (jc * 16 + fr) * 256;
#pragma unroll
            for (int c = 0; c < 4; c++) {
                short8 kf = *(const short8*)(rb + colKb[c]);
                s[jc] = __builtin_amdgcn_mfma_f32_16x16x32_bf16(kf, qf[c], s[jc], 0, 0, 0);
            }
        }

        float tm = -1e30f;
#pragma unroll
        for (int jc = 0; jc < 4; jc++)
#pragma unroll
            for (int r = 0; r < 4; r++) tm = fmaxf(tm, s[jc][r]);
        tm = fmaxf(tm, __shfl_xor(tm, 16));
        tm = fmaxf(tm, __shfl_xor(tm, 32));
        float nm = fmaxf(mrow, tm);
        float resc = exp2f(C1 * (mrow - nm));
        mrow = nm;
        float sum = 0.f;
#pragma unroll
        for (int jc = 0; jc < 4; jc++)
#pragma unroll
            for (int r = 0; r < 4; r++) {
                float p = exp2f(C1 * (s[jc][r] - nm));
                s[jc][r] = p;
                sum += p;
            }
        sum += __shfl_xor(sum, 16);
        sum += __shfl_xor(sum, 32);
        lrow = lrow * resc + sum;
#pragma unroll
        for (int f = 0; f < 8; f++)
#pragma unroll
            for (int r = 0; r < 4; r++) oacc[f][r] *= resc;

#pragma unroll
        for (int jc = 0; jc < 4; jc++) {
            s16x4 pk;
            pk[0] = f2bf(s[jc][0]); pk[1] = f2bf(s[jc][1]);
            pk[2] = f2bf(s[jc][2]); pk[3] = f2bf(s[jc][3]);
            *(s16x4*)(Pw + wr_off[jc]) = pk;
        }
        short8 pa[2];
#pragma unroll
        for (int kc = 0; kc < 2; kc++)
            pa[kc] = *(const short8*)(Pw + rd_off[kc]);

        if (t < NT - 4) asm volatile("s_waitcnt vmcnt(8)" ::: "memory");
        else            asm volatile("s_waitcnt vmcnt(0)" ::: "memory");
        __builtin_amdgcn_sched_barrier(0);
        __builtin_amdgcn_s_barrier();
        __builtin_amdgcn_sched_barrier(0);

        const char* Vcb = (const char*)lds + 65536 + (t & 3) * 16384;
#pragma unroll
        for (int f = 0; f < 8; f++) {
            const char* rb = Vcb + (f * 16 + fr) * 128;
#pragma unroll
            for (int kc = 0; kc < 2; kc++) {
                short8 vf = *(const short8*)(rb + colVb[kc]);
                oacc[f] = __builtin_amdgcn_mfma_f32_16x16x32_bf16(vf, pa[kc], oacc[f], 0, 0, 0);
            }
        }

        if (t + 4 < NT) stageK(t + 4);
        if (t + 3 < NT) stageV(t + 3);
    }

    const float inv = 1.f / lrow;
    const long row = qbase + fr;
#pragma unroll
    for (int f = 0; f < 8; f++) {
        float4 o;
        o.x = oacc[f][0] * inv; o.y = oacc[f][1] * inv;
        o.z = oacc[f][2] * inv; o.w = oacc[f][3] * inv;
        *(float4*)(O + row * (long)DMODEL + h * DK + f * 16 + fq * 4) = o;
    }
}

// ---------------- fused Add + LayerNorm (1 block = 1 row of 2048) -----------
template <bool WBF>
__global__ __launch_bounds__(256) void add_ln(const float* __restrict__ A,
                                              const float* __restrict__ B,
                                              const float* __restrict__ alpha,
                                              const float* __restrict__ beta,
                                              float* __restrict__ out,
                                              short* __restrict__ outbf) {
    const int row = blockIdx.x, t = threadIdx.x;
    const long base = (long)row * DMODEL;
    float4 va[2], vb[2];
    float s = 0.f, q = 0.f;
#pragma unroll
    for (int i = 0; i < 2; i++) {
        long off = base + (long)(t + i * 256) * 4;
        va[i] = *(const float4*)(A + off);
        vb[i] = *(const float4*)(B + off);
        float x0 = va[i].x + vb[i].x, x1 = va[i].y + vb[i].y;
        float x2 = va[i].z + vb[i].z, x3 = va[i].w + vb[i].w;
        s += x0 + x1 + x2 + x3;
        q += x0 * x0 + x1 * x1 + x2 * x2 + x3 * x3;
    }
#pragma unroll
    for (int o = 1; o < 64; o <<= 1) { s += __shfl_xor(s, o); q += __shfl_xor(q, o); }
    __shared__ float red[8];
    if ((t & 63) == 0) { red[t >> 6] = s; red[4 + (t >> 6)] = q; }
    __syncthreads();
    s = red[0] + red[1] + red[2] + red[3];
    q = red[4] + red[5] + red[6] + red[7];
    const float mean = s * (1.f / DMODEL);
    const float var = q * (1.f / DMODEL) - mean * mean;
    const float rstd = rsqrtf(var + 1e-5f);
#pragma unroll
    for (int i = 0; i < 2; i++) {
        long off = base + (long)(t + i * 256) * 4;
        float4 al = *(const float4*)(alpha + off);
        float4 be = *(const float4*)(beta + off);
        float x[4] = { va[i].x + vb[i].x, va[i].y + vb[i].y, va[i].z + vb[i].z, va[i].w + vb[i].w };
        float a[4] = { al.x, al.y, al.z, al.w };
        float b[4] = { be.x, be.y, be.z, be.w };
#pragma unroll
        for (int j = 0; j < 4; j++) {
            float o2 = (x[j] - mean) * rstd * a[j] + b[j];
            out[off + j] = o2;
            if (WBF) outbf[off + j] = f2bf(o2);
        }
    }
}

// -------- Add + LN2 with 4-slab (bf16) split-K reduction + bias -------------
__global__ __launch_bounds__(256) void add_ln2_red(const float* __restrict__ H1,
                                                   const short* __restrict__ F4,
                                                   const float* __restrict__ b2,
                                                   const float* __restrict__ alpha,
                                                   const float* __restrict__ beta,
                                                   float* __restrict__ out) {
    const int row = blockIdx.x, t = threadIdx.x;
    const long base = (long)row * DMODEL;
    const long SL = (long)N_TOK * DMODEL;
    float x[8];
    float s = 0.f, q = 0.f;
#pragma unroll
    for (int i = 0; i < 2; i++) {
        long off = base + (long)(t + i * 256) * 4;
        int col = (t + i * 256) * 4;
        float4 a  = *(const float4*)(H1 + off);
        s16x4 f0 = *(const s16x4*)(F4 + off);
        s16x4 f1 = *(const s16x4*)(F4 + off + SL);
        s16x4 f2 = *(const s16x4*)(F4 + off + 2 * SL);
        s16x4 f3 = *(const s16x4*)(F4 + off + 3 * SL);
        float4 bb = *(const float4*)(b2 + col);
        float xa[4] = { a.x + bb.x, a.y + bb.y, a.z + bb.z, a.w + bb.w };
#pragma unroll
        for (int j = 0; j < 4; j++) {
            float v = xa[j] + bf2f(f0[j]) + bf2f(f1[j]) + bf2f(f2[j]) + bf2f(f3[j]);
            x[i * 4 + j] = v;
            s += v; q += v * v;
        }
    }
#pragma unroll
    for (int o = 1; o < 64; o <<= 1) { s += __shfl_xor(s, o); q += __shfl_xor(q, o); }
    __shared__ float red[8];
    if ((t & 63) == 0) { red[t >> 6] = s; red[4 + (t >> 6)] = q; }
    __syncthreads();
    s = red[0] + red[1] + red[2] + red[3];
    q = red[4] + red[5] + red[6] + red[7];
    const float mean = s * (1.f / DMODEL);
    const float var = q * (1.f / DMODEL) - mean * mean;
    const float rstd = rsqrtf(var + 1e-5f);
#pragma unroll
    for (int i = 0; i < 2; i++) {
        long off = base + (long)(t + i * 256) * 4;
        float4 al = *(const float4*)(alpha + off);
        float4 be = *(const float4*)(beta + off);
        float a[4] = { al.x, al.y, al.z, al.w };
        float b[4] = { be.x, be.y, be.z, be.w };
#pragma unroll
        for (int j = 0; j < 4; j++)
            out[off + j] = (x[i * 4 + j] - mean) * rstd * a[j] + b[j];
    }
}

extern "C" void kernel_launch(void* const* d_in, const int* in_sizes, int n_in,
                              void* d_out, int out_size, void* d_ws, size_t ws_size,
                              hipStream_t stream) {
    const float* X      = (const float*)d_in[0];
    const float* Wq     = (const float*)d_in[1];
    const float* bq     = (const float*)d_in[2];
    const float* Wk     = (const float*)d_in[3];
    const float* bk     = (const float*)d_in[4];
    const float* Wv     = (const float*)d_in[5];
    const float* bv     = (const float*)d_in[6];
    const float* alpha1 = (const float*)d_in[7];
    const float* beta1  = (const float*)d_in[8];
    const float* W1     = (const float*)d_in[9];
    const float* b1     = (const float*)d_in[10];
    const float* W2     = (const float*)d_in[11];
    const float* b2     = (const float*)d_in[12];
    const float* alpha2 = (const float*)d_in[13];
    const float* beta2  = (const float*)d_in[14];
    float* out = (float*)d_out;

    char* ws = (char*)d_ws;
    size_t off = 0;
    auto alloc = [&](size_t bytes) -> void* {
        void* p = ws + off;
        off += (bytes + 255) & ~(size_t)255;
        return p;
    };
    short* XBF   = (short*)alloc(2048UL * 2048 * 2);       // dead after QKV gemm
    short* WQKVT = (short*)alloc(48UL * 128 * 2048 * 2);   // = [6144][2048]; dead after QKV
    short* W1T   = (short*)alloc(8192UL * 2048 * 2);       // dead after FFN1
    short* W2T   = (short*)alloc(2048UL * 8192 * 2);
    short* QKV   = (short*)alloc(48UL * 2048 * 128 * 2);   // Q(0-15),K(16-31),V(32-47)
    short* VT    = (short*)alloc(16UL * 128 * 2048 * 2);
    float* ATTN  = (float*)alloc(2048UL * 2048 * 4);
    float* H1    = (float*)alloc(2048UL * 2048 * 4);
    short* H1BF  = (short*)alloc(2048UL * 2048 * 2);
    short* G     = (short*)alloc(2048UL * 8192 * 2);
    // F4 (32 MB, 4 bf16 split-K slabs) aliases XBF+WQKVT (dead by FFN2)
    short* F4 = XBF;

    // 1. casts / transposes
    cast_f32_bf16<<<2048, 256, 0, stream>>>(X, XBF, 2048 * 2048 / 8);
    transpose_cast<float><<<dim3(2, 32, 16), 256, 0, stream>>>(Wq, WQKVT,                    2048, 128, 2048L * 128, 128L * 2048);
    transpose_cast<float><<<dim3(2, 32, 16), 256, 0, stream>>>(Wk, WQKVT + 16L * 128 * 2048, 2048, 128, 2048L * 128, 128L * 2048);
    transpose_cast<float><<<dim3(2, 32, 16), 256, 0, stream>>>(Wv, WQKVT + 32L * 128 * 2048, 2048, 128, 2048L * 128, 128L * 2048);
    transpose_cast<float><<<dim3(128, 32, 1), 256, 0, stream>>>(W1, W1T, 2048, 8192, 0, 0);
    transpose_cast<float><<<dim3(32, 128, 1), 256, 0, stream>>>(W2, W2T, 8192, 2048, 0, 0);

    // 2. QKV fused GEMM: M=2048, N=6144 (TM=8, TN=24 -> 192 blocks)
    gemm256<0><<<192, 512, 0, stream>>>(XBF, WQKVT, QKV, bq, bk, bv, 2048, 8);

    // 3. V -> V^T per head
    transpose_cast<__hip_bfloat16><<<dim3(2, 32, 16), 256, 0, stream>>>(
        (const __hip_bfloat16*)(QKV + 32L * 2048 * 128), VT, 2048, 128, 2048L * 128, 128L * 2048);

    // 4. attention (256 blocks x 8 waves; 4-deep pipelined K/V)
    attn_flash<<<256, 512, 0, stream>>>(QKV, QKV + 16L * 2048 * 128, VT, ATTN);

    // 5. Add & LN 1
    add_ln<true><<<2048, 256, 0, stream>>>(X, ATTN, alpha1, beta1, H1, H1BF);

    // 6. FFN: FFN1 M=2048 N=8192 (256 blocks); FFN2 split-K=4 (256 blocks)
    gemm256<1><<<256, 512, 0, stream>>>(H1BF, W1T, G, b1, nullptr, nullptr, 2048, 8);
    gemm256<2><<<256, 512, 0, stream>>>(G, W2T, F4, nullptr, nullptr, nullptr, 8192, 8);

    // 7. Add + reduce + LN 2 -> output
    add_ln2_red<<<2048, 256, 0, stream>>>(H1, F4, b2, alpha2, beta2, out);
}